// Round 7
// baseline (592.690 us; speedup 1.0000x reference)
//
#include <hip/hip_runtime.h>
#include <hip/hip_bf16.h>
#include <math.h>

typedef short v8s __attribute__((ext_vector_type(8)));
typedef float v4f __attribute__((ext_vector_type(4)));
typedef float v2f __attribute__((ext_vector_type(2)));
typedef unsigned short u16x4 __attribute__((ext_vector_type(4)));

__device__ __forceinline__ unsigned short f2bf(float f) {
    unsigned int u = __float_as_uint(f);
    u += 0x7fff + ((u >> 16) & 1);   // round-to-nearest-even
    return (unsigned short)(u >> 16);
}
__device__ __forceinline__ float bf2f(unsigned short h) {
    return __uint_as_float(((unsigned int)h) << 16);
}
__device__ __forceinline__ unsigned char f2fp8(float f) {
    int e = __builtin_amdgcn_cvt_pk_fp8_f32(f, f, 0, false);
    return (unsigned char)(e & 0xff);
}

struct GraphPtrs { const int* dst[6]; const int* src[6]; const float* sim[6]; };
struct Ptr3f { const float* p[3]; };

// ---------------- weight transpose + convert: W[K][N] fp32 -> Wt[N][K] bf16 ----------------
__global__ __launch_bounds__(256)
void wcvt_kernel(const float* __restrict__ W, unsigned short* __restrict__ Wt, int K, int N)
{
    __shared__ float tile[32][33];
    const int b = blockIdx.z;
    const float* Wb = W + (size_t)b * K * N;
    unsigned short* Wtb = Wt + (size_t)b * K * N;
    const int k0 = blockIdx.x * 32, n0 = blockIdx.y * 32;
    const int x = threadIdx.x & 31, y = threadIdx.x >> 5;
    #pragma unroll
    for (int j = 0; j < 4; ++j)
        tile[y + 8 * j][x] = Wb[(size_t)(k0 + y + 8 * j) * N + n0 + x];
    __syncthreads();
    #pragma unroll
    for (int j = 0; j < 4; ++j)
        Wtb[(size_t)(n0 + y + 8 * j) * K + k0 + x] = f2bf(tile[x][y + 8 * j]);
}

// q/k/v weights -> W3[(l,t)][768][256] (rows 0-255 q, 256-511 k, 512-767 v)
__global__ __launch_bounds__(256)
void wcvt_qkv_kernel(const float* __restrict__ qw, const float* __restrict__ kw,
                     const float* __restrict__ vw, unsigned short* __restrict__ W3)
{
    __shared__ float tile[32][33];
    const int z = blockIdx.z, lt = z / 3, sec = z - lt * 3;
    const float* src = (sec == 0 ? qw : sec == 1 ? kw : vw) + (size_t)lt * 65536;
    unsigned short* dst = W3 + ((size_t)lt * 768 + sec * 256) * 256;
    const int k0 = blockIdx.x * 32, n0 = blockIdx.y * 32;
    const int x = threadIdx.x & 31, y = threadIdx.x >> 5;
    #pragma unroll
    for (int j = 0; j < 4; ++j)
        tile[y + 8 * j][x] = src[(size_t)(k0 + y + 8 * j) * 256 + n0 + x];
    __syncthreads();
    #pragma unroll
    for (int j = 0; j < 4; ++j)
        dst[(size_t)(n0 + y + 8 * j) * 256 + k0 + x] = f2bf(tile[x][y + 8 * j]);
}

// bias768[lt][768] = concat(q_b[lt], k_b[lt], v_b[lt])
__global__ void bias_concat_kernel(const float* __restrict__ qb, const float* __restrict__ kb,
                                   const float* __restrict__ vb, float* __restrict__ out)
{
    int i = blockIdx.x * 256 + threadIdx.x;
    if (i < 6 * 768) {
        int lt = i / 768, c = i - lt * 768;
        int sec = c >> 8, cc = c & 255;
        const float* s = sec == 0 ? qb : sec == 1 ? kb : vb;
        out[i] = s[lt * 256 + cc];
    }
}

// ---------------- CSR build (all 6 etypes fused) ----------------
__global__ void hist6_kernel(GraphPtrs gp, int* __restrict__ deg6)
{
    constexpr int doff[6] = {0, 10000, 30000, 35000, 55000, 60000};
    const int ei = blockIdx.y;
    int e = blockIdx.x * 256 + threadIdx.x;
    if (e < 100000) atomicAdd(&deg6[doff[ei] + gp.dst[ei][e]], 1);
}

__global__ __launch_bounds__(256)
void scan6_kernel(const int* __restrict__ deg6, int* __restrict__ rp6, int* __restrict__ cursor6)
{
    constexpr int ndv[6]   = {10000, 20000, 5000, 20000, 5000, 10000};
    constexpr int doff[6]  = {0, 10000, 30000, 35000, 55000, 60000};
    constexpr int rpoff[6] = {0, 10001, 30002, 35003, 55004, 60005};
    const int b = blockIdx.x;
    const int nd = ndv[b];
    const int* deg = deg6 + doff[b];
    int* rowptr = rp6 + rpoff[b];
    int* cursor = cursor6 + doff[b];
    const int t = threadIdx.x, lane = t & 63, w = t >> 6;
    __shared__ int wsum[4];
    int carry = 0;
    for (int base = 0; base < nd; base += 1024) {
        int i0 = base + t * 4;
        int x0 = 0, x1 = 0, x2 = 0, x3 = 0;
        if (i0 + 3 < nd) {
            int4 v = *(const int4*)(deg + i0);
            x0 = v.x; x1 = v.y; x2 = v.z; x3 = v.w;
        } else {
            if (i0 < nd) x0 = deg[i0];
            if (i0 + 1 < nd) x1 = deg[i0 + 1];
            if (i0 + 2 < nd) x2 = deg[i0 + 2];
            if (i0 + 3 < nd) x3 = deg[i0 + 3];
        }
        int s1 = x0 + x1, s2 = s1 + x2, tot = s2 + x3;
        int inc = tot;
        #pragma unroll
        for (int o = 1; o < 64; o <<= 1) {
            int y = __shfl_up(inc, o, 64);
            if (lane >= o) inc += y;
        }
        if (lane == 63) wsum[w] = inc;
        __syncthreads();
        int woff = 0;
        #pragma unroll
        for (int ww = 0; ww < 4; ++ww) if (ww < w) woff += wsum[ww];
        int ebase = carry + woff + inc - tot;
        if (i0 < nd)     { rowptr[i0] = ebase;          cursor[i0] = ebase; }
        if (i0 + 1 < nd) { rowptr[i0 + 1] = ebase + x0; cursor[i0 + 1] = ebase + x0; }
        if (i0 + 2 < nd) { rowptr[i0 + 2] = ebase + s1; cursor[i0 + 2] = ebase + s1; }
        if (i0 + 3 < nd) { rowptr[i0 + 3] = ebase + s2; cursor[i0 + 3] = ebase + s2; }
        carry += wsum[0] + wsum[1] + wsum[2] + wsum[3];
        __syncthreads();
    }
    if (t == 0) rowptr[nd] = carry;
}

// scatter: pack (src, sim) into one int2 in CSR order
__global__ void scatter6_kernel(GraphPtrs gp, int* __restrict__ cursor6,
                                int2* __restrict__ csr_es6)
{
    constexpr int doff[6] = {0, 10000, 30000, 35000, 55000, 60000};
    const int ei = blockIdx.y;
    int e = blockIdx.x * 256 + threadIdx.x;
    if (e < 100000) {
        int j = atomicAdd(&cursor6[doff[ei] + gp.dst[ei][e]], 1);
        int2 es; es.x = gp.src[ei][e]; es.y = __float_as_int(gp.sim[ei][e]);
        csr_es6[(size_t)ei * 100000 + j] = es;
    }
}

// ---------------- MFMA GEMM core, fp32 A (converted on the fly) ----------------
__device__ __forceinline__ void gemm_core(const float* __restrict__ A,
    const unsigned short* __restrict__ Wt, int M, int K, int bm, int bn,
    unsigned short* __restrict__ As, unsigned short* __restrict__ Bs, v4f acc[4][4])
{
    const int tid = threadIdx.x;
    const int sr = tid >> 1, sc = (tid & 1) * 16;
    const int arow = bm + sr;
    const bool aok = arow < M;
    const float* ap = A + (size_t)arow * K + sc;
    const unsigned short* bp = Wt + (size_t)(bn + sr) * K + sc;
    const int lane = tid & 63, w = tid >> 6, wr = w >> 1, wc = w & 1;
    const int l16 = lane & 15, lg = lane >> 4;
    const int abase = (wr * 64 + l16) * 32 + lg * 8;
    const int bbase = (wc * 64 + l16) * 32 + lg * 8;

    for (int k0 = 0; k0 < K; k0 += 32) {
        float4 a0 = {0,0,0,0}, a1 = a0, a2 = a0, a3 = a0;
        if (aok) {
            a0 = *(const float4*)(ap + k0);
            a1 = *(const float4*)(ap + k0 + 4);
            a2 = *(const float4*)(ap + k0 + 8);
            a3 = *(const float4*)(ap + k0 + 12);
        }
        uint4 b0 = *(const uint4*)(bp + k0);
        uint4 b1 = *(const uint4*)(bp + k0 + 8);

        if (k0) __syncthreads();

        uint4 w0, w1;
        w0.x = (unsigned int)f2bf(a0.x) | ((unsigned int)f2bf(a0.y) << 16);
        w0.y = (unsigned int)f2bf(a0.z) | ((unsigned int)f2bf(a0.w) << 16);
        w0.z = (unsigned int)f2bf(a1.x) | ((unsigned int)f2bf(a1.y) << 16);
        w0.w = (unsigned int)f2bf(a1.z) | ((unsigned int)f2bf(a1.w) << 16);
        w1.x = (unsigned int)f2bf(a2.x) | ((unsigned int)f2bf(a2.y) << 16);
        w1.y = (unsigned int)f2bf(a2.z) | ((unsigned int)f2bf(a2.w) << 16);
        w1.z = (unsigned int)f2bf(a3.x) | ((unsigned int)f2bf(a3.y) << 16);
        w1.w = (unsigned int)f2bf(a3.z) | ((unsigned int)f2bf(a3.w) << 16);
        *(uint4*)&As[sr * 32 + sc]     = w0;
        *(uint4*)&As[sr * 32 + sc + 8] = w1;
        *(uint4*)&Bs[sr * 32 + sc]     = b0;
        *(uint4*)&Bs[sr * 32 + sc + 8] = b1;
        __syncthreads();

        v8s af[4], bfr[4];
        #pragma unroll
        for (int f = 0; f < 4; ++f) af[f] = *(const v8s*)&As[abase + f * 512];
        #pragma unroll
        for (int f = 0; f < 4; ++f) bfr[f] = *(const v8s*)&Bs[bbase + f * 512];
        #pragma unroll
        for (int i = 0; i < 4; ++i)
            #pragma unroll
            for (int j = 0; j < 4; ++j)
                acc[i][j] = __builtin_amdgcn_mfma_f32_16x16x32_bf16(af[i], bfr[j], acc[i][j], 0, 0, 0);
    }
}

// ---------------- MFMA GEMM core, bf16 A ----------------
__device__ __forceinline__ void gemm_core_bf(const unsigned short* __restrict__ A,
    const unsigned short* __restrict__ Wt, int M, int K, int bm, int bn,
    unsigned short* __restrict__ As, unsigned short* __restrict__ Bs, v4f acc[4][4])
{
    const int tid = threadIdx.x;
    const int sr = tid >> 1, sc = (tid & 1) * 16;
    const int arow = bm + sr;
    const bool aok = arow < M;
    const unsigned short* ap = A + (size_t)arow * K + sc;
    const unsigned short* bp = Wt + (size_t)(bn + sr) * K + sc;
    const int lane = tid & 63, w = tid >> 6, wr = w >> 1, wc = w & 1;
    const int l16 = lane & 15, lg = lane >> 4;
    const int abase = (wr * 64 + l16) * 32 + lg * 8;
    const int bbase = (wc * 64 + l16) * 32 + lg * 8;

    for (int k0 = 0; k0 < K; k0 += 32) {
        uint4 a0 = {0,0,0,0}, a1 = a0;
        if (aok) {
            a0 = *(const uint4*)(ap + k0);
            a1 = *(const uint4*)(ap + k0 + 8);
        }
        uint4 b0 = *(const uint4*)(bp + k0);
        uint4 b1 = *(const uint4*)(bp + k0 + 8);

        if (k0) __syncthreads();

        *(uint4*)&As[sr * 32 + sc]     = a0;
        *(uint4*)&As[sr * 32 + sc + 8] = a1;
        *(uint4*)&Bs[sr * 32 + sc]     = b0;
        *(uint4*)&Bs[sr * 32 + sc + 8] = b1;
        __syncthreads();

        v8s af[4], bfr[4];
        #pragma unroll
        for (int f = 0; f < 4; ++f) af[f] = *(const v8s*)&As[abase + f * 512];
        #pragma unroll
        for (int f = 0; f < 4; ++f) bfr[f] = *(const v8s*)&Bs[bbase + f * 512];
        #pragma unroll
        for (int i = 0; i < 4; ++i)
            #pragma unroll
            for (int j = 0; j < 4; ++j)
                acc[i][j] = __builtin_amdgcn_mfma_f32_16x16x32_bf16(af[i], bfr[j], acc[i][j], 0, 0, 0);
    }
}

// ---- adapt: h[t] = feats[t] @ adapt_w[t] + adapt_b[t]  (bf16 out only) ----
__global__ __launch_bounds__(256)
void adapt_gemm3(Ptr3f A3, const unsigned short* __restrict__ Wt3,
                 const float* __restrict__ bias3, unsigned short* __restrict__ hbf)
{
    constexpr int Ms[3] = {20000, 10000, 5000};
    constexpr size_t hoff[3] = {0, 20000ull * 256, 30000ull * 256};
    const int z = blockIdx.z;
    const int M = Ms[z];
    const int bm = blockIdx.y * 128, bn = blockIdx.x * 128;
    if (bm >= M) return;
    __shared__ unsigned short As[128 * 32], Bs[128 * 32];
    v4f acc[4][4] = {};
    gemm_core(A3.p[z], Wt3 + (size_t)z * 256 * 512, M, 512, bm, bn, As, Bs, acc);

    const int lane = threadIdx.x & 63, w = threadIdx.x >> 6;
    const int wr = w >> 1, wc = w & 1, l16 = lane & 15, lg = lane >> 4;
    const int row0 = bm + wr * 64, col0 = bn + wc * 64;
    const float* bias = bias3 + z * 256;
    unsigned short* Cb = hbf + hoff[z];
    float bv[4];
    #pragma unroll
    for (int fn = 0; fn < 4; ++fn) bv[fn] = bias[col0 + fn * 16 + l16];
    #pragma unroll
    for (int fm = 0; fm < 4; ++fm)
        #pragma unroll
        for (int i = 0; i < 4; ++i) {
            int gm = row0 + fm * 16 + lg * 4 + i;
            if (gm >= M) continue;
            #pragma unroll
            for (int fn = 0; fn < 4; ++fn)
                Cb[(size_t)gm * 256 + col0 + fn * 16 + l16] = f2bf(acc[fm][fn][i] + bv[fn]);
        }
}

// ---- qkv: row layout (1024 B/node): q 256xbf16 | kv 512B lane-interleaved fp8 ----
__global__ __launch_bounds__(256)
void qkv_gemm3(const unsigned short* __restrict__ hbf, const unsigned short* __restrict__ W3l,
               const float* __restrict__ bias768l, unsigned char* __restrict__ qkvb)
{
    constexpr int Ms[3] = {20000, 10000, 5000};
    constexpr size_t hoff[3] = {0, 20000ull * 256, 30000ull * 256};
    constexpr size_t qoffB[3] = {0, 20000ull * 1024, 30000ull * 1024};
    const int z = blockIdx.z;
    const int M = Ms[z];
    const int bm = blockIdx.y * 128, bn = blockIdx.x * 128;
    if (bm >= M) return;
    __shared__ unsigned short As[128 * 32], Bs[128 * 32];
    v4f acc[4][4] = {};
    gemm_core_bf(hbf + hoff[z], W3l + (size_t)z * 768 * 256, M, 256, bm, bn, As, Bs, acc);

    const int lane = threadIdx.x & 63, w = threadIdx.x >> 6;
    const int wr = w >> 1, wc = w & 1, l16 = lane & 15, lg = lane >> 4;
    const int row0 = bm + wr * 64, col0 = bn + wc * 64;
    const float* bias = bias768l + z * 768;
    unsigned char* base = qkvb + qoffB[z];
    float bv[4];
    #pragma unroll
    for (int fn = 0; fn < 4; ++fn) bv[fn] = bias[col0 + fn * 16 + l16];
    #pragma unroll
    for (int fm = 0; fm < 4; ++fm)
        #pragma unroll
        for (int i = 0; i < 4; ++i) {
            int gm = row0 + fm * 16 + lg * 4 + i;
            if (gm >= M) continue;
            #pragma unroll
            for (int fn = 0; fn < 4; ++fn) {
                int c = col0 + fn * 16 + l16;
                float val = acc[fm][fn][i] + bv[fn];
                unsigned char* rowp = base + (size_t)gm * 1024;
                if (c < 256) {
                    *(unsigned short*)(rowp + 2 * c) = f2bf(val);
                } else if (c < 512) {
                    int j = c - 256;
                    rowp[512 + 8 * (j >> 2) + (j & 3)] = f2fp8(val);
                } else {
                    int j = c - 512;
                    rowp[512 + 8 * (j >> 2) + 4 + (j & 3)] = f2fp8(val);
                }
            }
        }
}

// ---- a: h[t] = blend(0.5*agg[t]@a_w[l,t] + a_b[l,t], h[t])  (bf16 h in/out) ----
__global__ __launch_bounds__(256)
void a_gemm3(const unsigned short* __restrict__ aggbf, const unsigned short* __restrict__ Wtl,
             const float* __restrict__ biasl, const float* __restrict__ skipl,
             unsigned short* __restrict__ hbf)
{
    constexpr int Ms[3] = {20000, 10000, 5000};
    constexpr size_t hoff[3] = {0, 20000ull * 256, 30000ull * 256};
    const int z = blockIdx.z;
    const int M = Ms[z];
    const int bm = blockIdx.y * 128, bn = blockIdx.x * 128;
    if (bm >= M) return;
    __shared__ unsigned short As[128 * 32], Bs[128 * 32];
    v4f acc[4][4] = {};
    gemm_core_bf(aggbf + hoff[z], Wtl + (size_t)z * 65536, M, 256, bm, bn, As, Bs, acc);

    const int lane = threadIdx.x & 63, w = threadIdx.x >> 6;
    const int wr = w >> 1, wc = w & 1, l16 = lane & 15, lg = lane >> 4;
    const int row0 = bm + wr * 64, col0 = bn + wc * 64;
    const float* bias = biasl + z * 256;
    unsigned short* Cb = hbf + hoff[z];
    float sv = skipl[z];
    float alpha = 1.0f / (1.0f + expf(-sv));
    float beta = 1.0f - alpha;
    float bv[4];
    #pragma unroll
    for (int fn = 0; fn < 4; ++fn) bv[fn] = bias[col0 + fn * 16 + l16];
    #pragma unroll
    for (int fm = 0; fm < 4; ++fm)
        #pragma unroll
        for (int i = 0; i < 4; ++i) {
            int gm = row0 + fm * 16 + lg * 4 + i;
            if (gm >= M) continue;
            #pragma unroll
            for (int fn = 0; fn < 4; ++fn) {
                size_t idx = (size_t)gm * 256 + col0 + fn * 16 + l16;
                float val = acc[fm][fn][i] * 0.5f + bv[fn];
                val = alpha * val + beta * bf2f(Cb[idx]);
                Cb[idx] = f2bf(val);
            }
        }
}

// ---- final: out = feats[0] @ head_w + cvec  (plain bf16 MFMA) ----
__global__ __launch_bounds__(256)
void head_gemm(const float* __restrict__ A, const unsigned short* __restrict__ Wt,
               const float* __restrict__ bias, float* __restrict__ C)
{
    const int M = 20000, N = 512, K = 512;
    const int bm = blockIdx.y * 128, bn = blockIdx.x * 128;
    if (bm >= M) return;
    __shared__ unsigned short As[128 * 32], Bs[128 * 32];
    v4f acc[4][4] = {};
    gemm_core(A, Wt, M, K, bm, bn, As, Bs, acc);

    const int lane = threadIdx.x & 63, w = threadIdx.x >> 6;
    const int wr = w >> 1, wc = w & 1, l16 = lane & 15, lg = lane >> 4;
    const int row0 = bm + wr * 64, col0 = bn + wc * 64;
    float bv[4];
    #pragma unroll
    for (int fn = 0; fn < 4; ++fn) bv[fn] = bias[col0 + fn * 16 + l16];
    #pragma unroll
    for (int fm = 0; fm < 4; ++fm)
        #pragma unroll
        for (int i = 0; i < 4; ++i) {
            int gm = row0 + fm * 16 + lg * 4 + i;
            if (gm >= M) continue;
            #pragma unroll
            for (int fn = 0; fn < 4; ++fn)
                C[(size_t)gm * N + col0 + fn * 16 + l16] = acc[fm][fn][i] + bv[fn];
        }
}

// ---------------- fused attention: dual-relation interleaved, fp8 kv, exp2 softmax ----------------
__global__ __launch_bounds__(256)
void attn_fused_kernel(const unsigned char* __restrict__ qkvb,
                       const int* __restrict__ rp6, const int2* __restrict__ csr_es6,
                       const float* __restrict__ ewp, const float* __restrict__ ebp,
                       unsigned short* __restrict__ aggbf)
{
    constexpr size_t qoffB[3] = {0, 20000ull * 1024, 30000ull * 1024};
    constexpr size_t aoffE[3] = {0, 20000ull * 256, 30000ull * 256};
    constexpr int rpoff[6] = {0, 10001, 30002, 35003, 55004, 60005};
    constexpr int eAz[3] = {1, 0, 2}, eBz[3] = {3, 5, 4};    // incoming etypes per dst type
    constexpr int sAz[3] = {1, 0, 0}, sBz[3] = {2, 2, 1};    // their src node types

    const int gid = blockIdx.x * 4 + (threadIdx.x >> 6);     // 0..34999
    const int z = (gid < 20000) ? 0 : (gid < 30000 ? 1 : 2);
    const int d = gid - (z == 0 ? 0 : (z == 1 ? 20000 : 30000));
    const int t = threadIdx.x & 63;
    // fold 1/sqrt(32) * log2(e) into the edge-linear coefficients (exp2-domain softmax)
    const float kfold = 0.17677669529663687f * 1.4426950408889634f;
    const float ewv = ewp[0] * kfold, ebv = ebp[0] * kfold;

    u16x4 q4 = *(const u16x4*)(qkvb + qoffB[z] + (size_t)d * 1024 + 8 * t);
    const float qx0 = bf2f(q4[0]), qx1 = bf2f(q4[1]), qx2 = bf2f(q4[2]), qx3 = bf2f(q4[3]);

    const int eiA = eAz[z], eiB = eBz[z];
    const int2* esA = csr_es6 + (size_t)eiA * 100000;
    const int2* esB = csr_es6 + (size_t)eiB * 100000;
    const unsigned char* kvAp = qkvb + qoffB[sAz[z]] + 512 + 8 * t;
    const unsigned char* kvBp = qkvb + qoffB[sBz[z]] + 512 + 8 * t;
    const int begA = rp6[rpoff[eiA] + d], endA = rp6[rpoff[eiA] + d + 1];
    const int begB = rp6[rpoff[eiB] + d], endB = rp6[rpoff[eiB] + d + 1];
    const int nA = endA - begA, nB = endB - begB;

    float mA = -INFINITY, sA = 0.0f, mB = -INFINITY, sB = 0.0f;
    float4 accA = {0.f,0.f,0.f,0.f}, accB = {0.f,0.f,0.f,0.f};

    uint2 kvA0 = {0,0}, kvA1 = {0,0}, kvB0 = {0,0}, kvB1 = {0,0};
    float simA0 = 0.f, simA1 = 0.f, simB0 = 0.f, simB1 = 0.f;
    if (nA > 0) { int2 e = esA[begA];     simA0 = __int_as_float(e.y); kvA0 = *(const uint2*)(kvAp + (size_t)e.x * 1024); }
    if (nA > 1) { int2 e = esA[begA + 1]; simA1 = __int_as_float(e.y); kvA1 = *(const uint2*)(kvAp + (size_t)e.x * 1024); }
    if (nB > 0) { int2 e = esB[begB];     simB0 = __int_as_float(e.y); kvB0 = *(const uint2*)(kvBp + (size_t)e.x * 1024); }
    if (nB > 1) { int2 e = esB[begB + 1]; simB1 = __int_as_float(e.y); kvB1 = *(const uint2*)(kvBp + (size_t)e.x * 1024); }

    const int n = nA > nB ? nA : nB;
    for (int j = 0; j < n; ++j) {
        uint2 cA = kvA0; float fA = simA0; kvA0 = kvA1; simA0 = simA1;
        uint2 cB = kvB0; float fB = simB0; kvB0 = kvB1; simB0 = simB1;
        if (j + 2 < nA) { int2 e = esA[begA + j + 2]; simA1 = __int_as_float(e.y); kvA1 = *(const uint2*)(kvAp + (size_t)e.x * 1024); }
        if (j + 2 < nB) { int2 e = esB[begB + j + 2]; simB1 = __int_as_float(e.y); kvB1 = *(const uint2*)(kvBp + (size_t)e.x * 1024); }
        if (j < nA) {
            v2f k01 = __builtin_amdgcn_cvt_pk_f32_fp8((int)cA.x, false);
            v2f k23 = __builtin_amdgcn_cvt_pk_f32_fp8((int)cA.x, true);
            float dot = qx0 * k01[0] + qx1 * k01[1] + qx2 * k23[0] + qx3 * k23[1];
            dot += __shfl_xor(dot, 1);
            dot += __shfl_xor(dot, 2);
            dot += __shfl_xor(dot, 4);
            float sc = dot * fmaf(fA, ewv, ebv);
            if (sc > mA) {
                float r = exp2f(mA - sc);
                sA *= r; accA.x *= r; accA.y *= r; accA.z *= r; accA.w *= r;
                mA = sc;
            }
            float ex = exp2f(sc - mA);
            sA += ex;
            v2f v01 = __builtin_amdgcn_cvt_pk_f32_fp8((int)cA.y, false);
            v2f v23 = __builtin_amdgcn_cvt_pk_f32_fp8((int)cA.y, true);
            accA.x += ex * v01[0]; accA.y += ex * v01[1];
            accA.z += ex * v23[0]; accA.w += ex * v23[1];
        }
        if (j < nB) {
            v2f k01 = __builtin_amdgcn_cvt_pk_f32_fp8((int)cB.x, false);
            v2f k23 = __builtin_amdgcn_cvt_pk_f32_fp8((int)cB.x, true);
            float dot = qx0 * k01[0] + qx1 * k01[1] + qx2 * k23[0] + qx3 * k23[1];
            dot += __shfl_xor(dot, 1);
            dot += __shfl_xor(dot, 2);
            dot += __shfl_xor(dot, 4);
            float sc = dot * fmaf(fB, ewv, ebv);
            if (sc > mB) {
                float r = exp2f(mB - sc);
                sB *= r; accB.x *= r; accB.y *= r; accB.z *= r; accB.w *= r;
                mB = sc;
            }
            float ex = exp2f(sc - mB);
            sB += ex;
            v2f v01 = __builtin_amdgcn_cvt_pk_f32_fp8((int)cB.y, false);
            v2f v23 = __builtin_amdgcn_cvt_pk_f32_fp8((int)cB.y, true);
            accB.x += ex * v01[0]; accB.y += ex * v01[1];
            accB.z += ex * v23[0]; accB.w += ex * v23[1];
        }
    }
    float invA = (nA > 0) ? 1.0f / sA : 0.0f;
    float invB = (nB > 0) ? 1.0f / sB : 0.0f;
    u16x4 out;
    out[0] = f2bf(accA.x * invA + accB.x * invB);
    out[1] = f2bf(accA.y * invA + accB.y * invB);
    out[2] = f2bf(accA.z * invA + accB.z * invB);
    out[3] = f2bf(accA.w * invA + accB.w * invB);
    *(u16x4*)(aggbf + aoffE[z] + (size_t)d * 256 + 4 * t) = out;
}

__global__ void colsum_kernel(const unsigned short* __restrict__ hbf, float* __restrict__ out, int N)
{
    int c = threadIdx.x;
    float acc = 0.0f;
    for (int r = blockIdx.x; r < N; r += gridDim.x)
        acc += bf2f(hbf[(size_t)r * 256 + c]);
    atomicAdd(&out[c], acc);
}

__global__ __launch_bounds__(512)
void head_kernel(const float* __restrict__ colsum, float n_img,
                 const float* __restrict__ pred_w, const float* __restrict__ pred_b,
                 const float* __restrict__ head1_w, const float* __restrict__ head1_b,
                 const float* __restrict__ head_w, const float* __restrict__ head_b,
                 float* __restrict__ cvec)
{
    __shared__ float mean[256], o0[256], g[512];
    int t = threadIdx.x;
    if (t < 256) mean[t] = colsum[t] / n_img;
    __syncthreads();
    if (t < 256) {
        float acc = pred_b[t];
        for (int k = 0; k < 256; ++k) acc += mean[k] * pred_w[k * 256 + t];
        o0[t] = acc;
    }
    __syncthreads();
    {
        float acc = head1_b[t];
        for (int k = 0; k < 256; ++k) acc += o0[k] * head1_w[k * 512 + t];
        g[t] = acc;
    }
    __syncthreads();
    {
        float acc = head_b[t];
        for (int k = 0; k < 512; ++k) acc += g[k] * head_w[k * 512 + t];
        cvec[t] = acc;
    }
}

extern "C" void kernel_launch(void* const* d_in, const int* in_sizes, int n_in,
                              void* d_out, int out_size, void* d_ws, size_t ws_size,
                              hipStream_t stream)
{
    const int NI = 20000, E = 100000;

    const float* feat[3] = {(const float*)d_in[0], (const float*)d_in[1], (const float*)d_in[2]};
    const float* adapt_w = (const float*)d_in[3];
    const float* adapt_b = (const float*)d_in[4];
    const float* k_w = (const float*)d_in[5];
    const float* k_b = (const float*)d_in[6];
    const float* q_w = (const float*)d_in[7];
    const float* q_b = (const float*)d_in[8];
    const float* v_w = (const float*)d_in[9];
    const float* v_b = (const float*)d_in[10];
    const float* a_w = (const float*)d_in[11];
    const float* a_b = (const float*)d_in[12];
    const float* e_w = (const float*)d_in[13];
    const float* e_b = (const float*)d_in[14];
    const float* skip = (const float*)d_in[15];
    const float* pred_w = (const float*)d_in[16];
    const float* pred_b = (const float*)d_in[17];
    const float* head1_w = (const float*)d_in[19];
    const float* head1_b = (const float*)d_in[20];
    const float* head_w = (const float*)d_in[21];
    const float* head_b = (const float*)d_in[22];

    GraphPtrs gp;
    for (int i = 0; i < 6; ++i) {
        gp.sim[i] = (const float*)d_in[23 + i];
        gp.src[i] = (const int*)d_in[29 + 2 * i];
        gp.dst[i] = (const int*)d_in[30 + 2 * i];
    }

    float* ws = (float*)d_ws;
    size_t off = 0;
    auto alloc = [&](size_t n) { float* p = ws + off; off += (n + 3) & ~(size_t)3; return p; };
    const size_t NTOT = 35000ull * 256;
    unsigned short* hbf   = (unsigned short*)alloc(NTOT / 2);
    unsigned short* aggbf = (unsigned short*)alloc(NTOT / 2);
    unsigned char* qkvb   = (unsigned char*)alloc(35000ull * 256);   // 1024 B per node
    float* csum = alloc(256);
    float* cvec = alloc(512);
    int* deg6    = (int*)alloc(70000);
    int* cursor6 = (int*)alloc(70000);
    int* rp6     = (int*)alloc(70012);
    int2* csr_es6 = (int2*)alloc(1200000);
    unsigned short* adapt_wt = (unsigned short*)alloc(3 * 512 * 256 / 2);
    unsigned short* W3   = (unsigned short*)alloc(6ull * 768 * 256 / 2);  // [lt][768][256]
    unsigned short* a_wt = (unsigned short*)alloc(6 * 65536 / 2);
    float* bias768 = alloc(6 * 768);
    unsigned short* head_wt = (unsigned short*)alloc(512 * 512 / 2);

    // ---- CSR build: 4 dispatches for all 6 etypes ----
    hipMemsetAsync(deg6, 0, 70000 * sizeof(int), stream);
    hipLaunchKernelGGL(hist6_kernel, dim3((E + 255) / 256, 6), dim3(256), 0, stream, gp, deg6);
    hipLaunchKernelGGL(scan6_kernel, dim3(6), dim3(256), 0, stream, deg6, rp6, cursor6);
    hipLaunchKernelGGL(scatter6_kernel, dim3((E + 255) / 256, 6), dim3(256), 0, stream,
                       gp, cursor6, csr_es6);

    // ---- weights -> bf16 ----
    hipLaunchKernelGGL(wcvt_kernel, dim3(16, 8, 3), dim3(256), 0, stream, adapt_w, adapt_wt, 512, 256);
    hipLaunchKernelGGL(wcvt_qkv_kernel, dim3(8, 8, 18), dim3(256), 0, stream, q_w, k_w, v_w, W3);
    hipLaunchKernelGGL(wcvt_kernel, dim3(8, 8, 6), dim3(256), 0, stream, a_w, a_wt, 256, 256);
    hipLaunchKernelGGL(wcvt_kernel, dim3(16, 16, 1), dim3(256), 0, stream, head_w, head_wt, 512, 512);
    hipLaunchKernelGGL(bias_concat_kernel, dim3(18), dim3(256), 0, stream, q_b, k_b, v_b, bias768);

    // ---- adapt (all 3 types in one dispatch) ----
    Ptr3f fa; fa.p[0] = feat[0]; fa.p[1] = feat[1]; fa.p[2] = feat[2];
    hipLaunchKernelGGL(adapt_gemm3, dim3(2, 157, 3), dim3(256), 0, stream, fa, adapt_wt, adapt_b, hbf);

    for (int l = 0; l < 2; ++l) {
        hipLaunchKernelGGL(qkv_gemm3, dim3(6, 157, 3), dim3(256), 0, stream,
                           hbf, W3 + (size_t)l * 3 * 768 * 256, bias768 + (size_t)l * 3 * 768, qkvb);
        hipLaunchKernelGGL(attn_fused_kernel, dim3(8750), dim3(256), 0, stream,
                           qkvb, rp6, csr_es6, e_w + l, e_b + l, aggbf);
        hipLaunchKernelGGL(a_gemm3, dim3(2, 157, 3), dim3(256), 0, stream,
                           aggbf, a_wt + (size_t)l * 3 * 65536, a_b + (size_t)l * 3 * 256,
                           skip + l * 3, hbf);
    }

    hipMemsetAsync(csum, 0, 256 * sizeof(float), stream);
    hipLaunchKernelGGL(colsum_kernel, dim3(128), dim3(256), 0, stream, hbf, csum, NI);
    hipLaunchKernelGGL(head_kernel, dim3(1), dim3(512), 0, stream,
                       csum, (float)NI, pred_w, pred_b, head1_w, head1_b, head_w, head_b, cvec);

    // out = feats[0] @ head_w + cvec  (plain bf16 MFMA)
    hipLaunchKernelGGL(head_gemm, dim3(4, 157), dim3(256), 0, stream,
                       feat[0], head_wt, cvec, (float*)d_out);
}

// Round 8
// 590.317 us; speedup vs baseline: 1.0040x; 1.0040x over previous
//
#include <hip/hip_runtime.h>
#include <hip/hip_bf16.h>
#include <math.h>

typedef short v8s __attribute__((ext_vector_type(8)));
typedef float v4f __attribute__((ext_vector_type(4)));
typedef float v2f __attribute__((ext_vector_type(2)));
typedef unsigned short u16x4 __attribute__((ext_vector_type(4)));

__device__ __forceinline__ unsigned short f2bf(float f) {
    unsigned int u = __float_as_uint(f);
    u += 0x7fff + ((u >> 16) & 1);   // round-to-nearest-even
    return (unsigned short)(u >> 16);
}
__device__ __forceinline__ float bf2f(unsigned short h) {
    return __uint_as_float(((unsigned int)h) << 16);
}
__device__ __forceinline__ unsigned char f2fp8(float f) {
    int e = __builtin_amdgcn_cvt_pk_fp8_f32(f, f, 0, false);
    return (unsigned char)(e & 0xff);
}

struct GraphPtrs { const int* dst[6]; const int* src[6]; const float* sim[6]; };
struct Ptr3f { const float* p[3]; };

// ---------------- weight transpose + convert: W[K][N] fp32 -> Wt[N][K] bf16 ----------------
__global__ __launch_bounds__(256)
void wcvt_kernel(const float* __restrict__ W, unsigned short* __restrict__ Wt, int K, int N)
{
    __shared__ float tile[32][33];
    const int b = blockIdx.z;
    const float* Wb = W + (size_t)b * K * N;
    unsigned short* Wtb = Wt + (size_t)b * K * N;
    const int k0 = blockIdx.x * 32, n0 = blockIdx.y * 32;
    const int x = threadIdx.x & 31, y = threadIdx.x >> 5;
    #pragma unroll
    for (int j = 0; j < 4; ++j)
        tile[y + 8 * j][x] = Wb[(size_t)(k0 + y + 8 * j) * N + n0 + x];
    __syncthreads();
    #pragma unroll
    for (int j = 0; j < 4; ++j)
        Wtb[(size_t)(n0 + y + 8 * j) * K + k0 + x] = f2bf(tile[x][y + 8 * j]);
}

// q/k/v weights -> W3[(l,t)][768][256] (rows 0-255 q, 256-511 k, 512-767 v)
__global__ __launch_bounds__(256)
void wcvt_qkv_kernel(const float* __restrict__ qw, const float* __restrict__ kw,
                     const float* __restrict__ vw, unsigned short* __restrict__ W3)
{
    __shared__ float tile[32][33];
    const int z = blockIdx.z, lt = z / 3, sec = z - lt * 3;
    const float* src = (sec == 0 ? qw : sec == 1 ? kw : vw) + (size_t)lt * 65536;
    unsigned short* dst = W3 + ((size_t)lt * 768 + sec * 256) * 256;
    const int k0 = blockIdx.x * 32, n0 = blockIdx.y * 32;
    const int x = threadIdx.x & 31, y = threadIdx.x >> 5;
    #pragma unroll
    for (int j = 0; j < 4; ++j)
        tile[y + 8 * j][x] = src[(size_t)(k0 + y + 8 * j) * 256 + n0 + x];
    __syncthreads();
    #pragma unroll
    for (int j = 0; j < 4; ++j)
        dst[(size_t)(n0 + y + 8 * j) * 256 + k0 + x] = f2bf(tile[x][y + 8 * j]);
}

// bias768[lt][768] = concat(q_b[lt], k_b[lt], v_b[lt])
__global__ void bias_concat_kernel(const float* __restrict__ qb, const float* __restrict__ kb,
                                   const float* __restrict__ vb, float* __restrict__ out)
{
    int i = blockIdx.x * 256 + threadIdx.x;
    if (i < 6 * 768) {
        int lt = i / 768, c = i - lt * 768;
        int sec = c >> 8, cc = c & 255;
        const float* s = sec == 0 ? qb : sec == 1 ? kb : vb;
        out[i] = s[lt * 256 + cc];
    }
}

// ---------------- CSR build (all 6 etypes fused) ----------------
__global__ void hist6_kernel(GraphPtrs gp, int* __restrict__ deg6)
{
    constexpr int doff[6] = {0, 10000, 30000, 35000, 55000, 60000};
    const int ei = blockIdx.y;
    int e = blockIdx.x * 256 + threadIdx.x;
    if (e < 100000) atomicAdd(&deg6[doff[ei] + gp.dst[ei][e]], 1);
}

__global__ __launch_bounds__(256)
void scan6_kernel(const int* __restrict__ deg6, int* __restrict__ rp6, int* __restrict__ cursor6)
{
    constexpr int ndv[6]   = {10000, 20000, 5000, 20000, 5000, 10000};
    constexpr int doff[6]  = {0, 10000, 30000, 35000, 55000, 60000};
    constexpr int rpoff[6] = {0, 10001, 30002, 35003, 55004, 60005};
    const int b = blockIdx.x;
    const int nd = ndv[b];
    const int* deg = deg6 + doff[b];
    int* rowptr = rp6 + rpoff[b];
    int* cursor = cursor6 + doff[b];
    const int t = threadIdx.x, lane = t & 63, w = t >> 6;
    __shared__ int wsum[4];
    int carry = 0;
    for (int base = 0; base < nd; base += 1024) {
        int i0 = base + t * 4;
        int x0 = 0, x1 = 0, x2 = 0, x3 = 0;
        if (i0 + 3 < nd) {
            int4 v = *(const int4*)(deg + i0);
            x0 = v.x; x1 = v.y; x2 = v.z; x3 = v.w;
        } else {
            if (i0 < nd) x0 = deg[i0];
            if (i0 + 1 < nd) x1 = deg[i0 + 1];
            if (i0 + 2 < nd) x2 = deg[i0 + 2];
            if (i0 + 3 < nd) x3 = deg[i0 + 3];
        }
        int s1 = x0 + x1, s2 = s1 + x2, tot = s2 + x3;
        int inc = tot;
        #pragma unroll
        for (int o = 1; o < 64; o <<= 1) {
            int y = __shfl_up(inc, o, 64);
            if (lane >= o) inc += y;
        }
        if (lane == 63) wsum[w] = inc;
        __syncthreads();
        int woff = 0;
        #pragma unroll
        for (int ww = 0; ww < 4; ++ww) if (ww < w) woff += wsum[ww];
        int ebase = carry + woff + inc - tot;
        if (i0 < nd)     { rowptr[i0] = ebase;          cursor[i0] = ebase; }
        if (i0 + 1 < nd) { rowptr[i0 + 1] = ebase + x0; cursor[i0 + 1] = ebase + x0; }
        if (i0 + 2 < nd) { rowptr[i0 + 2] = ebase + s1; cursor[i0 + 2] = ebase + s1; }
        if (i0 + 3 < nd) { rowptr[i0 + 3] = ebase + s2; cursor[i0 + 3] = ebase + s2; }
        carry += wsum[0] + wsum[1] + wsum[2] + wsum[3];
        __syncthreads();
    }
    if (t == 0) rowptr[nd] = carry;
}

// scatter: pack (src, sim) into one int2 in CSR order
__global__ void scatter6_kernel(GraphPtrs gp, int* __restrict__ cursor6,
                                int2* __restrict__ csr_es6)
{
    constexpr int doff[6] = {0, 10000, 30000, 35000, 55000, 60000};
    const int ei = blockIdx.y;
    int e = blockIdx.x * 256 + threadIdx.x;
    if (e < 100000) {
        int j = atomicAdd(&cursor6[doff[ei] + gp.dst[ei][e]], 1);
        int2 es; es.x = gp.src[ei][e]; es.y = __float_as_int(gp.sim[ei][e]);
        csr_es6[(size_t)ei * 100000 + j] = es;
    }
}

// ---------------- MFMA GEMM core, fp32 A (converted on the fly) ----------------
__device__ __forceinline__ void gemm_core(const float* __restrict__ A,
    const unsigned short* __restrict__ Wt, int M, int K, int bm, int bn,
    unsigned short* __restrict__ As, unsigned short* __restrict__ Bs, v4f acc[4][4])
{
    const int tid = threadIdx.x;
    const int sr = tid >> 1, sc = (tid & 1) * 16;
    const int arow = bm + sr;
    const bool aok = arow < M;
    const float* ap = A + (size_t)arow * K + sc;
    const unsigned short* bp = Wt + (size_t)(bn + sr) * K + sc;
    const int lane = tid & 63, w = tid >> 6, wr = w >> 1, wc = w & 1;
    const int l16 = lane & 15, lg = lane >> 4;
    const int abase = (wr * 64 + l16) * 32 + lg * 8;
    const int bbase = (wc * 64 + l16) * 32 + lg * 8;

    for (int k0 = 0; k0 < K; k0 += 32) {
        float4 a0 = {0,0,0,0}, a1 = a0, a2 = a0, a3 = a0;
        if (aok) {
            a0 = *(const float4*)(ap + k0);
            a1 = *(const float4*)(ap + k0 + 4);
            a2 = *(const float4*)(ap + k0 + 8);
            a3 = *(const float4*)(ap + k0 + 12);
        }
        uint4 b0 = *(const uint4*)(bp + k0);
        uint4 b1 = *(const uint4*)(bp + k0 + 8);

        if (k0) __syncthreads();

        uint4 w0, w1;
        w0.x = (unsigned int)f2bf(a0.x) | ((unsigned int)f2bf(a0.y) << 16);
        w0.y = (unsigned int)f2bf(a0.z) | ((unsigned int)f2bf(a0.w) << 16);
        w0.z = (unsigned int)f2bf(a1.x) | ((unsigned int)f2bf(a1.y) << 16);
        w0.w = (unsigned int)f2bf(a1.z) | ((unsigned int)f2bf(a1.w) << 16);
        w1.x = (unsigned int)f2bf(a2.x) | ((unsigned int)f2bf(a2.y) << 16);
        w1.y = (unsigned int)f2bf(a2.z) | ((unsigned int)f2bf(a2.w) << 16);
        w1.z = (unsigned int)f2bf(a3.x) | ((unsigned int)f2bf(a3.y) << 16);
        w1.w = (unsigned int)f2bf(a3.z) | ((unsigned int)f2bf(a3.w) << 16);
        *(uint4*)&As[sr * 32 + sc]     = w0;
        *(uint4*)&As[sr * 32 + sc + 8] = w1;
        *(uint4*)&Bs[sr * 32 + sc]     = b0;
        *(uint4*)&Bs[sr * 32 + sc + 8] = b1;
        __syncthreads();

        v8s af[4], bfr[4];
        #pragma unroll
        for (int f = 0; f < 4; ++f) af[f] = *(const v8s*)&As[abase + f * 512];
        #pragma unroll
        for (int f = 0; f < 4; ++f) bfr[f] = *(const v8s*)&Bs[bbase + f * 512];
        #pragma unroll
        for (int i = 0; i < 4; ++i)
            #pragma unroll
            for (int j = 0; j < 4; ++j)
                acc[i][j] = __builtin_amdgcn_mfma_f32_16x16x32_bf16(af[i], bfr[j], acc[i][j], 0, 0, 0);
    }
}

// ---------------- MFMA GEMM core, bf16 A ----------------
__device__ __forceinline__ void gemm_core_bf(const unsigned short* __restrict__ A,
    const unsigned short* __restrict__ Wt, int M, int K, int bm, int bn,
    unsigned short* __restrict__ As, unsigned short* __restrict__ Bs, v4f acc[4][4])
{
    const int tid = threadIdx.x;
    const int sr = tid >> 1, sc = (tid & 1) * 16;
    const int arow = bm + sr;
    const bool aok = arow < M;
    const unsigned short* ap = A + (size_t)arow * K + sc;
    const unsigned short* bp = Wt + (size_t)(bn + sr) * K + sc;
    const int lane = tid & 63, w = tid >> 6, wr = w >> 1, wc = w & 1;
    const int l16 = lane & 15, lg = lane >> 4;
    const int abase = (wr * 64 + l16) * 32 + lg * 8;
    const int bbase = (wc * 64 + l16) * 32 + lg * 8;

    for (int k0 = 0; k0 < K; k0 += 32) {
        uint4 a0 = {0,0,0,0}, a1 = a0;
        if (aok) {
            a0 = *(const uint4*)(ap + k0);
            a1 = *(const uint4*)(ap + k0 + 8);
        }
        uint4 b0 = *(const uint4*)(bp + k0);
        uint4 b1 = *(const uint4*)(bp + k0 + 8);

        if (k0) __syncthreads();

        *(uint4*)&As[sr * 32 + sc]     = a0;
        *(uint4*)&As[sr * 32 + sc + 8] = a1;
        *(uint4*)&Bs[sr * 32 + sc]     = b0;
        *(uint4*)&Bs[sr * 32 + sc + 8] = b1;
        __syncthreads();

        v8s af[4], bfr[4];
        #pragma unroll
        for (int f = 0; f < 4; ++f) af[f] = *(const v8s*)&As[abase + f * 512];
        #pragma unroll
        for (int f = 0; f < 4; ++f) bfr[f] = *(const v8s*)&Bs[bbase + f * 512];
        #pragma unroll
        for (int i = 0; i < 4; ++i)
            #pragma unroll
            for (int j = 0; j < 4; ++j)
                acc[i][j] = __builtin_amdgcn_mfma_f32_16x16x32_bf16(af[i], bfr[j], acc[i][j], 0, 0, 0);
    }
}

// ---- adapt: h[t] = feats[t] @ adapt_w[t] + adapt_b[t]  (bf16 out only) ----
__global__ __launch_bounds__(256)
void adapt_gemm3(Ptr3f A3, const unsigned short* __restrict__ Wt3,
                 const float* __restrict__ bias3, unsigned short* __restrict__ hbf)
{
    constexpr int Ms[3] = {20000, 10000, 5000};
    constexpr size_t hoff[3] = {0, 20000ull * 256, 30000ull * 256};
    const int z = blockIdx.z;
    const int M = Ms[z];
    const int bm = blockIdx.y * 128, bn = blockIdx.x * 128;
    if (bm >= M) return;
    __shared__ unsigned short As[128 * 32], Bs[128 * 32];
    v4f acc[4][4] = {};
    gemm_core(A3.p[z], Wt3 + (size_t)z * 256 * 512, M, 512, bm, bn, As, Bs, acc);

    const int lane = threadIdx.x & 63, w = threadIdx.x >> 6;
    const int wr = w >> 1, wc = w & 1, l16 = lane & 15, lg = lane >> 4;
    const int row0 = bm + wr * 64, col0 = bn + wc * 64;
    const float* bias = bias3 + z * 256;
    unsigned short* Cb = hbf + hoff[z];
    float bv[4];
    #pragma unroll
    for (int fn = 0; fn < 4; ++fn) bv[fn] = bias[col0 + fn * 16 + l16];
    #pragma unroll
    for (int fm = 0; fm < 4; ++fm)
        #pragma unroll
        for (int i = 0; i < 4; ++i) {
            int gm = row0 + fm * 16 + lg * 4 + i;
            if (gm >= M) continue;
            #pragma unroll
            for (int fn = 0; fn < 4; ++fn)
                Cb[(size_t)gm * 256 + col0 + fn * 16 + l16] = f2bf(acc[fm][fn][i] + bv[fn]);
        }
}

// ---- qkv: row layout (1024 B/node): q 256xbf16 | kv 512B lane-interleaved fp8 ----
__global__ __launch_bounds__(256)
void qkv_gemm3(const unsigned short* __restrict__ hbf, const unsigned short* __restrict__ W3l,
               const float* __restrict__ bias768l, unsigned char* __restrict__ qkvb)
{
    constexpr int Ms[3] = {20000, 10000, 5000};
    constexpr size_t hoff[3] = {0, 20000ull * 256, 30000ull * 256};
    constexpr size_t qoffB[3] = {0, 20000ull * 1024, 30000ull * 1024};
    const int z = blockIdx.z;
    const int M = Ms[z];
    const int bm = blockIdx.y * 128, bn = blockIdx.x * 128;
    if (bm >= M) return;
    __shared__ unsigned short As[128 * 32], Bs[128 * 32];
    v4f acc[4][4] = {};
    gemm_core_bf(hbf + hoff[z], W3l + (size_t)z * 768 * 256, M, 256, bm, bn, As, Bs, acc);

    const int lane = threadIdx.x & 63, w = threadIdx.x >> 6;
    const int wr = w >> 1, wc = w & 1, l16 = lane & 15, lg = lane >> 4;
    const int row0 = bm + wr * 64, col0 = bn + wc * 64;
    const float* bias = bias768l + z * 768;
    unsigned char* base = qkvb + qoffB[z];
    float bv[4];
    #pragma unroll
    for (int fn = 0; fn < 4; ++fn) bv[fn] = bias[col0 + fn * 16 + l16];
    #pragma unroll
    for (int fm = 0; fm < 4; ++fm)
        #pragma unroll
        for (int i = 0; i < 4; ++i) {
            int gm = row0 + fm * 16 + lg * 4 + i;
            if (gm >= M) continue;
            #pragma unroll
            for (int fn = 0; fn < 4; ++fn) {
                int c = col0 + fn * 16 + l16;
                float val = acc[fm][fn][i] + bv[fn];
                unsigned char* rowp = base + (size_t)gm * 1024;
                if (c < 256) {
                    *(unsigned short*)(rowp + 2 * c) = f2bf(val);
                } else if (c < 512) {
                    int j = c - 256;
                    rowp[512 + 8 * (j >> 2) + (j & 3)] = f2fp8(val);
                } else {
                    int j = c - 512;
                    rowp[512 + 8 * (j >> 2) + 4 + (j & 3)] = f2fp8(val);
                }
            }
        }
}

// ---- a: h[t] = blend(0.5*agg[t]@a_w[l,t] + a_b[l,t], h[t])  (bf16 h in/out) ----
__global__ __launch_bounds__(256)
void a_gemm3(const unsigned short* __restrict__ aggbf, const unsigned short* __restrict__ Wtl,
             const float* __restrict__ biasl, const float* __restrict__ skipl,
             unsigned short* __restrict__ hbf)
{
    constexpr int Ms[3] = {20000, 10000, 5000};
    constexpr size_t hoff[3] = {0, 20000ull * 256, 30000ull * 256};
    const int z = blockIdx.z;
    const int M = Ms[z];
    const int bm = blockIdx.y * 128, bn = blockIdx.x * 128;
    if (bm >= M) return;
    __shared__ unsigned short As[128 * 32], Bs[128 * 32];
    v4f acc[4][4] = {};
    gemm_core_bf(aggbf + hoff[z], Wtl + (size_t)z * 65536, M, 256, bm, bn, As, Bs, acc);

    const int lane = threadIdx.x & 63, w = threadIdx.x >> 6;
    const int wr = w >> 1, wc = w & 1, l16 = lane & 15, lg = lane >> 4;
    const int row0 = bm + wr * 64, col0 = bn + wc * 64;
    const float* bias = biasl + z * 256;
    unsigned short* Cb = hbf + hoff[z];
    float sv = skipl[z];
    float alpha = 1.0f / (1.0f + expf(-sv));
    float beta = 1.0f - alpha;
    float bv[4];
    #pragma unroll
    for (int fn = 0; fn < 4; ++fn) bv[fn] = bias[col0 + fn * 16 + l16];
    #pragma unroll
    for (int fm = 0; fm < 4; ++fm)
        #pragma unroll
        for (int i = 0; i < 4; ++i) {
            int gm = row0 + fm * 16 + lg * 4 + i;
            if (gm >= M) continue;
            #pragma unroll
            for (int fn = 0; fn < 4; ++fn) {
                size_t idx = (size_t)gm * 256 + col0 + fn * 16 + l16;
                float val = acc[fm][fn][i] * 0.5f + bv[fn];
                val = alpha * val + beta * bf2f(Cb[idx]);
                Cb[idx] = f2bf(val);
            }
        }
}

// ---- final: out = feats[0] @ head_w + cvec  (plain bf16 MFMA) ----
__global__ __launch_bounds__(256)
void head_gemm(const float* __restrict__ A, const unsigned short* __restrict__ Wt,
               const float* __restrict__ bias, float* __restrict__ C)
{
    const int M = 20000, N = 512, K = 512;
    const int bm = blockIdx.y * 128, bn = blockIdx.x * 128;
    if (bm >= M) return;
    __shared__ unsigned short As[128 * 32], Bs[128 * 32];
    v4f acc[4][4] = {};
    gemm_core(A, Wt, M, K, bm, bn, As, Bs, acc);

    const int lane = threadIdx.x & 63, w = threadIdx.x >> 6;
    const int wr = w >> 1, wc = w & 1, l16 = lane & 15, lg = lane >> 4;
    const int row0 = bm + wr * 64, col0 = bn + wc * 64;
    float bv[4];
    #pragma unroll
    for (int fn = 0; fn < 4; ++fn) bv[fn] = bias[col0 + fn * 16 + l16];
    #pragma unroll
    for (int fm = 0; fm < 4; ++fm)
        #pragma unroll
        for (int i = 0; i < 4; ++i) {
            int gm = row0 + fm * 16 + lg * 4 + i;
            if (gm >= M) continue;
            #pragma unroll
            for (int fn = 0; fn < 4; ++fn)
                C[(size_t)gm * N + col0 + fn * 16 + l16] = acc[fm][fn][i] + bv[fn];
        }
}

// ---------------- fused attention: sequential relations, depth-4 ring prefetch ----------------
__global__ __launch_bounds__(256)
void attn_fused_kernel(const unsigned char* __restrict__ qkvb,
                       const int* __restrict__ rp6, const int2* __restrict__ csr_es6,
                       const float* __restrict__ ewp, const float* __restrict__ ebp,
                       unsigned short* __restrict__ aggbf)
{
    constexpr size_t qoffB[3] = {0, 20000ull * 1024, 30000ull * 1024};
    constexpr size_t aoffE[3] = {0, 20000ull * 256, 30000ull * 256};
    constexpr int rpoff[6] = {0, 10001, 30002, 35003, 55004, 60005};
    constexpr int eAz[3] = {1, 0, 2}, eBz[3] = {3, 5, 4};    // incoming etypes per dst type
    constexpr int sAz[3] = {1, 0, 0}, sBz[3] = {2, 2, 1};    // their src node types

    const int gid = blockIdx.x * 4 + (threadIdx.x >> 6);     // 0..34999
    const int z = (gid < 20000) ? 0 : (gid < 30000 ? 1 : 2);
    const int d = gid - (z == 0 ? 0 : (z == 1 ? 20000 : 30000));
    const int t = threadIdx.x & 63;
    // fold 1/sqrt(32) * log2(e) into the edge-linear coefficients (exp2-domain softmax)
    const float kfold = 0.17677669529663687f * 1.4426950408889634f;
    const float ewv = ewp[0] * kfold, ebv = ebp[0] * kfold;

    u16x4 q4 = *(const u16x4*)(qkvb + qoffB[z] + (size_t)d * 1024 + 8 * t);
    const float qx0 = bf2f(q4[0]), qx1 = bf2f(q4[1]), qx2 = bf2f(q4[2]), qx3 = bf2f(q4[3]);

    const int eiA = eAz[z], eiB = eBz[z];
    const int2* esA = csr_es6 + (size_t)eiA * 100000;
    const int2* esB = csr_es6 + (size_t)eiB * 100000;
    const unsigned char* kvAp = qkvb + qoffB[sAz[z]] + 512 + 8 * t;
    const unsigned char* kvBp = qkvb + qoffB[sBz[z]] + 512 + 8 * t;
    const int begA = rp6[rpoff[eiA] + d], endA = rp6[rpoff[eiA] + d + 1];
    const int begB = rp6[rpoff[eiB] + d], endB = rp6[rpoff[eiB] + d + 1];
    const int nA = endA - begA, nB = endB - begB;

    // preload rings for BOTH relations up front (8 gathers in flight)
    uint2 a0 = {0,0}, a1 = a0, a2 = a0, a3 = a0, b0 = a0, b1 = a0, b2 = a0, b3 = a0;
    float fa0 = 0.f, fa1 = 0.f, fa2 = 0.f, fa3 = 0.f, fb0 = 0.f, fb1 = 0.f, fb2 = 0.f, fb3 = 0.f;
    if (nA > 0) { int2 e = esA[begA];     fa0 = __int_as_float(e.y); a0 = *(const uint2*)(kvAp + (size_t)e.x * 1024); }
    if (nA > 1) { int2 e = esA[begA + 1]; fa1 = __int_as_float(e.y); a1 = *(const uint2*)(kvAp + (size_t)e.x * 1024); }
    if (nA > 2) { int2 e = esA[begA + 2]; fa2 = __int_as_float(e.y); a2 = *(const uint2*)(kvAp + (size_t)e.x * 1024); }
    if (nA > 3) { int2 e = esA[begA + 3]; fa3 = __int_as_float(e.y); a3 = *(const uint2*)(kvAp + (size_t)e.x * 1024); }
    if (nB > 0) { int2 e = esB[begB];     fb0 = __int_as_float(e.y); b0 = *(const uint2*)(kvBp + (size_t)e.x * 1024); }
    if (nB > 1) { int2 e = esB[begB + 1]; fb1 = __int_as_float(e.y); b1 = *(const uint2*)(kvBp + (size_t)e.x * 1024); }
    if (nB > 2) { int2 e = esB[begB + 2]; fb2 = __int_as_float(e.y); b2 = *(const uint2*)(kvBp + (size_t)e.x * 1024); }
    if (nB > 3) { int2 e = esB[begB + 3]; fb3 = __int_as_float(e.y); b3 = *(const uint2*)(kvBp + (size_t)e.x * 1024); }

    float m, s;
    float4 acc;

    auto edge = [&](uint2 kv, float sim) {
        v2f k01 = __builtin_amdgcn_cvt_pk_f32_fp8((int)kv.x, false);
        v2f k23 = __builtin_amdgcn_cvt_pk_f32_fp8((int)kv.x, true);
        float dot = qx0 * k01[0] + qx1 * k01[1] + qx2 * k23[0] + qx3 * k23[1];
        dot += __shfl_xor(dot, 1);
        dot += __shfl_xor(dot, 2);
        dot += __shfl_xor(dot, 4);
        float sc = dot * fmaf(sim, ewv, ebv);
        if (sc > m) {
            float r = exp2f(m - sc);
            s *= r; acc.x *= r; acc.y *= r; acc.z *= r; acc.w *= r;
            m = sc;
        }
        float ex = exp2f(sc - m);
        s += ex;
        v2f v01 = __builtin_amdgcn_cvt_pk_f32_fp8((int)kv.y, false);
        v2f v23 = __builtin_amdgcn_cvt_pk_f32_fp8((int)kv.y, true);
        acc.x += ex * v01[0]; acc.y += ex * v01[1];
        acc.z += ex * v23[0]; acc.w += ex * v23[1];
    };

    float4 res = {0.f, 0.f, 0.f, 0.f};

    // ---- relation A ----
    m = -INFINITY; s = 0.0f; acc = {0.f, 0.f, 0.f, 0.f};
    for (int j = 0; j < nA; j += 4) {
        edge(a0, fa0);
        if (j + 4 < nA) { int2 e = esA[begA + j + 4]; fa0 = __int_as_float(e.y); a0 = *(const uint2*)(kvAp + (size_t)e.x * 1024); }
        if (j + 1 < nA) {
            edge(a1, fa1);
            if (j + 5 < nA) { int2 e = esA[begA + j + 5]; fa1 = __int_as_float(e.y); a1 = *(const uint2*)(kvAp + (size_t)e.x * 1024); }
        }
        if (j + 2 < nA) {
            edge(a2, fa2);
            if (j + 6 < nA) { int2 e = esA[begA + j + 6]; fa2 = __int_as_float(e.y); a2 = *(const uint2*)(kvAp + (size_t)e.x * 1024); }
        }
        if (j + 3 < nA) {
            edge(a3, fa3);
            if (j + 7 < nA) { int2 e = esA[begA + j + 7]; fa3 = __int_as_float(e.y); a3 = *(const uint2*)(kvAp + (size_t)e.x * 1024); }
        }
    }
    if (nA > 0) {
        float inv = 1.0f / s;
        res.x += acc.x * inv; res.y += acc.y * inv;
        res.z += acc.z * inv; res.w += acc.w * inv;
    }

    // ---- relation B ----
    m = -INFINITY; s = 0.0f; acc = {0.f, 0.f, 0.f, 0.f};
    for (int j = 0; j < nB; j += 4) {
        edge(b0, fb0);
        if (j + 4 < nB) { int2 e = esB[begB + j + 4]; fb0 = __int_as_float(e.y); b0 = *(const uint2*)(kvBp + (size_t)e.x * 1024); }
        if (j + 1 < nB) {
            edge(b1, fb1);
            if (j + 5 < nB) { int2 e = esB[begB + j + 5]; fb1 = __int_as_float(e.y); b1 = *(const uint2*)(kvBp + (size_t)e.x * 1024); }
        }
        if (j + 2 < nB) {
            edge(b2, fb2);
            if (j + 6 < nB) { int2 e = esB[begB + j + 6]; fb2 = __int_as_float(e.y); b2 = *(const uint2*)(kvBp + (size_t)e.x * 1024); }
        }
        if (j + 3 < nB) {
            edge(b3, fb3);
            if (j + 7 < nB) { int2 e = esB[begB + j + 7]; fb3 = __int_as_float(e.y); b3 = *(const uint2*)(kvBp + (size_t)e.x * 1024); }
        }
    }
    if (nB > 0) {
        float inv = 1.0f / s;
        res.x += acc.x * inv; res.y += acc.y * inv;
        res.z += acc.z * inv; res.w += acc.w * inv;
    }

    u16x4 out;
    out[0] = f2bf(res.x); out[1] = f2bf(res.y);
    out[2] = f2bf(res.z); out[3] = f2bf(res.w);
    *(u16x4*)(aggbf + aoffE[z] + (size_t)d * 256 + 4 * t) = out;
}

__global__ void colsum_kernel(const unsigned short* __restrict__ hbf, float* __restrict__ out, int N)
{
    int c = threadIdx.x;
    float acc = 0.0f;
    for (int r = blockIdx.x; r < N; r += gridDim.x)
        acc += bf2f(hbf[(size_t)r * 256 + c]);
    atomicAdd(&out[c], acc);
}

__global__ __launch_bounds__(512)
void head_kernel(const float* __restrict__ colsum, float n_img,
                 const float* __restrict__ pred_w, const float* __restrict__ pred_b,
                 const float* __restrict__ head1_w, const float* __restrict__ head1_b,
                 const float* __restrict__ head_w, const float* __restrict__ head_b,
                 float* __restrict__ cvec)
{
    __shared__ float mean[256], o0[256], g[512];
    int t = threadIdx.x;
    if (t < 256) mean[t] = colsum[t] / n_img;
    __syncthreads();
    if (t < 256) {
        float acc = pred_b[t];
        for (int k = 0; k < 256; ++k) acc += mean[k] * pred_w[k * 256 + t];
        o0[t] = acc;
    }
    __syncthreads();
    {
        float acc = head1_b[t];
        for (int k = 0; k < 256; ++k) acc += o0[k] * head1_w[k * 512 + t];
        g[t] = acc;
    }
    __syncthreads();
    {
        float acc = head_b[t];
        for (int k = 0; k < 512; ++k) acc += g[k] * head_w[k * 512 + t];
        cvec[t] = acc;
    }
}

extern "C" void kernel_launch(void* const* d_in, const int* in_sizes, int n_in,
                              void* d_out, int out_size, void* d_ws, size_t ws_size,
                              hipStream_t stream)
{
    const int NI = 20000, E = 100000;

    const float* feat[3] = {(const float*)d_in[0], (const float*)d_in[1], (const float*)d_in[2]};
    const float* adapt_w = (const float*)d_in[3];
    const float* adapt_b = (const float*)d_in[4];
    const float* k_w = (const float*)d_in[5];
    const float* k_b = (const float*)d_in[6];
    const float* q_w = (const float*)d_in[7];
    const float* q_b = (const float*)d_in[8];
    const float* v_w = (const float*)d_in[9];
    const float* v_b = (const float*)d_in[10];
    const float* a_w = (const float*)d_in[11];
    const float* a_b = (const float*)d_in[12];
    const float* e_w = (const float*)d_in[13];
    const float* e_b = (const float*)d_in[14];
    const float* skip = (const float*)d_in[15];
    const float* pred_w = (const float*)d_in[16];
    const float* pred_b = (const float*)d_in[17];
    const float* head1_w = (const float*)d_in[19];
    const float* head1_b = (const float*)d_in[20];
    const float* head_w = (const float*)d_in[21];
    const float* head_b = (const float*)d_in[22];

    GraphPtrs gp;
    for (int i = 0; i < 6; ++i) {
        gp.sim[i] = (const float*)d_in[23 + i];
        gp.src[i] = (const int*)d_in[29 + 2 * i];
        gp.dst[i] = (const int*)d_in[30 + 2 * i];
    }

    float* ws = (float*)d_ws;
    size_t off = 0;
    auto alloc = [&](size_t n) { float* p = ws + off; off += (n + 3) & ~(size_t)3; return p; };
    const size_t NTOT = 35000ull * 256;
    unsigned short* hbf   = (unsigned short*)alloc(NTOT / 2);
    unsigned short* aggbf = (unsigned short*)alloc(NTOT / 2);
    unsigned char* qkvb   = (unsigned char*)alloc(35000ull * 256);   // 1024 B per node
    float* csum = alloc(256);
    float* cvec = alloc(512);
    int* deg6    = (int*)alloc(70000);
    int* cursor6 = (int*)alloc(70000);
    int* rp6     = (int*)alloc(70012);
    int2* csr_es6 = (int2*)alloc(1200000);
    unsigned short* adapt_wt = (unsigned short*)alloc(3 * 512 * 256 / 2);
    unsigned short* W3   = (unsigned short*)alloc(6ull * 768 * 256 / 2);  // [lt][768][256]
    unsigned short* a_wt = (unsigned short*)alloc(6 * 65536 / 2);
    float* bias768 = alloc(6 * 768);
    unsigned short* head_wt = (unsigned short*)alloc(512 * 512 / 2);

    // ---- CSR build: 4 dispatches for all 6 etypes ----
    hipMemsetAsync(deg6, 0, 70000 * sizeof(int), stream);
    hipLaunchKernelGGL(hist6_kernel, dim3((E + 255) / 256, 6), dim3(256), 0, stream, gp, deg6);
    hipLaunchKernelGGL(scan6_kernel, dim3(6), dim3(256), 0, stream, deg6, rp6, cursor6);
    hipLaunchKernelGGL(scatter6_kernel, dim3((E + 255) / 256, 6), dim3(256), 0, stream,
                       gp, cursor6, csr_es6);

    // ---- weights -> bf16 ----
    hipLaunchKernelGGL(wcvt_kernel, dim3(16, 8, 3), dim3(256), 0, stream, adapt_w, adapt_wt, 512, 256);
    hipLaunchKernelGGL(wcvt_qkv_kernel, dim3(8, 8, 18), dim3(256), 0, stream, q_w, k_w, v_w, W3);
    hipLaunchKernelGGL(wcvt_kernel, dim3(8, 8, 6), dim3(256), 0, stream, a_w, a_wt, 256, 256);
    hipLaunchKernelGGL(wcvt_kernel, dim3(16, 16, 1), dim3(256), 0, stream, head_w, head_wt, 512, 512);
    hipLaunchKernelGGL(bias_concat_kernel, dim3(18), dim3(256), 0, stream, q_b, k_b, v_b, bias768);

    // ---- adapt (all 3 types in one dispatch) ----
    Ptr3f fa; fa.p[0] = feat[0]; fa.p[1] = feat[1]; fa.p[2] = feat[2];
    hipLaunchKernelGGL(adapt_gemm3, dim3(2, 157, 3), dim3(256), 0, stream, fa, adapt_wt, adapt_b, hbf);

    for (int l = 0; l < 2; ++l) {
        hipLaunchKernelGGL(qkv_gemm3, dim3(6, 157, 3), dim3(256), 0, stream,
                           hbf, W3 + (size_t)l * 3 * 768 * 256, bias768 + (size_t)l * 3 * 768, qkvb);
        hipLaunchKernelGGL(attn_fused_kernel, dim3(8750), dim3(256), 0, stream,
                           qkvb, rp6, csr_es6, e_w + l, e_b + l, aggbf);
        hipLaunchKernelGGL(a_gemm3, dim3(2, 157, 3), dim3(256), 0, stream,
                           aggbf, a_wt + (size_t)l * 3 * 65536, a_b + (size_t)l * 3 * 256,
                           skip + l * 3, hbf);
    }

    hipMemsetAsync(csum, 0, 256 * sizeof(float), stream);
    hipLaunchKernelGGL(colsum_kernel, dim3(128), dim3(256), 0, stream, hbf, csum, NI);
    hipLaunchKernelGGL(head_kernel, dim3(1), dim3(512), 0, stream,
                       csum, (float)NI, pred_w, pred_b, head1_w, head1_b, head_w, head_b, cvec);

    // out = feats[0] @ head_w + cvec  (plain bf16 MFMA)
    hipLaunchKernelGGL(head_gemm, dim3(4, 157), dim3(256), 0, stream,
                       feat[0], head_wt, cvec, (float*)d_out);
}

// Round 9
// 566.542 us; speedup vs baseline: 1.0462x; 1.0420x over previous
//
#include <hip/hip_runtime.h>
#include <hip/hip_bf16.h>
#include <math.h>

typedef short v8s __attribute__((ext_vector_type(8)));
typedef float v4f __attribute__((ext_vector_type(4)));
typedef float v2f __attribute__((ext_vector_type(2)));
typedef unsigned short u16x4 __attribute__((ext_vector_type(4)));

__device__ __forceinline__ unsigned short f2bf(float f) {
    unsigned int u = __float_as_uint(f);
    u += 0x7fff + ((u >> 16) & 1);   // round-to-nearest-even
    return (unsigned short)(u >> 16);
}
__device__ __forceinline__ float bf2f(unsigned short h) {
    return __uint_as_float(((unsigned int)h) << 16);
}
__device__ __forceinline__ unsigned char f2fp8(float f) {
    int e = __builtin_amdgcn_cvt_pk_fp8_f32(f, f, 0, false);
    return (unsigned char)(e & 0xff);
}

struct GraphPtrs { const int* dst[6]; const int* src[6]; const float* sim[6]; };
struct Ptr3f { const float* p[3]; };

// ---------------- weight transpose + convert: W[K][N] fp32 -> Wt[N][K] bf16 ----------------
__global__ __launch_bounds__(256)
void wcvt_kernel(const float* __restrict__ W, unsigned short* __restrict__ Wt, int K, int N)
{
    __shared__ float tile[32][33];
    const int b = blockIdx.z;
    const float* Wb = W + (size_t)b * K * N;
    unsigned short* Wtb = Wt + (size_t)b * K * N;
    const int k0 = blockIdx.x * 32, n0 = blockIdx.y * 32;
    const int x = threadIdx.x & 31, y = threadIdx.x >> 5;
    #pragma unroll
    for (int j = 0; j < 4; ++j)
        tile[y + 8 * j][x] = Wb[(size_t)(k0 + y + 8 * j) * N + n0 + x];
    __syncthreads();
    #pragma unroll
    for (int j = 0; j < 4; ++j)
        Wtb[(size_t)(n0 + y + 8 * j) * K + k0 + x] = f2bf(tile[x][y + 8 * j]);
}

// q/k/v weights -> W3[(l,t)][768][256] (rows 0-255 q, 256-511 k, 512-767 v)
__global__ __launch_bounds__(256)
void wcvt_qkv_kernel(const float* __restrict__ qw, const float* __restrict__ kw,
                     const float* __restrict__ vw, unsigned short* __restrict__ W3)
{
    __shared__ float tile[32][33];
    const int z = blockIdx.z, lt = z / 3, sec = z - lt * 3;
    const float* src = (sec == 0 ? qw : sec == 1 ? kw : vw) + (size_t)lt * 65536;
    unsigned short* dst = W3 + ((size_t)lt * 768 + sec * 256) * 256;
    const int k0 = blockIdx.x * 32, n0 = blockIdx.y * 32;
    const int x = threadIdx.x & 31, y = threadIdx.x >> 5;
    #pragma unroll
    for (int j = 0; j < 4; ++j)
        tile[y + 8 * j][x] = src[(size_t)(k0 + y + 8 * j) * 256 + n0 + x];
    __syncthreads();
    #pragma unroll
    for (int j = 0; j < 4; ++j)
        dst[(size_t)(n0 + y + 8 * j) * 256 + k0 + x] = f2bf(tile[x][y + 8 * j]);
}

// bias768[lt][768] = concat(q_b[lt], k_b[lt], v_b[lt])
__global__ void bias_concat_kernel(const float* __restrict__ qb, const float* __restrict__ kb,
                                   const float* __restrict__ vb, float* __restrict__ out)
{
    int i = blockIdx.x * 256 + threadIdx.x;
    if (i < 6 * 768) {
        int lt = i / 768, c = i - lt * 768;
        int sec = c >> 8, cc = c & 255;
        const float* s = sec == 0 ? qb : sec == 1 ? kb : vb;
        out[i] = s[lt * 256 + cc];
    }
}

// ---------------- CSR build (all 6 etypes fused) ----------------
__global__ void hist6_kernel(GraphPtrs gp, int* __restrict__ deg6)
{
    constexpr int doff[6] = {0, 10000, 30000, 35000, 55000, 60000};
    const int ei = blockIdx.y;
    int e = blockIdx.x * 256 + threadIdx.x;
    if (e < 100000) atomicAdd(&deg6[doff[ei] + gp.dst[ei][e]], 1);
}

__global__ __launch_bounds__(256)
void scan6_kernel(const int* __restrict__ deg6, int* __restrict__ rp6, int* __restrict__ cursor6)
{
    constexpr int ndv[6]   = {10000, 20000, 5000, 20000, 5000, 10000};
    constexpr int doff[6]  = {0, 10000, 30000, 35000, 55000, 60000};
    constexpr int rpoff[6] = {0, 10001, 30002, 35003, 55004, 60005};
    const int b = blockIdx.x;
    const int nd = ndv[b];
    const int* deg = deg6 + doff[b];
    int* rowptr = rp6 + rpoff[b];
    int* cursor = cursor6 + doff[b];
    const int t = threadIdx.x, lane = t & 63, w = t >> 6;
    __shared__ int wsum[4];
    int carry = 0;
    for (int base = 0; base < nd; base += 1024) {
        int i0 = base + t * 4;
        int x0 = 0, x1 = 0, x2 = 0, x3 = 0;
        if (i0 + 3 < nd) {
            int4 v = *(const int4*)(deg + i0);
            x0 = v.x; x1 = v.y; x2 = v.z; x3 = v.w;
        } else {
            if (i0 < nd) x0 = deg[i0];
            if (i0 + 1 < nd) x1 = deg[i0 + 1];
            if (i0 + 2 < nd) x2 = deg[i0 + 2];
            if (i0 + 3 < nd) x3 = deg[i0 + 3];
        }
        int s1 = x0 + x1, s2 = s1 + x2, tot = s2 + x3;
        int inc = tot;
        #pragma unroll
        for (int o = 1; o < 64; o <<= 1) {
            int y = __shfl_up(inc, o, 64);
            if (lane >= o) inc += y;
        }
        if (lane == 63) wsum[w] = inc;
        __syncthreads();
        int woff = 0;
        #pragma unroll
        for (int ww = 0; ww < 4; ++ww) if (ww < w) woff += wsum[ww];
        int ebase = carry + woff + inc - tot;
        if (i0 < nd)     { rowptr[i0] = ebase;          cursor[i0] = ebase; }
        if (i0 + 1 < nd) { rowptr[i0 + 1] = ebase + x0; cursor[i0 + 1] = ebase + x0; }
        if (i0 + 2 < nd) { rowptr[i0 + 2] = ebase + s1; cursor[i0 + 2] = ebase + s1; }
        if (i0 + 3 < nd) { rowptr[i0 + 3] = ebase + s2; cursor[i0 + 3] = ebase + s2; }
        carry += wsum[0] + wsum[1] + wsum[2] + wsum[3];
        __syncthreads();
    }
    if (t == 0) rowptr[nd] = carry;
}

// scatter: pack (src, sim) into one int2 in CSR order
__global__ void scatter6_kernel(GraphPtrs gp, int* __restrict__ cursor6,
                                int2* __restrict__ csr_es6)
{
    constexpr int doff[6] = {0, 10000, 30000, 35000, 55000, 60000};
    const int ei = blockIdx.y;
    int e = blockIdx.x * 256 + threadIdx.x;
    if (e < 100000) {
        int j = atomicAdd(&cursor6[doff[ei] + gp.dst[ei][e]], 1);
        int2 es; es.x = gp.src[ei][e]; es.y = __float_as_int(gp.sim[ei][e]);
        csr_es6[(size_t)ei * 100000 + j] = es;
    }
}

// ---------------- MFMA GEMM core, fp32 A (converted on the fly), optional bf16 side-write ----------------
__device__ __forceinline__ void gemm_core(const float* __restrict__ A,
    const unsigned short* __restrict__ Wt, int M, int K, int bm, int bn,
    unsigned short* __restrict__ As, unsigned short* __restrict__ Bs, v4f acc[4][4],
    unsigned short* __restrict__ fout)
{
    const int tid = threadIdx.x;
    const int sr = tid >> 1, sc = (tid & 1) * 16;
    const int arow = bm + sr;
    const bool aok = arow < M;
    const float* ap = A + (size_t)arow * K + sc;
    const unsigned short* bp = Wt + (size_t)(bn + sr) * K + sc;
    const int lane = tid & 63, w = tid >> 6, wr = w >> 1, wc = w & 1;
    const int l16 = lane & 15, lg = lane >> 4;
    const int abase = (wr * 64 + l16) * 32 + lg * 8;
    const int bbase = (wc * 64 + l16) * 32 + lg * 8;

    for (int k0 = 0; k0 < K; k0 += 32) {
        float4 a0 = {0,0,0,0}, a1 = a0, a2 = a0, a3 = a0;
        if (aok) {
            a0 = *(const float4*)(ap + k0);
            a1 = *(const float4*)(ap + k0 + 4);
            a2 = *(const float4*)(ap + k0 + 8);
            a3 = *(const float4*)(ap + k0 + 12);
        }
        uint4 b0 = *(const uint4*)(bp + k0);
        uint4 b1 = *(const uint4*)(bp + k0 + 8);

        if (k0) __syncthreads();

        uint4 w0, w1;
        w0.x = (unsigned int)f2bf(a0.x) | ((unsigned int)f2bf(a0.y) << 16);
        w0.y = (unsigned int)f2bf(a0.z) | ((unsigned int)f2bf(a0.w) << 16);
        w0.z = (unsigned int)f2bf(a1.x) | ((unsigned int)f2bf(a1.y) << 16);
        w0.w = (unsigned int)f2bf(a1.z) | ((unsigned int)f2bf(a1.w) << 16);
        w1.x = (unsigned int)f2bf(a2.x) | ((unsigned int)f2bf(a2.y) << 16);
        w1.y = (unsigned int)f2bf(a2.z) | ((unsigned int)f2bf(a2.w) << 16);
        w1.z = (unsigned int)f2bf(a3.x) | ((unsigned int)f2bf(a3.y) << 16);
        w1.w = (unsigned int)f2bf(a3.z) | ((unsigned int)f2bf(a3.w) << 16);
        if (fout && aok) {
            *(uint4*)(fout + (size_t)arow * K + k0 + sc)     = w0;
            *(uint4*)(fout + (size_t)arow * K + k0 + sc + 8) = w1;
        }
        *(uint4*)&As[sr * 32 + sc]     = w0;
        *(uint4*)&As[sr * 32 + sc + 8] = w1;
        *(uint4*)&Bs[sr * 32 + sc]     = b0;
        *(uint4*)&Bs[sr * 32 + sc + 8] = b1;
        __syncthreads();

        v8s af[4], bfr[4];
        #pragma unroll
        for (int f = 0; f < 4; ++f) af[f] = *(const v8s*)&As[abase + f * 512];
        #pragma unroll
        for (int f = 0; f < 4; ++f) bfr[f] = *(const v8s*)&Bs[bbase + f * 512];
        #pragma unroll
        for (int i = 0; i < 4; ++i)
            #pragma unroll
            for (int j = 0; j < 4; ++j)
                acc[i][j] = __builtin_amdgcn_mfma_f32_16x16x32_bf16(af[i], bfr[j], acc[i][j], 0, 0, 0);
    }
}

// ---------------- MFMA GEMM core, bf16 A ----------------
__device__ __forceinline__ void gemm_core_bf(const unsigned short* __restrict__ A,
    const unsigned short* __restrict__ Wt, int M, int K, int bm, int bn,
    unsigned short* __restrict__ As, unsigned short* __restrict__ Bs, v4f acc[4][4])
{
    const int tid = threadIdx.x;
    const int sr = tid >> 1, sc = (tid & 1) * 16;
    const int arow = bm + sr;
    const bool aok = arow < M;
    const unsigned short* ap = A + (size_t)arow * K + sc;
    const unsigned short* bp = Wt + (size_t)(bn + sr) * K + sc;
    const int lane = tid & 63, w = tid >> 6, wr = w >> 1, wc = w & 1;
    const int l16 = lane & 15, lg = lane >> 4;
    const int abase = (wr * 64 + l16) * 32 + lg * 8;
    const int bbase = (wc * 64 + l16) * 32 + lg * 8;

    for (int k0 = 0; k0 < K; k0 += 32) {
        uint4 a0 = {0,0,0,0}, a1 = a0;
        if (aok) {
            a0 = *(const uint4*)(ap + k0);
            a1 = *(const uint4*)(ap + k0 + 8);
        }
        uint4 b0 = *(const uint4*)(bp + k0);
        uint4 b1 = *(const uint4*)(bp + k0 + 8);

        if (k0) __syncthreads();

        *(uint4*)&As[sr * 32 + sc]     = a0;
        *(uint4*)&As[sr * 32 + sc + 8] = a1;
        *(uint4*)&Bs[sr * 32 + sc]     = b0;
        *(uint4*)&Bs[sr * 32 + sc + 8] = b1;
        __syncthreads();

        v8s af[4], bfr[4];
        #pragma unroll
        for (int f = 0; f < 4; ++f) af[f] = *(const v8s*)&As[abase + f * 512];
        #pragma unroll
        for (int f = 0; f < 4; ++f) bfr[f] = *(const v8s*)&Bs[bbase + f * 512];
        #pragma unroll
        for (int i = 0; i < 4; ++i)
            #pragma unroll
            for (int j = 0; j < 4; ++j)
                acc[i][j] = __builtin_amdgcn_mfma_f32_16x16x32_bf16(af[i], bfr[j], acc[i][j], 0, 0, 0);
    }
}

// ---- adapt: h[t] = feats[t] @ adapt_w[t] + adapt_b[t]  (bf16 out; side-writes bf16 feat0) ----
__global__ __launch_bounds__(256)
void adapt_gemm3(Ptr3f A3, const unsigned short* __restrict__ Wt3,
                 const float* __restrict__ bias3, unsigned short* __restrict__ hbf,
                 unsigned short* __restrict__ fbf)
{
    constexpr int Ms[3] = {20000, 10000, 5000};
    constexpr size_t hoff[3] = {0, 20000ull * 256, 30000ull * 256};
    const int z = blockIdx.z;
    const int M = Ms[z];
    const int bm = blockIdx.y * 128, bn = blockIdx.x * 128;
    if (bm >= M) return;
    __shared__ unsigned short As[128 * 32], Bs[128 * 32];
    v4f acc[4][4] = {};
    unsigned short* fout = (z == 0 && blockIdx.x == 0) ? fbf : nullptr;
    gemm_core(A3.p[z], Wt3 + (size_t)z * 256 * 512, M, 512, bm, bn, As, Bs, acc, fout);

    const int lane = threadIdx.x & 63, w = threadIdx.x >> 6;
    const int wr = w >> 1, wc = w & 1, l16 = lane & 15, lg = lane >> 4;
    const int row0 = bm + wr * 64, col0 = bn + wc * 64;
    const float* bias = bias3 + z * 256;
    unsigned short* Cb = hbf + hoff[z];
    float bv[4];
    #pragma unroll
    for (int fn = 0; fn < 4; ++fn) bv[fn] = bias[col0 + fn * 16 + l16];
    #pragma unroll
    for (int fm = 0; fm < 4; ++fm)
        #pragma unroll
        for (int i = 0; i < 4; ++i) {
            int gm = row0 + fm * 16 + lg * 4 + i;
            if (gm >= M) continue;
            #pragma unroll
            for (int fn = 0; fn < 4; ++fn)
                Cb[(size_t)gm * 256 + col0 + fn * 16 + l16] = f2bf(acc[fm][fn][i] + bv[fn]);
        }
}

// ---- qkv: row layout (1024 B/node): q 256xbf16 | kv 512B lane-interleaved fp8 ----
__global__ __launch_bounds__(256)
void qkv_gemm3(const unsigned short* __restrict__ hbf, const unsigned short* __restrict__ W3l,
               const float* __restrict__ bias768l, unsigned char* __restrict__ qkvb)
{
    constexpr int Ms[3] = {20000, 10000, 5000};
    constexpr size_t hoff[3] = {0, 20000ull * 256, 30000ull * 256};
    constexpr size_t qoffB[3] = {0, 20000ull * 1024, 30000ull * 1024};
    const int z = blockIdx.z;
    const int M = Ms[z];
    const int bm = blockIdx.y * 128, bn = blockIdx.x * 128;
    if (bm >= M) return;
    __shared__ unsigned short As[128 * 32], Bs[128 * 32];
    v4f acc[4][4] = {};
    gemm_core_bf(hbf + hoff[z], W3l + (size_t)z * 768 * 256, M, 256, bm, bn, As, Bs, acc);

    const int lane = threadIdx.x & 63, w = threadIdx.x >> 6;
    const int wr = w >> 1, wc = w & 1, l16 = lane & 15, lg = lane >> 4;
    const int row0 = bm + wr * 64, col0 = bn + wc * 64;
    const float* bias = bias768l + z * 768;
    unsigned char* base = qkvb + qoffB[z];
    float bv[4];
    #pragma unroll
    for (int fn = 0; fn < 4; ++fn) bv[fn] = bias[col0 + fn * 16 + l16];
    #pragma unroll
    for (int fm = 0; fm < 4; ++fm)
        #pragma unroll
        for (int i = 0; i < 4; ++i) {
            int gm = row0 + fm * 16 + lg * 4 + i;
            if (gm >= M) continue;
            #pragma unroll
            for (int fn = 0; fn < 4; ++fn) {
                int c = col0 + fn * 16 + l16;
                float val = acc[fm][fn][i] + bv[fn];
                unsigned char* rowp = base + (size_t)gm * 1024;
                if (c < 256) {
                    *(unsigned short*)(rowp + 2 * c) = f2bf(val);
                } else if (c < 512) {
                    int j = c - 256;
                    rowp[512 + 8 * (j >> 2) + (j & 3)] = f2fp8(val);
                } else {
                    int j = c - 512;
                    rowp[512 + 8 * (j >> 2) + 4 + (j & 3)] = f2fp8(val);
                }
            }
        }
}

// ---- a: h[t] = blend(0.5*agg[t]@a_w[l,t] + a_b[l,t], h[t])  (bf16 h in/out) ----
__global__ __launch_bounds__(256)
void a_gemm3(const unsigned short* __restrict__ aggbf, const unsigned short* __restrict__ Wtl,
             const float* __restrict__ biasl, const float* __restrict__ skipl,
             unsigned short* __restrict__ hbf)
{
    constexpr int Ms[3] = {20000, 10000, 5000};
    constexpr size_t hoff[3] = {0, 20000ull * 256, 30000ull * 256};
    const int z = blockIdx.z;
    const int M = Ms[z];
    const int bm = blockIdx.y * 128, bn = blockIdx.x * 128;
    if (bm >= M) return;
    __shared__ unsigned short As[128 * 32], Bs[128 * 32];
    v4f acc[4][4] = {};
    gemm_core_bf(aggbf + hoff[z], Wtl + (size_t)z * 65536, M, 256, bm, bn, As, Bs, acc);

    const int lane = threadIdx.x & 63, w = threadIdx.x >> 6;
    const int wr = w >> 1, wc = w & 1, l16 = lane & 15, lg = lane >> 4;
    const int row0 = bm + wr * 64, col0 = bn + wc * 64;
    const float* bias = biasl + z * 256;
    unsigned short* Cb = hbf + hoff[z];
    float sv = skipl[z];
    float alpha = 1.0f / (1.0f + expf(-sv));
    float beta = 1.0f - alpha;
    float bv[4];
    #pragma unroll
    for (int fn = 0; fn < 4; ++fn) bv[fn] = bias[col0 + fn * 16 + l16];
    #pragma unroll
    for (int fm = 0; fm < 4; ++fm)
        #pragma unroll
        for (int i = 0; i < 4; ++i) {
            int gm = row0 + fm * 16 + lg * 4 + i;
            if (gm >= M) continue;
            #pragma unroll
            for (int fn = 0; fn < 4; ++fn) {
                size_t idx = (size_t)gm * 256 + col0 + fn * 16 + l16;
                float val = acc[fm][fn][i] * 0.5f + bv[fn];
                val = alpha * val + beta * bf2f(Cb[idx]);
                Cb[idx] = f2bf(val);
            }
        }
}

// ---- final: out = fbf(bf16 feats[0]) @ head_w + cvec ----
__global__ __launch_bounds__(256)
void head_gemm(const unsigned short* __restrict__ A, const unsigned short* __restrict__ Wt,
               const float* __restrict__ bias, float* __restrict__ C)
{
    const int M = 20000, N = 512, K = 512;
    const int bm = blockIdx.y * 128, bn = blockIdx.x * 128;
    if (bm >= M) return;
    __shared__ unsigned short As[128 * 32], Bs[128 * 32];
    v4f acc[4][4] = {};
    gemm_core_bf(A, Wt, M, K, bm, bn, As, Bs, acc);

    const int lane = threadIdx.x & 63, w = threadIdx.x >> 6;
    const int wr = w >> 1, wc = w & 1, l16 = lane & 15, lg = lane >> 4;
    const int row0 = bm + wr * 64, col0 = bn + wc * 64;
    float bv[4];
    #pragma unroll
    for (int fn = 0; fn < 4; ++fn) bv[fn] = bias[col0 + fn * 16 + l16];
    #pragma unroll
    for (int fm = 0; fm < 4; ++fm)
        #pragma unroll
        for (int i = 0; i < 4; ++i) {
            int gm = row0 + fm * 16 + lg * 4 + i;
            if (gm >= M) continue;
            #pragma unroll
            for (int fn = 0; fn < 4; ++fn)
                C[(size_t)gm * N + col0 + fn * 16 + l16] = acc[fm][fn][i] + bv[fn];
        }
}

// ---------------- fused attention: round-6 structure (depth-2 ring, sequential relations) ----------------
__global__ __launch_bounds__(256)
void attn_fused_kernel(const unsigned char* __restrict__ qkvb,
                       const int* __restrict__ rp6, const int2* __restrict__ csr_es6,
                       const float* __restrict__ ewp, const float* __restrict__ ebp,
                       unsigned short* __restrict__ aggbf)
{
    constexpr int ndd[3] = {20000, 10000, 5000};
    constexpr size_t qoffB[3] = {0, 20000ull * 1024, 30000ull * 1024};
    constexpr size_t aoffE[3] = {0, 20000ull * 256, 30000ull * 256};
    constexpr int rpoff[6] = {0, 10001, 30002, 35003, 55004, 60005};
    constexpr int eAz[3] = {1, 0, 2}, eBz[3] = {3, 5, 4};    // incoming etypes per dst type
    constexpr int sAz[3] = {1, 0, 0}, sBz[3] = {2, 2, 1};    // their src node types

    const int z = blockIdx.y;
    const int d = blockIdx.x * 4 + (threadIdx.x >> 6);
    if (d >= ndd[z]) return;
    const int t = threadIdx.x & 63;
    // fold 1/sqrt(32) * log2(e) into the edge-linear coefficients (exp2-domain softmax)
    const float kfold = 0.17677669529663687f * 1.4426950408889634f;
    const float ewv = ewp[0] * kfold, ebv = ebp[0] * kfold;

    u16x4 q4 = *(const u16x4*)(qkvb + qoffB[z] + (size_t)d * 1024 + 8 * t);
    const float qx0 = bf2f(q4[0]), qx1 = bf2f(q4[1]), qx2 = bf2f(q4[2]), qx3 = bf2f(q4[3]);

    float4 res = {0.f, 0.f, 0.f, 0.f};
    #pragma unroll
    for (int rr = 0; rr < 2; ++rr) {
        const int ei = rr == 0 ? eAz[z] : eBz[z];
        const int stp = rr == 0 ? sAz[z] : sBz[z];
        const int2* es = csr_es6 + (size_t)ei * 100000;
        const unsigned char* kvp = qkvb + qoffB[stp] + 512 + 8 * t;
        const int beg = rp6[rpoff[ei] + d], end = rp6[rpoff[ei] + d + 1];
        const int n = end - beg;

        float m = -INFINITY, s = 0.0f;
        float4 acc = {0.f, 0.f, 0.f, 0.f};

        // depth-2 ring: two edges in flight
        uint2 kv0 = {0, 0}, kv1 = {0, 0};
        float sim0 = 0.0f, sim1 = 0.0f;
        if (n > 0) { int2 e = es[beg];     sim0 = __int_as_float(e.y); kv0 = *(const uint2*)(kvp + (size_t)e.x * 1024); }
        if (n > 1) { int2 e = es[beg + 1]; sim1 = __int_as_float(e.y); kv1 = *(const uint2*)(kvp + (size_t)e.x * 1024); }
        for (int j = 0; j < n; ++j) {
            uint2 kvc = kv0; float simc = sim0;
            kv0 = kv1; sim0 = sim1;
            if (j + 2 < n) {
                int2 e = es[beg + j + 2];
                sim1 = __int_as_float(e.y);
                kv1 = *(const uint2*)(kvp + (size_t)e.x * 1024);
            }
            v2f k01 = __builtin_amdgcn_cvt_pk_f32_fp8((int)kvc.x, false);
            v2f k23 = __builtin_amdgcn_cvt_pk_f32_fp8((int)kvc.x, true);
            float dot = qx0 * k01[0] + qx1 * k01[1] + qx2 * k23[0] + qx3 * k23[1];
            dot += __shfl_xor(dot, 1);
            dot += __shfl_xor(dot, 2);
            dot += __shfl_xor(dot, 4);
            float sc = dot * fmaf(simc, ewv, ebv);
            if (sc > m) {
                float r = exp2f(m - sc);
                s *= r;
                acc.x *= r; acc.y *= r; acc.z *= r; acc.w *= r;
                m = sc;
            }
            float ex = exp2f(sc - m);
            s += ex;
            v2f v01 = __builtin_amdgcn_cvt_pk_f32_fp8((int)kvc.y, false);
            v2f v23 = __builtin_amdgcn_cvt_pk_f32_fp8((int)kvc.y, true);
            acc.x += ex * v01[0]; acc.y += ex * v01[1];
            acc.z += ex * v23[0]; acc.w += ex * v23[1];
        }
        float inv = (n > 0) ? 1.0f / s : 0.0f;
        res.x += acc.x * inv; res.y += acc.y * inv;
        res.z += acc.z * inv; res.w += acc.w * inv;
    }
    u16x4 out;
    out[0] = f2bf(res.x); out[1] = f2bf(res.y);
    out[2] = f2bf(res.z); out[3] = f2bf(res.w);
    *(u16x4*)(aggbf + aoffE[z] + (size_t)d * 256 + 4 * t) = out;
}

__global__ void colsum_kernel(const unsigned short* __restrict__ hbf, float* __restrict__ out, int N)
{
    int c = threadIdx.x;
    float acc = 0.0f;
    for (int r = blockIdx.x; r < N; r += gridDim.x)
        acc += bf2f(hbf[(size_t)r * 256 + c]);
    atomicAdd(&out[c], acc);
}

__global__ __launch_bounds__(512)
void head_kernel(const float* __restrict__ colsum, float n_img,
                 const float* __restrict__ pred_w, const float* __restrict__ pred_b,
                 const float* __restrict__ head1_w, const float* __restrict__ head1_b,
                 const float* __restrict__ head_w, const float* __restrict__ head_b,
                 float* __restrict__ cvec)
{
    __shared__ float mean[256], o0[256], g[512];
    int t = threadIdx.x;
    if (t < 256) mean[t] = colsum[t] / n_img;
    __syncthreads();
    if (t < 256) {
        float acc = pred_b[t];
        for (int k = 0; k < 256; ++k) acc += mean[k] * pred_w[k * 256 + t];
        o0[t] = acc;
    }
    __syncthreads();
    {
        float acc = head1_b[t];
        for (int k = 0; k < 256; ++k) acc += o0[k] * head1_w[k * 512 + t];
        g[t] = acc;
    }
    __syncthreads();
    {
        float acc = head_b[t];
        for (int k = 0; k < 512; ++k) acc += g[k] * head_w[k * 512 + t];
        cvec[t] = acc;
    }
}

extern "C" void kernel_launch(void* const* d_in, const int* in_sizes, int n_in,
                              void* d_out, int out_size, void* d_ws, size_t ws_size,
                              hipStream_t stream)
{
    const int NI = 20000, E = 100000;

    const float* feat[3] = {(const float*)d_in[0], (const float*)d_in[1], (const float*)d_in[2]};
    const float* adapt_w = (const float*)d_in[3];
    const float* adapt_b = (const float*)d_in[4];
    const float* k_w = (const float*)d_in[5];
    const float* k_b = (const float*)d_in[6];
    const float* q_w = (const float*)d_in[7];
    const float* q_b = (const float*)d_in[8];
    const float* v_w = (const float*)d_in[9];
    const float* v_b = (const float*)d_in[10];
    const float* a_w = (const float*)d_in[11];
    const float* a_b = (const float*)d_in[12];
    const float* e_w = (const float*)d_in[13];
    const float* e_b = (const float*)d_in[14];
    const float* skip = (const float*)d_in[15];
    const float* pred_w = (const float*)d_in[16];
    const float* pred_b = (const float*)d_in[17];
    const float* head1_w = (const float*)d_in[19];
    const float* head1_b = (const float*)d_in[20];
    const float* head_w = (const float*)d_in[21];
    const float* head_b = (const float*)d_in[22];

    GraphPtrs gp;
    for (int i = 0; i < 6; ++i) {
        gp.sim[i] = (const float*)d_in[23 + i];
        gp.src[i] = (const int*)d_in[29 + 2 * i];
        gp.dst[i] = (const int*)d_in[30 + 2 * i];
    }

    float* ws = (float*)d_ws;
    size_t off = 0;
    auto alloc = [&](size_t n) { float* p = ws + off; off += (n + 3) & ~(size_t)3; return p; };
    const size_t NTOT = 35000ull * 256;
    unsigned short* hbf   = (unsigned short*)alloc(NTOT / 2);
    unsigned short* aggbf = (unsigned short*)alloc(NTOT / 2);
    unsigned char* qkvb   = (unsigned char*)alloc(35000ull * 256);   // 1024 B per node
    unsigned short* fbf   = (unsigned short*)alloc(20000ull * 512 / 2);  // bf16 feats[0]
    float* csum = alloc(256);
    float* cvec = alloc(512);
    int* deg6    = (int*)alloc(70000);
    int* cursor6 = (int*)alloc(70000);
    int* rp6     = (int*)alloc(70012);
    int2* csr_es6 = (int2*)alloc(1200000);
    unsigned short* adapt_wt = (unsigned short*)alloc(3 * 512 * 256 / 2);
    unsigned short* W3   = (unsigned short*)alloc(6ull * 768 * 256 / 2);  // [lt][768][256]
    unsigned short* a_wt = (unsigned short*)alloc(6 * 65536 / 2);
    float* bias768 = alloc(6 * 768);
    unsigned short* head_wt = (unsigned short*)alloc(512 * 512 / 2);

    // ---- CSR build: 4 dispatches for all 6 etypes ----
    hipMemsetAsync(deg6, 0, 70000 * sizeof(int), stream);
    hipLaunchKernelGGL(hist6_kernel, dim3((E + 255) / 256, 6), dim3(256), 0, stream, gp, deg6);
    hipLaunchKernelGGL(scan6_kernel, dim3(6), dim3(256), 0, stream, deg6, rp6, cursor6);
    hipLaunchKernelGGL(scatter6_kernel, dim3((E + 255) / 256, 6), dim3(256), 0, stream,
                       gp, cursor6, csr_es6);

    // ---- weights -> bf16 ----
    hipLaunchKernelGGL(wcvt_kernel, dim3(16, 8, 3), dim3(256), 0, stream, adapt_w, adapt_wt, 512, 256);
    hipLaunchKernelGGL(wcvt_qkv_kernel, dim3(8, 8, 18), dim3(256), 0, stream, q_w, k_w, v_w, W3);
    hipLaunchKernelGGL(wcvt_kernel, dim3(8, 8, 6), dim3(256), 0, stream, a_w, a_wt, 256, 256);
    hipLaunchKernelGGL(wcvt_kernel, dim3(16, 16, 1), dim3(256), 0, stream, head_w, head_wt, 512, 512);
    hipLaunchKernelGGL(bias_concat_kernel, dim3(18), dim3(256), 0, stream, q_b, k_b, v_b, bias768);

    // ---- adapt (all 3 types in one dispatch; side-writes bf16 feat0 into fbf) ----
    Ptr3f fa; fa.p[0] = feat[0]; fa.p[1] = feat[1]; fa.p[2] = feat[2];
    hipLaunchKernelGGL(adapt_gemm3, dim3(2, 157, 3), dim3(256), 0, stream, fa, adapt_wt, adapt_b, hbf, fbf);

    for (int l = 0; l < 2; ++l) {
        hipLaunchKernelGGL(qkv_gemm3, dim3(6, 157, 3), dim3(256), 0, stream,
                           hbf, W3 + (size_t)l * 3 * 768 * 256, bias768 + (size_t)l * 3 * 768, qkvb);
        hipLaunchKernelGGL(attn_fused_kernel, dim3(5000, 3), dim3(256), 0, stream,
                           qkvb, rp6, csr_es6, e_w + l, e_b + l, aggbf);
        hipLaunchKernelGGL(a_gemm3, dim3(2, 157, 3), dim3(256), 0, stream,
                           aggbf, a_wt + (size_t)l * 3 * 65536, a_b + (size_t)l * 3 * 256,
                           skip + l * 3, hbf);
    }

    hipMemsetAsync(csum, 0, 256 * sizeof(float), stream);
    hipLaunchKernelGGL(colsum_kernel, dim3(128), dim3(256), 0, stream, hbf, csum, NI);
    hipLaunchKernelGGL(head_kernel, dim3(1), dim3(512), 0, stream,
                       csum, (float)NI, pred_w, pred_b, head1_w, head1_b, head_w, head_b, cvec);

    // out = bf16(feats[0]) @ head_w + cvec
    hipLaunchKernelGGL(head_gemm, dim3(4, 157), dim3(256), 0, stream,
                       fbf, head_wt, cvec, (float*)d_out);
}

// Round 11
// 560.871 us; speedup vs baseline: 1.0567x; 1.0101x over previous
//
#include <hip/hip_runtime.h>
#include <hip/hip_bf16.h>
#include <math.h>

typedef short v8s __attribute__((ext_vector_type(8)));
typedef float v4f __attribute__((ext_vector_type(4)));
typedef float v2f __attribute__((ext_vector_type(2)));
typedef unsigned short u16x4 __attribute__((ext_vector_type(4)));

__device__ __forceinline__ unsigned short f2bf(float f) {
    unsigned int u = __float_as_uint(f);
    u += 0x7fff + ((u >> 16) & 1);   // round-to-nearest-even
    return (unsigned short)(u >> 16);
}
__device__ __forceinline__ float bf2f(unsigned short h) {
    return __uint_as_float(((unsigned int)h) << 16);
}
__device__ __forceinline__ unsigned char f2fp8(float f) {
    int e = __builtin_amdgcn_cvt_pk_fp8_f32(f, f, 0, false);
    return (unsigned char)(e & 0xff);
}
// cross-lane add via DPP (VALU-only, replaces ds_bpermute-based __shfl_xor).
// ctrl must be a compile-time constant -> template parameter.
template<int CTRL>
__device__ __forceinline__ float dpp_xadd(float x) {
    int y = __builtin_amdgcn_mov_dpp(__float_as_int(x), CTRL, 0xF, 0xF, true);
    return x + __int_as_float(y);
}

struct GraphPtrs { const int* dst[6]; const int* src[6]; const float* sim[6]; };
struct Ptr3f { const float* p[3]; };

// ---------------- weight transpose + convert: W[K][N] fp32 -> Wt[N][K] bf16 ----------------
__global__ __launch_bounds__(256)
void wcvt_kernel(const float* __restrict__ W, unsigned short* __restrict__ Wt, int K, int N)
{
    __shared__ float tile[32][33];
    const int b = blockIdx.z;
    const float* Wb = W + (size_t)b * K * N;
    unsigned short* Wtb = Wt + (size_t)b * K * N;
    const int k0 = blockIdx.x * 32, n0 = blockIdx.y * 32;
    const int x = threadIdx.x & 31, y = threadIdx.x >> 5;
    #pragma unroll
    for (int j = 0; j < 4; ++j)
        tile[y + 8 * j][x] = Wb[(size_t)(k0 + y + 8 * j) * N + n0 + x];
    __syncthreads();
    #pragma unroll
    for (int j = 0; j < 4; ++j)
        Wtb[(size_t)(n0 + y + 8 * j) * K + k0 + x] = f2bf(tile[x][y + 8 * j]);
}

// q/k/v weights -> W3[(l,t)][768][256] (rows 0-255 q, 256-511 k, 512-767 v)
__global__ __launch_bounds__(256)
void wcvt_qkv_kernel(const float* __restrict__ qw, const float* __restrict__ kw,
                     const float* __restrict__ vw, unsigned short* __restrict__ W3)
{
    __shared__ float tile[32][33];
    const int z = blockIdx.z, lt = z / 3, sec = z - lt * 3;
    const float* src = (sec == 0 ? qw : sec == 1 ? kw : vw) + (size_t)lt * 65536;
    unsigned short* dst = W3 + ((size_t)lt * 768 + sec * 256) * 256;
    const int k0 = blockIdx.x * 32, n0 = blockIdx.y * 32;
    const int x = threadIdx.x & 31, y = threadIdx.x >> 5;
    #pragma unroll
    for (int j = 0; j < 4; ++j)
        tile[y + 8 * j][x] = src[(size_t)(k0 + y + 8 * j) * 256 + n0 + x];
    __syncthreads();
    #pragma unroll
    for (int j = 0; j < 4; ++j)
        dst[(size_t)(n0 + y + 8 * j) * 256 + k0 + x] = f2bf(tile[x][y + 8 * j]);
}

// bias768[lt][768] = concat(q_b[lt], k_b[lt], v_b[lt])
__global__ void bias_concat_kernel(const float* __restrict__ qb, const float* __restrict__ kb,
                                   const float* __restrict__ vb, float* __restrict__ out)
{
    int i = blockIdx.x * 256 + threadIdx.x;
    if (i < 6 * 768) {
        int lt = i / 768, c = i - lt * 768;
        int sec = c >> 8, cc = c & 255;
        const float* s = sec == 0 ? qb : sec == 1 ? kb : vb;
        out[i] = s[lt * 256 + cc];
    }
}

// ---------------- CSR build (all 6 etypes fused) ----------------
__global__ void hist6_kernel(GraphPtrs gp, int* __restrict__ deg6)
{
    constexpr int doff[6] = {0, 10000, 30000, 35000, 55000, 60000};
    const int ei = blockIdx.y;
    int e = blockIdx.x * 256 + threadIdx.x;
    if (e < 100000) atomicAdd(&deg6[doff[ei] + gp.dst[ei][e]], 1);
}

__global__ __launch_bounds__(256)
void scan6_kernel(const int* __restrict__ deg6, int* __restrict__ rp6, int* __restrict__ cursor6)
{
    constexpr int ndv[6]   = {10000, 20000, 5000, 20000, 5000, 10000};
    constexpr int doff[6]  = {0, 10000, 30000, 35000, 55000, 60000};
    constexpr int rpoff[6] = {0, 10001, 30002, 35003, 55004, 60005};
    const int b = blockIdx.x;
    const int nd = ndv[b];
    const int* deg = deg6 + doff[b];
    int* rowptr = rp6 + rpoff[b];
    int* cursor = cursor6 + doff[b];
    const int t = threadIdx.x, lane = t & 63, w = t >> 6;
    __shared__ int wsum[4];
    int carry = 0;
    for (int base = 0; base < nd; base += 1024) {
        int i0 = base + t * 4;
        int x0 = 0, x1 = 0, x2 = 0, x3 = 0;
        if (i0 + 3 < nd) {
            int4 v = *(const int4*)(deg + i0);
            x0 = v.x; x1 = v.y; x2 = v.z; x3 = v.w;
        } else {
            if (i0 < nd) x0 = deg[i0];
            if (i0 + 1 < nd) x1 = deg[i0 + 1];
            if (i0 + 2 < nd) x2 = deg[i0 + 2];
            if (i0 + 3 < nd) x3 = deg[i0 + 3];
        }
        int s1 = x0 + x1, s2 = s1 + x2, tot = s2 + x3;
        int inc = tot;
        #pragma unroll
        for (int o = 1; o < 64; o <<= 1) {
            int y = __shfl_up(inc, o, 64);
            if (lane >= o) inc += y;
        }
        if (lane == 63) wsum[w] = inc;
        __syncthreads();
        int woff = 0;
        #pragma unroll
        for (int ww = 0; ww < 4; ++ww) if (ww < w) woff += wsum[ww];
        int ebase = carry + woff + inc - tot;
        if (i0 < nd)     { rowptr[i0] = ebase;          cursor[i0] = ebase; }
        if (i0 + 1 < nd) { rowptr[i0 + 1] = ebase + x0; cursor[i0 + 1] = ebase + x0; }
        if (i0 + 2 < nd) { rowptr[i0 + 2] = ebase + s1; cursor[i0 + 2] = ebase + s1; }
        if (i0 + 3 < nd) { rowptr[i0 + 3] = ebase + s2; cursor[i0 + 3] = ebase + s2; }
        carry += wsum[0] + wsum[1] + wsum[2] + wsum[3];
        __syncthreads();
    }
    if (t == 0) rowptr[nd] = carry;
}

// scatter: pack (src, sim) into one int2 in CSR order
__global__ void scatter6_kernel(GraphPtrs gp, int* __restrict__ cursor6,
                                int2* __restrict__ csr_es6)
{
    constexpr int doff[6] = {0, 10000, 30000, 35000, 55000, 60000};
    const int ei = blockIdx.y;
    int e = blockIdx.x * 256 + threadIdx.x;
    if (e < 100000) {
        int j = atomicAdd(&cursor6[doff[ei] + gp.dst[ei][e]], 1);
        int2 es; es.x = gp.src[ei][e]; es.y = __float_as_int(gp.sim[ei][e]);
        csr_es6[(size_t)ei * 100000 + j] = es;
    }
}

// ---------------- MFMA GEMM core, fp32 A (converted on the fly), optional bf16 side-write ----------------
__device__ __forceinline__ void gemm_core(const float* __restrict__ A,
    const unsigned short* __restrict__ Wt, int M, int K, int bm, int bn,
    unsigned short* __restrict__ As, unsigned short* __restrict__ Bs, v4f acc[4][4],
    unsigned short* __restrict__ fout)
{
    const int tid = threadIdx.x;
    const int sr = tid >> 1, sc = (tid & 1) * 16;
    const int arow = bm + sr;
    const bool aok = arow < M;
    const float* ap = A + (size_t)arow * K + sc;
    const unsigned short* bp = Wt + (size_t)(bn + sr) * K + sc;
    const int lane = tid & 63, w = tid >> 6, wr = w >> 1, wc = w & 1;
    const int l16 = lane & 15, lg = lane >> 4;
    const int abase = (wr * 64 + l16) * 32 + lg * 8;
    const int bbase = (wc * 64 + l16) * 32 + lg * 8;

    for (int k0 = 0; k0 < K; k0 += 32) {
        float4 a0 = {0,0,0,0}, a1 = a0, a2 = a0, a3 = a0;
        if (aok) {
            a0 = *(const float4*)(ap + k0);
            a1 = *(const float4*)(ap + k0 + 4);
            a2 = *(const float4*)(ap + k0 + 8);
            a3 = *(const float4*)(ap + k0 + 12);
        }
        uint4 b0 = *(const uint4*)(bp + k0);
        uint4 b1 = *(const uint4*)(bp + k0 + 8);

        if (k0) __syncthreads();

        uint4 w0, w1;
        w0.x = (unsigned int)f2bf(a0.x) | ((unsigned int)f2bf(a0.y) << 16);
        w0.y = (unsigned int)f2bf(a0.z) | ((unsigned int)f2bf(a0.w) << 16);
        w0.z = (unsigned int)f2bf(a1.x) | ((unsigned int)f2bf(a1.y) << 16);
        w0.w = (unsigned int)f2bf(a1.z) | ((unsigned int)f2bf(a1.w) << 16);
        w1.x = (unsigned int)f2bf(a2.x) | ((unsigned int)f2bf(a2.y) << 16);
        w1.y = (unsigned int)f2bf(a2.z) | ((unsigned int)f2bf(a2.w) << 16);
        w1.z = (unsigned int)f2bf(a3.x) | ((unsigned int)f2bf(a3.y) << 16);
        w1.w = (unsigned int)f2bf(a3.z) | ((unsigned int)f2bf(a3.w) << 16);
        if (fout && aok) {
            *(uint4*)(fout + (size_t)arow * K + k0 + sc)     = w0;
            *(uint4*)(fout + (size_t)arow * K + k0 + sc + 8) = w1;
        }
        *(uint4*)&As[sr * 32 + sc]     = w0;
        *(uint4*)&As[sr * 32 + sc + 8] = w1;
        *(uint4*)&Bs[sr * 32 + sc]     = b0;
        *(uint4*)&Bs[sr * 32 + sc + 8] = b1;
        __syncthreads();

        v8s af[4], bfr[4];
        #pragma unroll
        for (int f = 0; f < 4; ++f) af[f] = *(const v8s*)&As[abase + f * 512];
        #pragma unroll
        for (int f = 0; f < 4; ++f) bfr[f] = *(const v8s*)&Bs[bbase + f * 512];
        #pragma unroll
        for (int i = 0; i < 4; ++i)
            #pragma unroll
            for (int j = 0; j < 4; ++j)
                acc[i][j] = __builtin_amdgcn_mfma_f32_16x16x32_bf16(af[i], bfr[j], acc[i][j], 0, 0, 0);
    }
}

// ---------------- MFMA GEMM core, bf16 A ----------------
__device__ __forceinline__ void gemm_core_bf(const unsigned short* __restrict__ A,
    const unsigned short* __restrict__ Wt, int M, int K, int bm, int bn,
    unsigned short* __restrict__ As, unsigned short* __restrict__ Bs, v4f acc[4][4])
{
    const int tid = threadIdx.x;
    const int sr = tid >> 1, sc = (tid & 1) * 16;
    const int arow = bm + sr;
    const bool aok = arow < M;
    const unsigned short* ap = A + (size_t)arow * K + sc;
    const unsigned short* bp = Wt + (size_t)(bn + sr) * K + sc;
    const int lane = tid & 63, w = tid >> 6, wr = w >> 1, wc = w & 1;
    const int l16 = lane & 15, lg = lane >> 4;
    const int abase = (wr * 64 + l16) * 32 + lg * 8;
    const int bbase = (wc * 64 + l16) * 32 + lg * 8;

    for (int k0 = 0; k0 < K; k0 += 32) {
        uint4 a0 = {0,0,0,0}, a1 = a0;
        if (aok) {
            a0 = *(const uint4*)(ap + k0);
            a1 = *(const uint4*)(ap + k0 + 8);
        }
        uint4 b0 = *(const uint4*)(bp + k0);
        uint4 b1 = *(const uint4*)(bp + k0 + 8);

        if (k0) __syncthreads();

        *(uint4*)&As[sr * 32 + sc]     = a0;
        *(uint4*)&As[sr * 32 + sc + 8] = a1;
        *(uint4*)&Bs[sr * 32 + sc]     = b0;
        *(uint4*)&Bs[sr * 32 + sc + 8] = b1;
        __syncthreads();

        v8s af[4], bfr[4];
        #pragma unroll
        for (int f = 0; f < 4; ++f) af[f] = *(const v8s*)&As[abase + f * 512];
        #pragma unroll
        for (int f = 0; f < 4; ++f) bfr[f] = *(const v8s*)&Bs[bbase + f * 512];
        #pragma unroll
        for (int i = 0; i < 4; ++i)
            #pragma unroll
            for (int j = 0; j < 4; ++j)
                acc[i][j] = __builtin_amdgcn_mfma_f32_16x16x32_bf16(af[i], bfr[j], acc[i][j], 0, 0, 0);
    }
}

// ---- adapt: h[t] = feats[t] @ adapt_w[t] + adapt_b[t]  (bf16 out; side-writes bf16 feat0) ----
__global__ __launch_bounds__(256)
void adapt_gemm3(Ptr3f A3, const unsigned short* __restrict__ Wt3,
                 const float* __restrict__ bias3, unsigned short* __restrict__ hbf,
                 unsigned short* __restrict__ fbf)
{
    constexpr int Ms[3] = {20000, 10000, 5000};
    constexpr size_t hoff[3] = {0, 20000ull * 256, 30000ull * 256};
    const int z = blockIdx.z;
    const int M = Ms[z];
    const int bm = blockIdx.y * 128, bn = blockIdx.x * 128;
    if (bm >= M) return;
    __shared__ unsigned short As[128 * 32], Bs[128 * 32];
    v4f acc[4][4] = {};
    unsigned short* fout = (z == 0 && blockIdx.x == 0) ? fbf : nullptr;
    gemm_core(A3.p[z], Wt3 + (size_t)z * 256 * 512, M, 512, bm, bn, As, Bs, acc, fout);

    const int lane = threadIdx.x & 63, w = threadIdx.x >> 6;
    const int wr = w >> 1, wc = w & 1, l16 = lane & 15, lg = lane >> 4;
    const int row0 = bm + wr * 64, col0 = bn + wc * 64;
    const float* bias = bias3 + z * 256;
    unsigned short* Cb = hbf + hoff[z];
    float bv[4];
    #pragma unroll
    for (int fn = 0; fn < 4; ++fn) bv[fn] = bias[col0 + fn * 16 + l16];
    #pragma unroll
    for (int fm = 0; fm < 4; ++fm)
        #pragma unroll
        for (int i = 0; i < 4; ++i) {
            int gm = row0 + fm * 16 + lg * 4 + i;
            if (gm >= M) continue;
            #pragma unroll
            for (int fn = 0; fn < 4; ++fn)
                Cb[(size_t)gm * 256 + col0 + fn * 16 + l16] = f2bf(acc[fm][fn][i] + bv[fn]);
        }
}

// ---- qkv: row layout (1024 B/node): q 256xbf16 | kv 512B lane-interleaved fp8 ----
__global__ __launch_bounds__(256)
void qkv_gemm3(const unsigned short* __restrict__ hbf, const unsigned short* __restrict__ W3l,
               const float* __restrict__ bias768l, unsigned char* __restrict__ qkvb)
{
    constexpr int Ms[3] = {20000, 10000, 5000};
    constexpr size_t hoff[3] = {0, 20000ull * 256, 30000ull * 256};
    constexpr size_t qoffB[3] = {0, 20000ull * 1024, 30000ull * 1024};
    const int z = blockIdx.z;
    const int M = Ms[z];
    const int bm = blockIdx.y * 128, bn = blockIdx.x * 128;
    if (bm >= M) return;
    __shared__ unsigned short As[128 * 32], Bs[128 * 32];
    v4f acc[4][4] = {};
    gemm_core_bf(hbf + hoff[z], W3l + (size_t)z * 768 * 256, M, 256, bm, bn, As, Bs, acc);

    const int lane = threadIdx.x & 63, w = threadIdx.x >> 6;
    const int wr = w >> 1, wc = w & 1, l16 = lane & 15, lg = lane >> 4;
    const int row0 = bm + wr * 64, col0 = bn + wc * 64;
    const float* bias = bias768l + z * 768;
    unsigned char* base = qkvb + qoffB[z];
    float bv[4];
    #pragma unroll
    for (int fn = 0; fn < 4; ++fn) bv[fn] = bias[col0 + fn * 16 + l16];
    #pragma unroll
    for (int fm = 0; fm < 4; ++fm)
        #pragma unroll
        for (int i = 0; i < 4; ++i) {
            int gm = row0 + fm * 16 + lg * 4 + i;
            if (gm >= M) continue;
            #pragma unroll
            for (int fn = 0; fn < 4; ++fn) {
                int c = col0 + fn * 16 + l16;
                float val = acc[fm][fn][i] + bv[fn];
                unsigned char* rowp = base + (size_t)gm * 1024;
                if (c < 256) {
                    *(unsigned short*)(rowp + 2 * c) = f2bf(val);
                } else if (c < 512) {
                    int j = c - 256;
                    rowp[512 + 8 * (j >> 2) + (j & 3)] = f2fp8(val);
                } else {
                    int j = c - 512;
                    rowp[512 + 8 * (j >> 2) + 4 + (j & 3)] = f2fp8(val);
                }
            }
        }
}

// ---- a: h[t] = blend(0.5*agg[t]@a_w[l,t] + a_b[l,t], h[t])  (bf16 h in/out) ----
__global__ __launch_bounds__(256)
void a_gemm3(const unsigned short* __restrict__ aggbf, const unsigned short* __restrict__ Wtl,
             const float* __restrict__ biasl, const float* __restrict__ skipl,
             unsigned short* __restrict__ hbf)
{
    constexpr int Ms[3] = {20000, 10000, 5000};
    constexpr size_t hoff[3] = {0, 20000ull * 256, 30000ull * 256};
    const int z = blockIdx.z;
    const int M = Ms[z];
    const int bm = blockIdx.y * 128, bn = blockIdx.x * 128;
    if (bm >= M) return;
    __shared__ unsigned short As[128 * 32], Bs[128 * 32];
    v4f acc[4][4] = {};
    gemm_core_bf(aggbf + hoff[z], Wtl + (size_t)z * 65536, M, 256, bm, bn, As, Bs, acc);

    const int lane = threadIdx.x & 63, w = threadIdx.x >> 6;
    const int wr = w >> 1, wc = w & 1, l16 = lane & 15, lg = lane >> 4;
    const int row0 = bm + wr * 64, col0 = bn + wc * 64;
    const float* bias = biasl + z * 256;
    unsigned short* Cb = hbf + hoff[z];
    float sv = skipl[z];
    float alpha = 1.0f / (1.0f + expf(-sv));
    float beta = 1.0f - alpha;
    float bv[4];
    #pragma unroll
    for (int fn = 0; fn < 4; ++fn) bv[fn] = bias[col0 + fn * 16 + l16];
    #pragma unroll
    for (int fm = 0; fm < 4; ++fm)
        #pragma unroll
        for (int i = 0; i < 4; ++i) {
            int gm = row0 + fm * 16 + lg * 4 + i;
            if (gm >= M) continue;
            #pragma unroll
            for (int fn = 0; fn < 4; ++fn) {
                size_t idx = (size_t)gm * 256 + col0 + fn * 16 + l16;
                float val = acc[fm][fn][i] * 0.5f + bv[fn];
                val = alpha * val + beta * bf2f(Cb[idx]);
                Cb[idx] = f2bf(val);
            }
        }
}

// ---- final: out = fbf(bf16 feats[0]) @ head_w + cvec ----
__global__ __launch_bounds__(256)
void head_gemm(const unsigned short* __restrict__ A, const unsigned short* __restrict__ Wt,
               const float* __restrict__ bias, float* __restrict__ C)
{
    const int M = 20000, N = 512, K = 512;
    const int bm = blockIdx.y * 128, bn = blockIdx.x * 128;
    if (bm >= M) return;
    __shared__ unsigned short As[128 * 32], Bs[128 * 32];
    v4f acc[4][4] = {};
    gemm_core_bf(A, Wt, M, K, bm, bn, As, Bs, acc);

    const int lane = threadIdx.x & 63, w = threadIdx.x >> 6;
    const int wr = w >> 1, wc = w & 1, l16 = lane & 15, lg = lane >> 4;
    const int row0 = bm + wr * 64, col0 = bn + wc * 64;
    float bv[4];
    #pragma unroll
    for (int fn = 0; fn < 4; ++fn) bv[fn] = bias[col0 + fn * 16 + l16];
    #pragma unroll
    for (int fm = 0; fm < 4; ++fm)
        #pragma unroll
        for (int i = 0; i < 4; ++i) {
            int gm = row0 + fm * 16 + lg * 4 + i;
            if (gm >= M) continue;
            #pragma unroll
            for (int fn = 0; fn < 4; ++fn)
                C[(size_t)gm * N + col0 + fn * 16 + l16] = acc[fm][fn][i] + bv[fn];
        }
}

// ---------------- fused attention: depth-2 ring, sequential relations, DPP reduce, branchless ----------------
__global__ __launch_bounds__(256)
void attn_fused_kernel(const unsigned char* __restrict__ qkvb,
                       const int* __restrict__ rp6, const int2* __restrict__ csr_es6,
                       const float* __restrict__ ewp, const float* __restrict__ ebp,
                       unsigned short* __restrict__ aggbf)
{
    constexpr int ndd[3] = {20000, 10000, 5000};
    constexpr size_t qoffB[3] = {0, 20000ull * 1024, 30000ull * 1024};
    constexpr size_t aoffE[3] = {0, 20000ull * 256, 30000ull * 256};
    constexpr int rpoff[6] = {0, 10001, 30002, 35003, 55004, 60005};
    constexpr int eAz[3] = {1, 0, 2}, eBz[3] = {3, 5, 4};    // incoming etypes per dst type
    constexpr int sAz[3] = {1, 0, 0}, sBz[3] = {2, 2, 1};    // their src node types

    const int z = blockIdx.y;
    const int d = blockIdx.x * 4 + (threadIdx.x >> 6);
    if (d >= ndd[z]) return;
    const int t = threadIdx.x & 63;
    // fold 1/sqrt(32) * log2(e) into the edge-linear coefficients (exp2-domain softmax)
    const float kfold = 0.17677669529663687f * 1.4426950408889634f;
    const float ewv = ewp[0] * kfold, ebv = ebp[0] * kfold;

    u16x4 q4 = *(const u16x4*)(qkvb + qoffB[z] + (size_t)d * 1024 + 8 * t);
    const float qx0 = bf2f(q4[0]), qx1 = bf2f(q4[1]), qx2 = bf2f(q4[2]), qx3 = bf2f(q4[3]);

    float4 res = {0.f, 0.f, 0.f, 0.f};
    #pragma unroll
    for (int rr = 0; rr < 2; ++rr) {
        const int ei = rr == 0 ? eAz[z] : eBz[z];
        const int stp = rr == 0 ? sAz[z] : sBz[z];
        const int2* es = csr_es6 + (size_t)ei * 100000;
        const unsigned char* kvp = qkvb + qoffB[stp] + 512 + 8 * t;
        const int beg = rp6[rpoff[ei] + d], end = rp6[rpoff[ei] + d + 1];
        const int n = end - beg;

        float m = -INFINITY, s = 0.0f;
        float4 acc = {0.f, 0.f, 0.f, 0.f};

        // depth-2 ring: two edges in flight
        uint2 kv0 = {0, 0}, kv1 = {0, 0};
        float sim0 = 0.0f, sim1 = 0.0f;
        if (n > 0) { int2 e = es[beg];     sim0 = __int_as_float(e.y); kv0 = *(const uint2*)(kvp + (size_t)e.x * 1024); }
        if (n > 1) { int2 e = es[beg + 1]; sim1 = __int_as_float(e.y); kv1 = *(const uint2*)(kvp + (size_t)e.x * 1024); }
        for (int j = 0; j < n; ++j) {
            uint2 kvc = kv0; float simc = sim0;
            kv0 = kv1; sim0 = sim1;
            if (j + 2 < n) {
                int2 e = es[beg + j + 2];
                sim1 = __int_as_float(e.y);
                kv1 = *(const uint2*)(kvp + (size_t)e.x * 1024);
            }
            v2f k01 = __builtin_amdgcn_cvt_pk_f32_fp8((int)kvc.x, false);
            v2f k23 = __builtin_amdgcn_cvt_pk_f32_fp8((int)kvc.x, true);
            float dot = qx0 * k01[0] + qx1 * k01[1] + qx2 * k23[0] + qx3 * k23[1];
            // 8-lane head reduce via DPP (VALU-only): xor1, xor2, then cross-quad mirror
            dot = dpp_xadd<0xB1>(dot);   // quad_perm [1,0,3,2]  == lane^1
            dot = dpp_xadd<0x4E>(dot);   // quad_perm [2,3,0,1]  == lane^2
            dot = dpp_xadd<0x141>(dot);  // row_half_mirror      == other quad in 8-group
            float sc = dot * fmaf(simc, ewv, ebv);
            // branchless online softmax (first iter: exp2(-inf)=0)
            float nm = fmaxf(m, sc);
            float r  = exp2f(m - nm);
            float ex = exp2f(sc - nm);
            m = nm;
            s = fmaf(s, r, ex);
            v2f v01 = __builtin_amdgcn_cvt_pk_f32_fp8((int)kvc.y, false);
            v2f v23 = __builtin_amdgcn_cvt_pk_f32_fp8((int)kvc.y, true);
            acc.x = fmaf(acc.x, r, ex * v01[0]);
            acc.y = fmaf(acc.y, r, ex * v01[1]);
            acc.z = fmaf(acc.z, r, ex * v23[0]);
            acc.w = fmaf(acc.w, r, ex * v23[1]);
        }
        float inv = (n > 0) ? 1.0f / s : 0.0f;
        res.x += acc.x * inv; res.y += acc.y * inv;
        res.z += acc.z * inv; res.w += acc.w * inv;
    }
    u16x4 out;
    out[0] = f2bf(res.x); out[1] = f2bf(res.y);
    out[2] = f2bf(res.z); out[3] = f2bf(res.w);
    *(u16x4*)(aggbf + aoffE[z] + (size_t)d * 256 + 4 * t) = out;
}

__global__ void colsum_kernel(const unsigned short* __restrict__ hbf, float* __restrict__ out, int N)
{
    int c = threadIdx.x;
    float acc = 0.0f;
    for (int r = blockIdx.x; r < N; r += gridDim.x)
        acc += bf2f(hbf[(size_t)r * 256 + c]);
    atomicAdd(&out[c], acc);
}

__global__ __launch_bounds__(512)
void head_kernel(const float* __restrict__ colsum, float n_img,
                 const float* __restrict__ pred_w, const float* __restrict__ pred_b,
                 const float* __restrict__ head1_w, const float* __restrict__ head1_b,
                 const float* __restrict__ head_w, const float* __restrict__ head_b,
                 float* __restrict__ cvec)
{
    __shared__ float mean[256], o0[256], g[512];
    int t = threadIdx.x;
    if (t < 256) mean[t] = colsum[t] / n_img;
    __syncthreads();
    if (t < 256) {
        float acc = pred_b[t];
        for (int k = 0; k < 256; ++k) acc += mean[k] * pred_w[k * 256 + t];
        o0[t] = acc;
    }
    __syncthreads();
    {
        float acc = head1_b[t];
        for (int k = 0; k < 256; ++k) acc += o0[k] * head1_w[k * 512 + t];
        g[t] = acc;
    }
    __syncthreads();
    {
        float acc = head_b[t];
        for (int k = 0; k < 512; ++k) acc += g[k] * head_w[k * 512 + t];
        cvec[t] = acc;
    }
}

extern "C" void kernel_launch(void* const* d_in, const int* in_sizes, int n_in,
                              void* d_out, int out_size, void* d_ws, size_t ws_size,
                              hipStream_t stream)
{
    const int NI = 20000, E = 100000;

    const float* feat[3] = {(const float*)d_in[0], (const float*)d_in[1], (const float*)d_in[2]};
    const float* adapt_w = (const float*)d_in[3];
    const float* adapt_b = (const float*)d_in[4];
    const float* k_w = (const float*)d_in[5];
    const float* k_b = (const float*)d_in[6];
    const float* q_w = (const float*)d_in[7];
    const float* q_b = (const float*)d_in[8];
    const float* v_w = (const float*)d_in[9];
    const float* v_b = (const float*)d_in[10];
    const float* a_w = (const float*)d_in[11];
    const float* a_b = (const float*)d_in[12];
    const float* e_w = (const float*)d_in[13];
    const float* e_b = (const float*)d_in[14];
    const float* skip = (const float*)d_in[15];
    const float* pred_w = (const float*)d_in[16];
    const float* pred_b = (const float*)d_in[17];
    const float* head1_w = (const float*)d_in[19];
    const float* head1_b = (const float*)d_in[20];
    const float* head_w = (const float*)d_in[21];
    const float* head_b = (const float*)d_in[22];

    GraphPtrs gp;
    for (int i = 0; i < 6; ++i) {
        gp.sim[i] = (const float*)d_in[23 + i];
        gp.src[i] = (const int*)d_in[29 + 2 * i];
        gp.dst[i] = (const int*)d_in[30 + 2 * i];
    }

    float* ws = (float*)d_ws;
    size_t off = 0;
    auto alloc = [&](size_t n) { float* p = ws + off; off += (n + 3) & ~(size_t)3; return p; };
    const size_t NTOT = 35000ull * 256;
    unsigned short* hbf   = (unsigned short*)alloc(NTOT / 2);
    unsigned short* aggbf = (unsigned short*)alloc(NTOT / 2);
    unsigned char* qkvb   = (unsigned char*)alloc(35000ull * 256);   // 1024 B per node
    unsigned short* fbf   = (unsigned short*)alloc(20000ull * 512 / 2);  // bf16 feats[0]
    float* csum = alloc(256);
    float* cvec = alloc(512);
    int* deg6    = (int*)alloc(70000);
    int* cursor6 = (int*)alloc(70000);
    int* rp6     = (int*)alloc(70012);
    int2* csr_es6 = (int2*)alloc(1200000);
    unsigned short* adapt_wt = (unsigned short*)alloc(3 * 512 * 256 / 2);
    unsigned short* W3   = (unsigned short*)alloc(6ull * 768 * 256 / 2);  // [lt][768][256]
    unsigned short* a_wt = (unsigned short*)alloc(6 * 65536 / 2);
    float* bias768 = alloc(6 * 768);
    unsigned short* head_wt = (unsigned short*)alloc(512 * 512 / 2);

    // ---- CSR build: 4 dispatches for all 6 etypes ----
    hipMemsetAsync(deg6, 0, 70000 * sizeof(int), stream);
    hipLaunchKernelGGL(hist6_kernel, dim3((E + 255) / 256, 6), dim3(256), 0, stream, gp, deg6);
    hipLaunchKernelGGL(scan6_kernel, dim3(6), dim3(256), 0, stream, deg6, rp6, cursor6);
    hipLaunchKernelGGL(scatter6_kernel, dim3((E + 255) / 256, 6), dim3(256), 0, stream,
                       gp, cursor6, csr_es6);

    // ---- weights -> bf16 ----
    hipLaunchKernelGGL(wcvt_kernel, dim3(16, 8, 3), dim3(256), 0, stream, adapt_w, adapt_wt, 512, 256);
    hipLaunchKernelGGL(wcvt_qkv_kernel, dim3(8, 8, 18), dim3(256), 0, stream, q_w, k_w, v_w, W3);
    hipLaunchKernelGGL(wcvt_kernel, dim3(8, 8, 6), dim3(256), 0, stream, a_w, a_wt, 256, 256);
    hipLaunchKernelGGL(wcvt_kernel, dim3(16, 16, 1), dim3(256), 0, stream, head_w, head_wt, 512, 512);
    hipLaunchKernelGGL(bias_concat_kernel, dim3(18), dim3(256), 0, stream, q_b, k_b, v_b, bias768);

    // ---- adapt (all 3 types in one dispatch; side-writes bf16 feat0 into fbf) ----
    Ptr3f fa; fa.p[0] = feat[0]; fa.p[1] = feat[1]; fa.p[2] = feat[2];
    hipLaunchKernelGGL(adapt_gemm3, dim3(2, 157, 3), dim3(256), 0, stream, fa, adapt_wt, adapt_b, hbf, fbf);

    for (int l = 0; l < 2; ++l) {
        hipLaunchKernelGGL(qkv_gemm3, dim3(6, 157, 3), dim3(256), 0, stream,
                           hbf, W3 + (size_t)l * 3 * 768 * 256, bias768 + (size_t)l * 3 * 768, qkvb);
        hipLaunchKernelGGL(attn_fused_kernel, dim3(5000, 3), dim3(256), 0, stream,
                           qkvb, rp6, csr_es6, e_w + l, e_b + l, aggbf);
        hipLaunchKernelGGL(a_gemm3, dim3(2, 157, 3), dim3(256), 0, stream,
                           aggbf, a_wt + (size_t)l * 3 * 65536, a_b + (size_t)l * 3 * 256,
                           skip + l * 3, hbf);
    }

    hipMemsetAsync(csum, 0, 256 * sizeof(float), stream);
    hipLaunchKernelGGL(colsum_kernel, dim3(128), dim3(256), 0, stream, hbf, csum, NI);
    hipLaunchKernelGGL(head_kernel, dim3(1), dim3(512), 0, stream,
                       csum, (float)NI, pred_w, pred_b, head1_w, head1_b, head_w, head_b, cvec);

    // out = bf16(feats[0]) @ head_w + cvec
    hipLaunchKernelGGL(head_gemm, dim3(4, 157), dim3(256), 0, stream,
                       fbf, head_wt, cvec, (float*)d_out);
}

// Round 12
// 533.202 us; speedup vs baseline: 1.1116x; 1.0519x over previous
//
#include <hip/hip_runtime.h>
#include <hip/hip_bf16.h>
#include <math.h>

typedef short v8s __attribute__((ext_vector_type(8)));
typedef float v4f __attribute__((ext_vector_type(4)));
typedef float v2f __attribute__((ext_vector_type(2)));
typedef unsigned short u16x4 __attribute__((ext_vector_type(4)));

__device__ __forceinline__ unsigned short f2bf(float f) {
    unsigned int u = __float_as_uint(f);
    u += 0x7fff + ((u >> 16) & 1);   // round-to-nearest-even
    return (unsigned short)(u >> 16);
}
__device__ __forceinline__ float bf2f(unsigned short h) {
    return __uint_as_float(((unsigned int)h) << 16);
}
__device__ __forceinline__ unsigned char f2fp8(float f) {
    int e = __builtin_amdgcn_cvt_pk_fp8_f32(f, f, 0, false);
    return (unsigned char)(e & 0xff);
}
// cross-lane add via DPP (VALU-only); ctrl must be a compile-time constant.
template<int CTRL>
__device__ __forceinline__ float dpp_xadd(float x) {
    int y = __builtin_amdgcn_mov_dpp(__float_as_int(x), CTRL, 0xF, 0xF, true);
    return x + __int_as_float(y);
}

struct GraphPtrs { const int* dst[6]; const int* src[6]; const float* sim[6]; };
struct Ptr3f { const float* p[3]; };

// ---------------- weight transpose + convert: W[K][N] fp32 -> Wt[N][K] bf16 ----------------
__global__ __launch_bounds__(256)
void wcvt_kernel(const float* __restrict__ W, unsigned short* __restrict__ Wt, int K, int N)
{
    __shared__ float tile[32][33];
    const int b = blockIdx.z;
    const float* Wb = W + (size_t)b * K * N;
    unsigned short* Wtb = Wt + (size_t)b * K * N;
    const int k0 = blockIdx.x * 32, n0 = blockIdx.y * 32;
    const int x = threadIdx.x & 31, y = threadIdx.x >> 5;
    #pragma unroll
    for (int j = 0; j < 4; ++j)
        tile[y + 8 * j][x] = Wb[(size_t)(k0 + y + 8 * j) * N + n0 + x];
    __syncthreads();
    #pragma unroll
    for (int j = 0; j < 4; ++j)
        Wtb[(size_t)(n0 + y + 8 * j) * K + k0 + x] = f2bf(tile[x][y + 8 * j]);
}

// q/k/v weights -> W3[(l,t)][768][256] (rows 0-255 q, 256-511 k, 512-767 v)
__global__ __launch_bounds__(256)
void wcvt_qkv_kernel(const float* __restrict__ qw, const float* __restrict__ kw,
                     const float* __restrict__ vw, unsigned short* __restrict__ W3)
{
    __shared__ float tile[32][33];
    const int z = blockIdx.z, lt = z / 3, sec = z - lt * 3;
    const float* src = (sec == 0 ? qw : sec == 1 ? kw : vw) + (size_t)lt * 65536;
    unsigned short* dst = W3 + ((size_t)lt * 768 + sec * 256) * 256;
    const int k0 = blockIdx.x * 32, n0 = blockIdx.y * 32;
    const int x = threadIdx.x & 31, y = threadIdx.x >> 5;
    #pragma unroll
    for (int j = 0; j < 4; ++j)
        tile[y + 8 * j][x] = src[(size_t)(k0 + y + 8 * j) * 256 + n0 + x];
    __syncthreads();
    #pragma unroll
    for (int j = 0; j < 4; ++j)
        dst[(size_t)(n0 + y + 8 * j) * 256 + k0 + x] = f2bf(tile[x][y + 8 * j]);
}

// bias768[lt][768] = concat(q_b[lt], k_b[lt], v_b[lt])
__global__ void bias_concat_kernel(const float* __restrict__ qb, const float* __restrict__ kb,
                                   const float* __restrict__ vb, float* __restrict__ out)
{
    int i = blockIdx.x * 256 + threadIdx.x;
    if (i < 6 * 768) {
        int lt = i / 768, c = i - lt * 768;
        int sec = c >> 8, cc = c & 255;
        const float* s = sec == 0 ? qb : sec == 1 ? kb : vb;
        out[i] = s[lt * 256 + cc];
    }
}

// ---------------- CSR build (all 6 etypes fused) ----------------
__global__ void hist6_kernel(GraphPtrs gp, int* __restrict__ deg6)
{
    constexpr int doff[6] = {0, 10000, 30000, 35000, 55000, 60000};
    const int ei = blockIdx.y;
    int e = blockIdx.x * 256 + threadIdx.x;
    if (e < 100000) atomicAdd(&deg6[doff[ei] + gp.dst[ei][e]], 1);
}

__global__ __launch_bounds__(256)
void scan6_kernel(const int* __restrict__ deg6, int* __restrict__ rp6, int* __restrict__ cursor6)
{
    constexpr int ndv[6]   = {10000, 20000, 5000, 20000, 5000, 10000};
    constexpr int doff[6]  = {0, 10000, 30000, 35000, 55000, 60000};
    constexpr int rpoff[6] = {0, 10001, 30002, 35003, 55004, 60005};
    const int b = blockIdx.x;
    const int nd = ndv[b];
    const int* deg = deg6 + doff[b];
    int* rowptr = rp6 + rpoff[b];
    int* cursor = cursor6 + doff[b];
    const int t = threadIdx.x, lane = t & 63, w = t >> 6;
    __shared__ int wsum[4];
    int carry = 0;
    for (int base = 0; base < nd; base += 1024) {
        int i0 = base + t * 4;
        int x0 = 0, x1 = 0, x2 = 0, x3 = 0;
        if (i0 + 3 < nd) {
            int4 v = *(const int4*)(deg + i0);
            x0 = v.x; x1 = v.y; x2 = v.z; x3 = v.w;
        } else {
            if (i0 < nd) x0 = deg[i0];
            if (i0 + 1 < nd) x1 = deg[i0 + 1];
            if (i0 + 2 < nd) x2 = deg[i0 + 2];
            if (i0 + 3 < nd) x3 = deg[i0 + 3];
        }
        int s1 = x0 + x1, s2 = s1 + x2, tot = s2 + x3;
        int inc = tot;
        #pragma unroll
        for (int o = 1; o < 64; o <<= 1) {
            int y = __shfl_up(inc, o, 64);
            if (lane >= o) inc += y;
        }
        if (lane == 63) wsum[w] = inc;
        __syncthreads();
        int woff = 0;
        #pragma unroll
        for (int ww = 0; ww < 4; ++ww) if (ww < w) woff += wsum[ww];
        int ebase = carry + woff + inc - tot;
        if (i0 < nd)     { rowptr[i0] = ebase;          cursor[i0] = ebase; }
        if (i0 + 1 < nd) { rowptr[i0 + 1] = ebase + x0; cursor[i0 + 1] = ebase + x0; }
        if (i0 + 2 < nd) { rowptr[i0 + 2] = ebase + s1; cursor[i0 + 2] = ebase + s1; }
        if (i0 + 3 < nd) { rowptr[i0 + 3] = ebase + s2; cursor[i0 + 3] = ebase + s2; }
        carry += wsum[0] + wsum[1] + wsum[2] + wsum[3];
        __syncthreads();
    }
    if (t == 0) rowptr[nd] = carry;
}

// scatter: pack (src, sim) into one int2 in CSR order
__global__ void scatter6_kernel(GraphPtrs gp, int* __restrict__ cursor6,
                                int2* __restrict__ csr_es6)
{
    constexpr int doff[6] = {0, 10000, 30000, 35000, 55000, 60000};
    const int ei = blockIdx.y;
    int e = blockIdx.x * 256 + threadIdx.x;
    if (e < 100000) {
        int j = atomicAdd(&cursor6[doff[ei] + gp.dst[ei][e]], 1);
        int2 es; es.x = gp.src[ei][e]; es.y = __float_as_int(gp.sim[ei][e]);
        csr_es6[(size_t)ei * 100000 + j] = es;
    }
}

// ---------------- MFMA GEMM core, fp32 A (converted on the fly), optional bf16 side-write ----------------
__device__ __forceinline__ void gemm_core(const float* __restrict__ A,
    const unsigned short* __restrict__ Wt, int M, int K, int bm, int bn,
    unsigned short* __restrict__ As, unsigned short* __restrict__ Bs, v4f acc[4][4],
    unsigned short* __restrict__ fout)
{
    const int tid = threadIdx.x;
    const int sr = tid >> 1, sc = (tid & 1) * 16;
    const int arow = bm + sr;
    const bool aok = arow < M;
    const float* ap = A + (size_t)arow * K + sc;
    const unsigned short* bp = Wt + (size_t)(bn + sr) * K + sc;
    const int lane = tid & 63, w = tid >> 6, wr = w >> 1, wc = w & 1;
    const int l16 = lane & 15, lg = lane >> 4;
    const int abase = (wr * 64 + l16) * 32 + lg * 8;
    const int bbase = (wc * 64 + l16) * 32 + lg * 8;

    for (int k0 = 0; k0 < K; k0 += 32) {
        float4 a0 = {0,0,0,0}, a1 = a0, a2 = a0, a3 = a0;
        if (aok) {
            a0 = *(const float4*)(ap + k0);
            a1 = *(const float4*)(ap + k0 + 4);
            a2 = *(const float4*)(ap + k0 + 8);
            a3 = *(const float4*)(ap + k0 + 12);
        }
        uint4 b0 = *(const uint4*)(bp + k0);
        uint4 b1 = *(const uint4*)(bp + k0 + 8);

        if (k0) __syncthreads();

        uint4 w0, w1;
        w0.x = (unsigned int)f2bf(a0.x) | ((unsigned int)f2bf(a0.y) << 16);
        w0.y = (unsigned int)f2bf(a0.z) | ((unsigned int)f2bf(a0.w) << 16);
        w0.z = (unsigned int)f2bf(a1.x) | ((unsigned int)f2bf(a1.y) << 16);
        w0.w = (unsigned int)f2bf(a1.z) | ((unsigned int)f2bf(a1.w) << 16);
        w1.x = (unsigned int)f2bf(a2.x) | ((unsigned int)f2bf(a2.y) << 16);
        w1.y = (unsigned int)f2bf(a2.z) | ((unsigned int)f2bf(a2.w) << 16);
        w1.z = (unsigned int)f2bf(a3.x) | ((unsigned int)f2bf(a3.y) << 16);
        w1.w = (unsigned int)f2bf(a3.z) | ((unsigned int)f2bf(a3.w) << 16);
        if (fout && aok) {
            *(uint4*)(fout + (size_t)arow * K + k0 + sc)     = w0;
            *(uint4*)(fout + (size_t)arow * K + k0 + sc + 8) = w1;
        }
        *(uint4*)&As[sr * 32 + sc]     = w0;
        *(uint4*)&As[sr * 32 + sc + 8] = w1;
        *(uint4*)&Bs[sr * 32 + sc]     = b0;
        *(uint4*)&Bs[sr * 32 + sc + 8] = b1;
        __syncthreads();

        v8s af[4], bfr[4];
        #pragma unroll
        for (int f = 0; f < 4; ++f) af[f] = *(const v8s*)&As[abase + f * 512];
        #pragma unroll
        for (int f = 0; f < 4; ++f) bfr[f] = *(const v8s*)&Bs[bbase + f * 512];
        #pragma unroll
        for (int i = 0; i < 4; ++i)
            #pragma unroll
            for (int j = 0; j < 4; ++j)
                acc[i][j] = __builtin_amdgcn_mfma_f32_16x16x32_bf16(af[i], bfr[j], acc[i][j], 0, 0, 0);
    }
}

// ---------------- MFMA GEMM core, bf16 A ----------------
__device__ __forceinline__ void gemm_core_bf(const unsigned short* __restrict__ A,
    const unsigned short* __restrict__ Wt, int M, int K, int bm, int bn,
    unsigned short* __restrict__ As, unsigned short* __restrict__ Bs, v4f acc[4][4])
{
    const int tid = threadIdx.x;
    const int sr = tid >> 1, sc = (tid & 1) * 16;
    const int arow = bm + sr;
    const bool aok = arow < M;
    const unsigned short* ap = A + (size_t)arow * K + sc;
    const unsigned short* bp = Wt + (size_t)(bn + sr) * K + sc;
    const int lane = tid & 63, w = tid >> 6, wr = w >> 1, wc = w & 1;
    const int l16 = lane & 15, lg = lane >> 4;
    const int abase = (wr * 64 + l16) * 32 + lg * 8;
    const int bbase = (wc * 64 + l16) * 32 + lg * 8;

    for (int k0 = 0; k0 < K; k0 += 32) {
        uint4 a0 = {0,0,0,0}, a1 = a0;
        if (aok) {
            a0 = *(const uint4*)(ap + k0);
            a1 = *(const uint4*)(ap + k0 + 8);
        }
        uint4 b0 = *(const uint4*)(bp + k0);
        uint4 b1 = *(const uint4*)(bp + k0 + 8);

        if (k0) __syncthreads();

        *(uint4*)&As[sr * 32 + sc]     = a0;
        *(uint4*)&As[sr * 32 + sc + 8] = a1;
        *(uint4*)&Bs[sr * 32 + sc]     = b0;
        *(uint4*)&Bs[sr * 32 + sc + 8] = b1;
        __syncthreads();

        v8s af[4], bfr[4];
        #pragma unroll
        for (int f = 0; f < 4; ++f) af[f] = *(const v8s*)&As[abase + f * 512];
        #pragma unroll
        for (int f = 0; f < 4; ++f) bfr[f] = *(const v8s*)&Bs[bbase + f * 512];
        #pragma unroll
        for (int i = 0; i < 4; ++i)
            #pragma unroll
            for (int j = 0; j < 4; ++j)
                acc[i][j] = __builtin_amdgcn_mfma_f32_16x16x32_bf16(af[i], bfr[j], acc[i][j], 0, 0, 0);
    }
}

// ---- adapt: h[t] = feats[t] @ adapt_w[t] + adapt_b[t]  (bf16 out; side-writes bf16 feat0) ----
__global__ __launch_bounds__(256)
void adapt_gemm3(Ptr3f A3, const unsigned short* __restrict__ Wt3,
                 const float* __restrict__ bias3, unsigned short* __restrict__ hbf,
                 unsigned short* __restrict__ fbf)
{
    constexpr int Ms[3] = {20000, 10000, 5000};
    constexpr size_t hoff[3] = {0, 20000ull * 256, 30000ull * 256};
    const int z = blockIdx.z;
    const int M = Ms[z];
    const int bm = blockIdx.y * 128, bn = blockIdx.x * 128;
    if (bm >= M) return;
    __shared__ unsigned short As[128 * 32], Bs[128 * 32];
    v4f acc[4][4] = {};
    unsigned short* fout = (z == 0 && blockIdx.x == 0) ? fbf : nullptr;
    gemm_core(A3.p[z], Wt3 + (size_t)z * 256 * 512, M, 512, bm, bn, As, Bs, acc, fout);

    const int lane = threadIdx.x & 63, w = threadIdx.x >> 6;
    const int wr = w >> 1, wc = w & 1, l16 = lane & 15, lg = lane >> 4;
    const int row0 = bm + wr * 64, col0 = bn + wc * 64;
    const float* bias = bias3 + z * 256;
    unsigned short* Cb = hbf + hoff[z];
    float bv[4];
    #pragma unroll
    for (int fn = 0; fn < 4; ++fn) bv[fn] = bias[col0 + fn * 16 + l16];
    #pragma unroll
    for (int fm = 0; fm < 4; ++fm)
        #pragma unroll
        for (int i = 0; i < 4; ++i) {
            int gm = row0 + fm * 16 + lg * 4 + i;
            if (gm >= M) continue;
            #pragma unroll
            for (int fn = 0; fn < 4; ++fn)
                Cb[(size_t)gm * 256 + col0 + fn * 16 + l16] = f2bf(acc[fm][fn][i] + bv[fn]);
        }
}

// ---- qkv: row layout (1024 B/node): q 256xbf16 | kv 512B lane-interleaved fp8 ----
__global__ __launch_bounds__(256)
void qkv_gemm3(const unsigned short* __restrict__ hbf, const unsigned short* __restrict__ W3l,
               const float* __restrict__ bias768l, unsigned char* __restrict__ qkvb)
{
    constexpr int Ms[3] = {20000, 10000, 5000};
    constexpr size_t hoff[3] = {0, 20000ull * 256, 30000ull * 256};
    constexpr size_t qoffB[3] = {0, 20000ull * 1024, 30000ull * 1024};
    const int z = blockIdx.z;
    const int M = Ms[z];
    const int bm = blockIdx.y * 128, bn = blockIdx.x * 128;
    if (bm >= M) return;
    __shared__ unsigned short As[128 * 32], Bs[128 * 32];
    v4f acc[4][4] = {};
    gemm_core_bf(hbf + hoff[z], W3l + (size_t)z * 768 * 256, M, 256, bm, bn, As, Bs, acc);

    const int lane = threadIdx.x & 63, w = threadIdx.x >> 6;
    const int wr = w >> 1, wc = w & 1, l16 = lane & 15, lg = lane >> 4;
    const int row0 = bm + wr * 64, col0 = bn + wc * 64;
    const float* bias = bias768l + z * 768;
    unsigned char* base = qkvb + qoffB[z];
    float bv[4];
    #pragma unroll
    for (int fn = 0; fn < 4; ++fn) bv[fn] = bias[col0 + fn * 16 + l16];
    #pragma unroll
    for (int fm = 0; fm < 4; ++fm)
        #pragma unroll
        for (int i = 0; i < 4; ++i) {
            int gm = row0 + fm * 16 + lg * 4 + i;
            if (gm >= M) continue;
            #pragma unroll
            for (int fn = 0; fn < 4; ++fn) {
                int c = col0 + fn * 16 + l16;
                float val = acc[fm][fn][i] + bv[fn];
                unsigned char* rowp = base + (size_t)gm * 1024;
                if (c < 256) {
                    *(unsigned short*)(rowp + 2 * c) = f2bf(val);
                } else if (c < 512) {
                    int j = c - 256;
                    rowp[512 + 8 * (j >> 2) + (j & 3)] = f2fp8(val);
                } else {
                    int j = c - 512;
                    rowp[512 + 8 * (j >> 2) + 4 + (j & 3)] = f2fp8(val);
                }
            }
        }
}

// ---- a: h[t] = blend(0.5*agg[t]@a_w[l,t] + a_b[l,t], h[t])  (bf16 h in/out) ----
__global__ __launch_bounds__(256)
void a_gemm3(const unsigned short* __restrict__ aggbf, const unsigned short* __restrict__ Wtl,
             const float* __restrict__ biasl, const float* __restrict__ skipl,
             unsigned short* __restrict__ hbf)
{
    constexpr int Ms[3] = {20000, 10000, 5000};
    constexpr size_t hoff[3] = {0, 20000ull * 256, 30000ull * 256};
    const int z = blockIdx.z;
    const int M = Ms[z];
    const int bm = blockIdx.y * 128, bn = blockIdx.x * 128;
    if (bm >= M) return;
    __shared__ unsigned short As[128 * 32], Bs[128 * 32];
    v4f acc[4][4] = {};
    gemm_core_bf(aggbf + hoff[z], Wtl + (size_t)z * 65536, M, 256, bm, bn, As, Bs, acc);

    const int lane = threadIdx.x & 63, w = threadIdx.x >> 6;
    const int wr = w >> 1, wc = w & 1, l16 = lane & 15, lg = lane >> 4;
    const int row0 = bm + wr * 64, col0 = bn + wc * 64;
    const float* bias = biasl + z * 256;
    unsigned short* Cb = hbf + hoff[z];
    float sv = skipl[z];
    float alpha = 1.0f / (1.0f + expf(-sv));
    float beta = 1.0f - alpha;
    float bv[4];
    #pragma unroll
    for (int fn = 0; fn < 4; ++fn) bv[fn] = bias[col0 + fn * 16 + l16];
    #pragma unroll
    for (int fm = 0; fm < 4; ++fm)
        #pragma unroll
        for (int i = 0; i < 4; ++i) {
            int gm = row0 + fm * 16 + lg * 4 + i;
            if (gm >= M) continue;
            #pragma unroll
            for (int fn = 0; fn < 4; ++fn) {
                size_t idx = (size_t)gm * 256 + col0 + fn * 16 + l16;
                float val = acc[fm][fn][i] * 0.5f + bv[fn];
                val = alpha * val + beta * bf2f(Cb[idx]);
                Cb[idx] = f2bf(val);
            }
        }
}

// ---- final: out = fbf(bf16 feats[0]) @ head_w + cvec ----
__global__ __launch_bounds__(256)
void head_gemm(const unsigned short* __restrict__ A, const unsigned short* __restrict__ Wt,
               const float* __restrict__ bias, float* __restrict__ C)
{
    const int M = 20000, N = 512, K = 512;
    const int bm = blockIdx.y * 128, bn = blockIdx.x * 128;
    if (bm >= M) return;
    __shared__ unsigned short As[128 * 32], Bs[128 * 32];
    v4f acc[4][4] = {};
    gemm_core_bf(A, Wt, M, K, bm, bn, As, Bs, acc);

    const int lane = threadIdx.x & 63, w = threadIdx.x >> 6;
    const int wr = w >> 1, wc = w & 1, l16 = lane & 15, lg = lane >> 4;
    const int row0 = bm + wr * 64, col0 = bn + wc * 64;
    float bv[4];
    #pragma unroll
    for (int fn = 0; fn < 4; ++fn) bv[fn] = bias[col0 + fn * 16 + l16];
    #pragma unroll
    for (int fm = 0; fm < 4; ++fm)
        #pragma unroll
        for (int i = 0; i < 4; ++i) {
            int gm = row0 + fm * 16 + lg * 4 + i;
            if (gm >= M) continue;
            #pragma unroll
            for (int fn = 0; fn < 4; ++fn)
                C[(size_t)gm * N + col0 + fn * 16 + l16] = acc[fm][fn][i] + bv[fn];
        }
}

// ---------------- fused attention: 2 edges per wave (lane halves), split-softmax merge ----------------
// lane t: half = t>>5 (even/odd edges), h = t&31 owns channels 8h..8h+7 (head = h>>2).
__global__ __launch_bounds__(256)
void attn_fused_kernel(const unsigned char* __restrict__ qkvb,
                       const int* __restrict__ rp6, const int2* __restrict__ csr_es6,
                       const float* __restrict__ ewp, const float* __restrict__ ebp,
                       unsigned short* __restrict__ aggbf)
{
    constexpr int ndd[3] = {20000, 10000, 5000};
    constexpr size_t qoffB[3] = {0, 20000ull * 1024, 30000ull * 1024};
    constexpr size_t aoffE[3] = {0, 20000ull * 256, 30000ull * 256};
    constexpr int rpoff[6] = {0, 10001, 30002, 35003, 55004, 60005};
    constexpr int eAz[3] = {1, 0, 2}, eBz[3] = {3, 5, 4};    // incoming etypes per dst type
    constexpr int sAz[3] = {1, 0, 0}, sBz[3] = {2, 2, 1};    // their src node types

    const int z = blockIdx.y;
    const int d = blockIdx.x * 4 + (threadIdx.x >> 6);
    if (d >= ndd[z]) return;
    const int t = threadIdx.x & 63;
    const int half = t >> 5, h = t & 31;
    // fold 1/sqrt(32) * log2(e) into the edge-linear coefficients (exp2-domain softmax)
    const float kfold = 0.17677669529663687f * 1.4426950408889634f;
    const float ewv = ewp[0] * kfold, ebv = ebp[0] * kfold;

    // q channels 8h..8h+7 (both halves load the same row)
    uint4 qw4 = *(const uint4*)(qkvb + qoffB[z] + (size_t)d * 1024 + 16 * h);
    const float qf0 = bf2f((unsigned short)(qw4.x & 0xffff));
    const float qf1 = bf2f((unsigned short)(qw4.x >> 16));
    const float qf2 = bf2f((unsigned short)(qw4.y & 0xffff));
    const float qf3 = bf2f((unsigned short)(qw4.y >> 16));
    const float qf4 = bf2f((unsigned short)(qw4.z & 0xffff));
    const float qf5 = bf2f((unsigned short)(qw4.z >> 16));
    const float qf6 = bf2f((unsigned short)(qw4.w & 0xffff));
    const float qf7 = bf2f((unsigned short)(qw4.w >> 16));

    float r0 = 0.f, r1 = 0.f, r2 = 0.f, r3 = 0.f, r4 = 0.f, r5 = 0.f, r6 = 0.f, r7 = 0.f;

    #pragma unroll
    for (int rr = 0; rr < 2; ++rr) {
        const int ei = rr == 0 ? eAz[z] : eBz[z];
        const int stp = rr == 0 ? sAz[z] : sBz[z];
        const int2* es = csr_es6 + (size_t)ei * 100000;
        const unsigned char* kvp = qkvb + qoffB[stp] + 512 + 16 * h;
        const int beg = rp6[rpoff[ei] + d], end = rp6[rpoff[ei] + d + 1];
        const int n = end - beg;
        if (n == 0) continue;

        float m = -1e30f, s = 0.f;
        float a0 = 0.f, a1 = 0.f, a2 = 0.f, a3 = 0.f, a4 = 0.f, a5 = 0.f, a6 = 0.f, a7 = 0.f;

        // depth-2 ring on edge PAIRS; this half handles edges (jj + half)
        uint4 kv0 = {0,0,0,0}, kv1 = kv0;
        float sm0 = 0.f, sm1 = 0.f;
        {
            int i0 = half, i1 = 2 + half;
            if (i0 < n) { int2 e = es[beg + i0]; sm0 = __int_as_float(e.y); kv0 = *(const uint4*)(kvp + (size_t)e.x * 1024); }
            if (i1 < n) { int2 e = es[beg + i1]; sm1 = __int_as_float(e.y); kv1 = *(const uint4*)(kvp + (size_t)e.x * 1024); }
        }
        for (int jj = 0; jj < n; jj += 2) {
            uint4 kvc = kv0; float simc = sm0;
            kv0 = kv1; sm0 = sm1;
            int inx = jj + 4 + half;
            if (inx < n) { int2 e = es[beg + inx]; sm1 = __int_as_float(e.y); kv1 = *(const uint4*)(kvp + (size_t)e.x * 1024); }
            if (jj + half < n) {
                v2f k01 = __builtin_amdgcn_cvt_pk_f32_fp8((int)kvc.x, false);
                v2f k23 = __builtin_amdgcn_cvt_pk_f32_fp8((int)kvc.x, true);
                v2f k45 = __builtin_amdgcn_cvt_pk_f32_fp8((int)kvc.z, false);
                v2f k67 = __builtin_amdgcn_cvt_pk_f32_fp8((int)kvc.z, true);
                float dot = qf0 * k01[0] + qf1 * k01[1] + qf2 * k23[0] + qf3 * k23[1]
                          + qf4 * k45[0] + qf5 * k45[1] + qf6 * k67[0] + qf7 * k67[1];
                // head reduce: 4 lanes per head -> 2 quad-local DPP steps
                dot = dpp_xadd<0xB1>(dot);   // lane^1
                dot = dpp_xadd<0x4E>(dot);   // lane^2
                float sc = dot * fmaf(simc, ewv, ebv);
                float nm = fmaxf(m, sc);
                float rsc = exp2f(m - nm);
                float ex = exp2f(sc - nm);
                m = nm;
                s = fmaf(s, rsc, ex);
                v2f v01 = __builtin_amdgcn_cvt_pk_f32_fp8((int)kvc.y, false);
                v2f v23 = __builtin_amdgcn_cvt_pk_f32_fp8((int)kvc.y, true);
                v2f v45 = __builtin_amdgcn_cvt_pk_f32_fp8((int)kvc.w, false);
                v2f v67 = __builtin_amdgcn_cvt_pk_f32_fp8((int)kvc.w, true);
                a0 = fmaf(a0, rsc, ex * v01[0]);
                a1 = fmaf(a1, rsc, ex * v01[1]);
                a2 = fmaf(a2, rsc, ex * v23[0]);
                a3 = fmaf(a3, rsc, ex * v23[1]);
                a4 = fmaf(a4, rsc, ex * v45[0]);
                a5 = fmaf(a5, rsc, ex * v45[1]);
                a6 = fmaf(a6, rsc, ex * v67[0]);
                a7 = fmaf(a7, rsc, ex * v67[1]);
            }
        }
        // merge even/odd partial softmaxes across lane^32
        float mo = __shfl_xor(m, 32);
        float so = __shfl_xor(s, 32);
        float mm = fmaxf(m, mo);
        float rs = exp2f(m - mm), ro = exp2f(mo - mm);
        float stot = fmaf(s, rs, so * ro);     // n>0 -> stot>0
        float inv = 1.0f / stot;
        float o0 = __shfl_xor(a0, 32), o1 = __shfl_xor(a1, 32);
        float o2 = __shfl_xor(a2, 32), o3 = __shfl_xor(a3, 32);
        float o4 = __shfl_xor(a4, 32), o5 = __shfl_xor(a5, 32);
        float o6 = __shfl_xor(a6, 32), o7 = __shfl_xor(a7, 32);
        r0 += fmaf(a0, rs, o0 * ro) * inv;
        r1 += fmaf(a1, rs, o1 * ro) * inv;
        r2 += fmaf(a2, rs, o2 * ro) * inv;
        r3 += fmaf(a3, rs, o3 * ro) * inv;
        r4 += fmaf(a4, rs, o4 * ro) * inv;
        r5 += fmaf(a5, rs, o5 * ro) * inv;
        r6 += fmaf(a6, rs, o6 * ro) * inv;
        r7 += fmaf(a7, rs, o7 * ro) * inv;
    }

    if (half == 0) {
        uint4 o;
        o.x = (unsigned int)f2bf(r0) | ((unsigned int)f2bf(r1) << 16);
        o.y = (unsigned int)f2bf(r2) | ((unsigned int)f2bf(r3) << 16);
        o.z = (unsigned int)f2bf(r4) | ((unsigned int)f2bf(r5) << 16);
        o.w = (unsigned int)f2bf(r6) | ((unsigned int)f2bf(r7) << 16);
        *(uint4*)((unsigned char*)(aggbf + aoffE[z]) + (size_t)d * 512 + 16 * h) = o;
    }
}

__global__ void colsum_kernel(const unsigned short* __restrict__ hbf, float* __restrict__ out, int N)
{
    int c = threadIdx.x;
    float acc = 0.0f;
    for (int r = blockIdx.x; r < N; r += gridDim.x)
        acc += bf2f(hbf[(size_t)r * 256 + c]);
    atomicAdd(&out[c], acc);
}

__global__ __launch_bounds__(512)
void head_kernel(const float* __restrict__ colsum, float n_img,
                 const float* __restrict__ pred_w, const float* __restrict__ pred_b,
                 const float* __restrict__ head1_w, const float* __restrict__ head1_b,
                 const float* __restrict__ head_w, const float* __restrict__ head_b,
                 float* __restrict__ cvec)
{
    __shared__ float mean[256], o0[256], g[512];
    int t = threadIdx.x;
    if (t < 256) mean[t] = colsum[t] / n_img;
    __syncthreads();
    if (t < 256) {
        float acc = pred_b[t];
        for (int k = 0; k < 256; ++k) acc += mean[k] * pred_w[k * 256 + t];
        o0[t] = acc;
    }
    __syncthreads();
    {
        float acc = head1_b[t];
        for (int k = 0; k < 256; ++k) acc += o0[k] * head1_w[k * 512 + t];
        g[t] = acc;
    }
    __syncthreads();
    {
        float acc = head_b[t];
        for (int k = 0; k < 512; ++k) acc += g[k] * head_w[k * 512 + t];
        cvec[t] = acc;
    }
}

extern "C" void kernel_launch(void* const* d_in, const int* in_sizes, int n_in,
                              void* d_out, int out_size, void* d_ws, size_t ws_size,
                              hipStream_t stream)
{
    const int NI = 20000, E = 100000;

    const float* feat[3] = {(const float*)d_in[0], (const float*)d_in[1], (const float*)d_in[2]};
    const float* adapt_w = (const float*)d_in[3];
    const float* adapt_b = (const float*)d_in[4];
    const float* k_w = (const float*)d_in[5];
    const float* k_b = (const float*)d_in[6];
    const float* q_w = (const float*)d_in[7];
    const float* q_b = (const float*)d_in[8];
    const float* v_w = (const float*)d_in[9];
    const float* v_b = (const float*)d_in[10];
    const float* a_w = (const float*)d_in[11];
    const float* a_b = (const float*)d_in[12];
    const float* e_w = (const float*)d_in[13];
    const float* e_b = (const float*)d_in[14];
    const float* skip = (const float*)d_in[15];
    const float* pred_w = (const float*)d_in[16];
    const float* pred_b = (const float*)d_in[17];
    const float* head1_w = (const float*)d_in[19];
    const float* head1_b = (const float*)d_in[20];
    const float* head_w = (const float*)d_in[21];
    const float* head_b = (const float*)d_in[22];

    GraphPtrs gp;
    for (int i = 0; i < 6; ++i) {
        gp.sim[i] = (const float*)d_in[23 + i];
        gp.src[i] = (const int*)d_in[29 + 2 * i];
        gp.dst[i] = (const int*)d_in[30 + 2 * i];
    }

    float* ws = (float*)d_ws;
    size_t off = 0;
    auto alloc = [&](size_t n) { float* p = ws + off; off += (n + 3) & ~(size_t)3; return p; };
    const size_t NTOT = 35000ull * 256;
    unsigned short* hbf   = (unsigned short*)alloc(NTOT / 2);
    unsigned short* aggbf = (unsigned short*)alloc(NTOT / 2);
    unsigned char* qkvb   = (unsigned char*)alloc(35000ull * 256);   // 1024 B per node
    unsigned short* fbf   = (unsigned short*)alloc(20000ull * 512 / 2);  // bf16 feats[0]
    float* csum = alloc(256);
    float* cvec = alloc(512);
    int* deg6    = (int*)alloc(70000);
    int* cursor6 = (int*)alloc(70000);
    int* rp6     = (int*)alloc(70012);
    int2* csr_es6 = (int2*)alloc(1200000);
    unsigned short* adapt_wt = (unsigned short*)alloc(3 * 512 * 256 / 2);
    unsigned short* W3   = (unsigned short*)alloc(6ull * 768 * 256 / 2);  // [lt][768][256]
    unsigned short* a_wt = (unsigned short*)alloc(6 * 65536 / 2);
    float* bias768 = alloc(6 * 768);
    unsigned short* head_wt = (unsigned short*)alloc(512 * 512 / 2);

    // ---- CSR build: 4 dispatches for all 6 etypes ----
    hipMemsetAsync(deg6, 0, 70000 * sizeof(int), stream);
    hipLaunchKernelGGL(hist6_kernel, dim3((E + 255) / 256, 6), dim3(256), 0, stream, gp, deg6);
    hipLaunchKernelGGL(scan6_kernel, dim3(6), dim3(256), 0, stream, deg6, rp6, cursor6);
    hipLaunchKernelGGL(scatter6_kernel, dim3((E + 255) / 256, 6), dim3(256), 0, stream,
                       gp, cursor6, csr_es6);

    // ---- weights -> bf16 ----
    hipLaunchKernelGGL(wcvt_kernel, dim3(16, 8, 3), dim3(256), 0, stream, adapt_w, adapt_wt, 512, 256);
    hipLaunchKernelGGL(wcvt_qkv_kernel, dim3(8, 8, 18), dim3(256), 0, stream, q_w, k_w, v_w, W3);
    hipLaunchKernelGGL(wcvt_kernel, dim3(8, 8, 6), dim3(256), 0, stream, a_w, a_wt, 256, 256);
    hipLaunchKernelGGL(wcvt_kernel, dim3(16, 16, 1), dim3(256), 0, stream, head_w, head_wt, 512, 512);
    hipLaunchKernelGGL(bias_concat_kernel, dim3(18), dim3(256), 0, stream, q_b, k_b, v_b, bias768);

    // ---- adapt (all 3 types in one dispatch; side-writes bf16 feat0 into fbf) ----
    Ptr3f fa; fa.p[0] = feat[0]; fa.p[1] = feat[1]; fa.p[2] = feat[2];
    hipLaunchKernelGGL(adapt_gemm3, dim3(2, 157, 3), dim3(256), 0, stream, fa, adapt_wt, adapt_b, hbf, fbf);

    for (int l = 0; l < 2; ++l) {
        hipLaunchKernelGGL(qkv_gemm3, dim3(6, 157, 3), dim3(256), 0, stream,
                           hbf, W3 + (size_t)l * 3 * 768 * 256, bias768 + (size_t)l * 3 * 768, qkvb);
        hipLaunchKernelGGL(attn_fused_kernel, dim3(5000, 3), dim3(256), 0, stream,
                           qkvb, rp6, csr_es6, e_w + l, e_b + l, aggbf);
        hipLaunchKernelGGL(a_gemm3, dim3(2, 157, 3), dim3(256), 0, stream,
                           aggbf, a_wt + (size_t)l * 3 * 65536, a_b + (size_t)l * 3 * 256,
                           skip + l * 3, hbf);
    }

    hipMemsetAsync(csum, 0, 256 * sizeof(float), stream);
    hipLaunchKernelGGL(colsum_kernel, dim3(128), dim3(256), 0, stream, hbf, csum, NI);
    hipLaunchKernelGGL(head_kernel, dim3(1), dim3(512), 0, stream,
                       csum, (float)NI, pred_w, pred_b, head1_w, head1_b, head_w, head_b, cvec);

    // out = bf16(feats[0]) @ head_w + cvec
    hipLaunchKernelGGL(head_gemm, dim3(4, 157), dim3(256), 0, stream,
                       fbf, head_wt, cvec, (float*)d_out);
}

// Round 13
// 508.604 us; speedup vs baseline: 1.1653x; 1.0484x over previous
//
#include <hip/hip_runtime.h>
#include <hip/hip_bf16.h>
#include <math.h>

typedef short v8s __attribute__((ext_vector_type(8)));
typedef float v4f __attribute__((ext_vector_type(4)));
typedef float v2f __attribute__((ext_vector_type(2)));
typedef unsigned short u16x4 __attribute__((ext_vector_type(4)));

__device__ __forceinline__ unsigned short f2bf(float f) {
    unsigned int u = __float_as_uint(f);
    u += 0x7fff + ((u >> 16) & 1);   // round-to-nearest-even
    return (unsigned short)(u >> 16);
}
__device__ __forceinline__ float bf2f(unsigned short h) {
    return __uint_as_float(((unsigned int)h) << 16);
}
__device__ __forceinline__ unsigned char f2fp8(float f) {
    int e = __builtin_amdgcn_cvt_pk_fp8_f32(f, f, 0, false);
    return (unsigned char)(e & 0xff);
}
// cross-lane add via DPP (VALU-only); ctrl must be a compile-time constant.
template<int CTRL>
__device__ __forceinline__ float dpp_xadd(float x) {
    int y = __builtin_amdgcn_mov_dpp(__float_as_int(x), CTRL, 0xF, 0xF, true);
    return x + __int_as_float(y);
}

struct GraphPtrs { const int* dst[6]; const int* src[6]; const float* sim[6]; };
struct Ptr3f { const float* p[3]; };

// ---------------- weight transpose + convert: W[K][N] fp32 -> Wt[N][K] bf16 ----------------
__global__ __launch_bounds__(256)
void wcvt_kernel(const float* __restrict__ W, unsigned short* __restrict__ Wt, int K, int N)
{
    __shared__ float tile[32][33];
    const int b = blockIdx.z;
    const float* Wb = W + (size_t)b * K * N;
    unsigned short* Wtb = Wt + (size_t)b * K * N;
    const int k0 = blockIdx.x * 32, n0 = blockIdx.y * 32;
    const int x = threadIdx.x & 31, y = threadIdx.x >> 5;
    #pragma unroll
    for (int j = 0; j < 4; ++j)
        tile[y + 8 * j][x] = Wb[(size_t)(k0 + y + 8 * j) * N + n0 + x];
    __syncthreads();
    #pragma unroll
    for (int j = 0; j < 4; ++j)
        Wtb[(size_t)(n0 + y + 8 * j) * K + k0 + x] = f2bf(tile[x][y + 8 * j]);
}

// q/k/v weights -> W3[(l,t)][768][256] (rows 0-255 q, 256-511 k, 512-767 v)
__global__ __launch_bounds__(256)
void wcvt_qkv_kernel(const float* __restrict__ qw, const float* __restrict__ kw,
                     const float* __restrict__ vw, unsigned short* __restrict__ W3)
{
    __shared__ float tile[32][33];
    const int z = blockIdx.z, lt = z / 3, sec = z - lt * 3;
    const float* src = (sec == 0 ? qw : sec == 1 ? kw : vw) + (size_t)lt * 65536;
    unsigned short* dst = W3 + ((size_t)lt * 768 + sec * 256) * 256;
    const int k0 = blockIdx.x * 32, n0 = blockIdx.y * 32;
    const int x = threadIdx.x & 31, y = threadIdx.x >> 5;
    #pragma unroll
    for (int j = 0; j < 4; ++j)
        tile[y + 8 * j][x] = src[(size_t)(k0 + y + 8 * j) * 256 + n0 + x];
    __syncthreads();
    #pragma unroll
    for (int j = 0; j < 4; ++j)
        dst[(size_t)(n0 + y + 8 * j) * 256 + k0 + x] = f2bf(tile[x][y + 8 * j]);
}

// bias768[lt][768] = concat(q_b[lt], k_b[lt], v_b[lt])
__global__ void bias_concat_kernel(const float* __restrict__ qb, const float* __restrict__ kb,
                                   const float* __restrict__ vb, float* __restrict__ out)
{
    int i = blockIdx.x * 256 + threadIdx.x;
    if (i < 6 * 768) {
        int lt = i / 768, c = i - lt * 768;
        int sec = c >> 8, cc = c & 255;
        const float* s = sec == 0 ? qb : sec == 1 ? kb : vb;
        out[i] = s[lt * 256 + cc];
    }
}

// ---------------- CSR build (all 6 etypes fused) ----------------
__global__ void hist6_kernel(GraphPtrs gp, int* __restrict__ deg6)
{
    constexpr int doff[6] = {0, 10000, 30000, 35000, 55000, 60000};
    const int ei = blockIdx.y;
    int e = blockIdx.x * 256 + threadIdx.x;
    if (e < 100000) atomicAdd(&deg6[doff[ei] + gp.dst[ei][e]], 1);
}

__global__ __launch_bounds__(256)
void scan6_kernel(const int* __restrict__ deg6, int* __restrict__ rp6, int* __restrict__ cursor6)
{
    constexpr int ndv[6]   = {10000, 20000, 5000, 20000, 5000, 10000};
    constexpr int doff[6]  = {0, 10000, 30000, 35000, 55000, 60000};
    constexpr int rpoff[6] = {0, 10001, 30002, 35003, 55004, 60005};
    const int b = blockIdx.x;
    const int nd = ndv[b];
    const int* deg = deg6 + doff[b];
    int* rowptr = rp6 + rpoff[b];
    int* cursor = cursor6 + doff[b];
    const int t = threadIdx.x, lane = t & 63, w = t >> 6;
    __shared__ int wsum[4];
    int carry = 0;
    for (int base = 0; base < nd; base += 1024) {
        int i0 = base + t * 4;
        int x0 = 0, x1 = 0, x2 = 0, x3 = 0;
        if (i0 + 3 < nd) {
            int4 v = *(const int4*)(deg + i0);
            x0 = v.x; x1 = v.y; x2 = v.z; x3 = v.w;
        } else {
            if (i0 < nd) x0 = deg[i0];
            if (i0 + 1 < nd) x1 = deg[i0 + 1];
            if (i0 + 2 < nd) x2 = deg[i0 + 2];
            if (i0 + 3 < nd) x3 = deg[i0 + 3];
        }
        int s1 = x0 + x1, s2 = s1 + x2, tot = s2 + x3;
        int inc = tot;
        #pragma unroll
        for (int o = 1; o < 64; o <<= 1) {
            int y = __shfl_up(inc, o, 64);
            if (lane >= o) inc += y;
        }
        if (lane == 63) wsum[w] = inc;
        __syncthreads();
        int woff = 0;
        #pragma unroll
        for (int ww = 0; ww < 4; ++ww) if (ww < w) woff += wsum[ww];
        int ebase = carry + woff + inc - tot;
        if (i0 < nd)     { rowptr[i0] = ebase;          cursor[i0] = ebase; }
        if (i0 + 1 < nd) { rowptr[i0 + 1] = ebase + x0; cursor[i0 + 1] = ebase + x0; }
        if (i0 + 2 < nd) { rowptr[i0 + 2] = ebase + s1; cursor[i0 + 2] = ebase + s1; }
        if (i0 + 3 < nd) { rowptr[i0 + 3] = ebase + s2; cursor[i0 + 3] = ebase + s2; }
        carry += wsum[0] + wsum[1] + wsum[2] + wsum[3];
        __syncthreads();
    }
    if (t == 0) rowptr[nd] = carry;
}

// scatter: pack (src, sim) into one int2 in CSR order
__global__ void scatter6_kernel(GraphPtrs gp, int* __restrict__ cursor6,
                                int2* __restrict__ csr_es6)
{
    constexpr int doff[6] = {0, 10000, 30000, 35000, 55000, 60000};
    const int ei = blockIdx.y;
    int e = blockIdx.x * 256 + threadIdx.x;
    if (e < 100000) {
        int j = atomicAdd(&cursor6[doff[ei] + gp.dst[ei][e]], 1);
        int2 es; es.x = gp.src[ei][e]; es.y = __float_as_int(gp.sim[ei][e]);
        csr_es6[(size_t)ei * 100000 + j] = es;
    }
}

// ---------------- MFMA GEMM core, fp32 A (converted on the fly), optional bf16 side-write ----------------
__device__ __forceinline__ void gemm_core(const float* __restrict__ A,
    const unsigned short* __restrict__ Wt, int M, int K, int bm, int bn,
    unsigned short* __restrict__ As, unsigned short* __restrict__ Bs, v4f acc[4][4],
    unsigned short* __restrict__ fout)
{
    const int tid = threadIdx.x;
    const int sr = tid >> 1, sc = (tid & 1) * 16;
    const int arow = bm + sr;
    const bool aok = arow < M;
    const float* ap = A + (size_t)arow * K + sc;
    const unsigned short* bp = Wt + (size_t)(bn + sr) * K + sc;
    const int lane = tid & 63, w = tid >> 6, wr = w >> 1, wc = w & 1;
    const int l16 = lane & 15, lg = lane >> 4;
    const int abase = (wr * 64 + l16) * 32 + lg * 8;
    const int bbase = (wc * 64 + l16) * 32 + lg * 8;

    for (int k0 = 0; k0 < K; k0 += 32) {
        float4 a0 = {0,0,0,0}, a1 = a0, a2 = a0, a3 = a0;
        if (aok) {
            a0 = *(const float4*)(ap + k0);
            a1 = *(const float4*)(ap + k0 + 4);
            a2 = *(const float4*)(ap + k0 + 8);
            a3 = *(const float4*)(ap + k0 + 12);
        }
        uint4 b0 = *(const uint4*)(bp + k0);
        uint4 b1 = *(const uint4*)(bp + k0 + 8);

        if (k0) __syncthreads();

        uint4 w0, w1;
        w0.x = (unsigned int)f2bf(a0.x) | ((unsigned int)f2bf(a0.y) << 16);
        w0.y = (unsigned int)f2bf(a0.z) | ((unsigned int)f2bf(a0.w) << 16);
        w0.z = (unsigned int)f2bf(a1.x) | ((unsigned int)f2bf(a1.y) << 16);
        w0.w = (unsigned int)f2bf(a1.z) | ((unsigned int)f2bf(a1.w) << 16);
        w1.x = (unsigned int)f2bf(a2.x) | ((unsigned int)f2bf(a2.y) << 16);
        w1.y = (unsigned int)f2bf(a2.z) | ((unsigned int)f2bf(a2.w) << 16);
        w1.z = (unsigned int)f2bf(a3.x) | ((unsigned int)f2bf(a3.y) << 16);
        w1.w = (unsigned int)f2bf(a3.z) | ((unsigned int)f2bf(a3.w) << 16);
        if (fout && aok) {
            *(uint4*)(fout + (size_t)arow * K + k0 + sc)     = w0;
            *(uint4*)(fout + (size_t)arow * K + k0 + sc + 8) = w1;
        }
        *(uint4*)&As[sr * 32 + sc]     = w0;
        *(uint4*)&As[sr * 32 + sc + 8] = w1;
        *(uint4*)&Bs[sr * 32 + sc]     = b0;
        *(uint4*)&Bs[sr * 32 + sc + 8] = b1;
        __syncthreads();

        v8s af[4], bfr[4];
        #pragma unroll
        for (int f = 0; f < 4; ++f) af[f] = *(const v8s*)&As[abase + f * 512];
        #pragma unroll
        for (int f = 0; f < 4; ++f) bfr[f] = *(const v8s*)&Bs[bbase + f * 512];
        #pragma unroll
        for (int i = 0; i < 4; ++i)
            #pragma unroll
            for (int j = 0; j < 4; ++j)
                acc[i][j] = __builtin_amdgcn_mfma_f32_16x16x32_bf16(af[i], bfr[j], acc[i][j], 0, 0, 0);
    }
}

// ---------------- MFMA GEMM core, bf16 A — direct global->LDS DMA staging ----------------
__device__ __forceinline__ void gemm_core_bf(const unsigned short* __restrict__ A,
    const unsigned short* __restrict__ Wt, int M, int K, int bm, int bn,
    unsigned short* __restrict__ As, unsigned short* __restrict__ Bs, v4f acc[4][4])
{
    const int tid = threadIdx.x;
    const int lane = tid & 63, w = tid >> 6, wr = w >> 1, wc = w & 1;
    const int l16 = lane & 15, lg = lane >> 4;
    const int abase = (wr * 64 + l16) * 32 + lg * 8;
    const int bbase = (wc * 64 + l16) * 32 + lg * 8;

    // wave w stages tile rows 32w..32w+31 (two 16-row DMA groups).
    // lane l -> row +(l>>2), bf16 col chunk (l&3)*8 (16 B); LDS dest = wave base + lane*16.
    const int r0 = 32 * w + (lane >> 2);
    const int cb = (lane & 3) * 8;
    const unsigned short* ag0 = A  + (size_t)(bm + r0) * K + cb;
    const unsigned short* ag1 = A  + (size_t)(bm + r0 + 16) * K + cb;
    const unsigned short* bg0 = Wt + (size_t)(bn + r0) * K + cb;
    const unsigned short* bg1 = Wt + (size_t)(bn + r0 + 16) * K + cb;
    const bool aok0 = (bm + r0) < M, aok1 = (bm + r0 + 16) < M;
    unsigned short* al0 = As + (32 * w) * 32;
    unsigned short* al1 = As + (32 * w + 16) * 32;
    unsigned short* bl0 = Bs + (32 * w) * 32;
    unsigned short* bl1 = Bs + (32 * w + 16) * 32;

    for (int k0 = 0; k0 < K; k0 += 32) {
        if (k0) __syncthreads();   // previous tile fully consumed
        if (aok0) __builtin_amdgcn_global_load_lds(
            (const __attribute__((address_space(1))) void*)(ag0 + k0),
            (__attribute__((address_space(3))) void*)al0, 16, 0, 0);
        if (aok1) __builtin_amdgcn_global_load_lds(
            (const __attribute__((address_space(1))) void*)(ag1 + k0),
            (__attribute__((address_space(3))) void*)al1, 16, 0, 0);
        __builtin_amdgcn_global_load_lds(
            (const __attribute__((address_space(1))) void*)(bg0 + k0),
            (__attribute__((address_space(3))) void*)bl0, 16, 0, 0);
        __builtin_amdgcn_global_load_lds(
            (const __attribute__((address_space(1))) void*)(bg1 + k0),
            (__attribute__((address_space(3))) void*)bl1, 16, 0, 0);
        __syncthreads();           // compiler inserts vmcnt(0) drain before barrier

        v8s af[4], bfr[4];
        #pragma unroll
        for (int f = 0; f < 4; ++f) af[f] = *(const v8s*)&As[abase + f * 512];
        #pragma unroll
        for (int f = 0; f < 4; ++f) bfr[f] = *(const v8s*)&Bs[bbase + f * 512];
        #pragma unroll
        for (int i = 0; i < 4; ++i)
            #pragma unroll
            for (int j = 0; j < 4; ++j)
                acc[i][j] = __builtin_amdgcn_mfma_f32_16x16x32_bf16(af[i], bfr[j], acc[i][j], 0, 0, 0);
    }
}

// ---- adapt: h[t] = feats[t] @ adapt_w[t] + adapt_b[t]  (bf16 out; side-writes bf16 feat0) ----
__global__ __launch_bounds__(256)
void adapt_gemm3(Ptr3f A3, const unsigned short* __restrict__ Wt3,
                 const float* __restrict__ bias3, unsigned short* __restrict__ hbf,
                 unsigned short* __restrict__ fbf)
{
    constexpr int Ms[3] = {20000, 10000, 5000};
    constexpr size_t hoff[3] = {0, 20000ull * 256, 30000ull * 256};
    const int z = blockIdx.z;
    const int M = Ms[z];
    const int bm = blockIdx.y * 128, bn = blockIdx.x * 128;
    if (bm >= M) return;
    __shared__ unsigned short As[128 * 32], Bs[128 * 32];
    v4f acc[4][4] = {};
    unsigned short* fout = (z == 0 && blockIdx.x == 0) ? fbf : nullptr;
    gemm_core(A3.p[z], Wt3 + (size_t)z * 256 * 512, M, 512, bm, bn, As, Bs, acc, fout);

    const int lane = threadIdx.x & 63, w = threadIdx.x >> 6;
    const int wr = w >> 1, wc = w & 1, l16 = lane & 15, lg = lane >> 4;
    const int row0 = bm + wr * 64, col0 = bn + wc * 64;
    const float* bias = bias3 + z * 256;
    unsigned short* Cb = hbf + hoff[z];
    float bv[4];
    #pragma unroll
    for (int fn = 0; fn < 4; ++fn) bv[fn] = bias[col0 + fn * 16 + l16];
    #pragma unroll
    for (int fm = 0; fm < 4; ++fm)
        #pragma unroll
        for (int i = 0; i < 4; ++i) {
            int gm = row0 + fm * 16 + lg * 4 + i;
            if (gm >= M) continue;
            #pragma unroll
            for (int fn = 0; fn < 4; ++fn)
                Cb[(size_t)gm * 256 + col0 + fn * 16 + l16] = f2bf(acc[fm][fn][i] + bv[fn]);
        }
}

// ---- qkv: row layout (1024 B/node): q 256xbf16 | kv 512B lane-interleaved fp8 ----
__global__ __launch_bounds__(256)
void qkv_gemm3(const unsigned short* __restrict__ hbf, const unsigned short* __restrict__ W3l,
               const float* __restrict__ bias768l, unsigned char* __restrict__ qkvb)
{
    constexpr int Ms[3] = {20000, 10000, 5000};
    constexpr size_t hoff[3] = {0, 20000ull * 256, 30000ull * 256};
    constexpr size_t qoffB[3] = {0, 20000ull * 1024, 30000ull * 1024};
    const int z = blockIdx.z;
    const int M = Ms[z];
    const int bm = blockIdx.y * 128, bn = blockIdx.x * 128;
    if (bm >= M) return;
    __shared__ unsigned short As[128 * 32], Bs[128 * 32];
    v4f acc[4][4] = {};
    gemm_core_bf(hbf + hoff[z], W3l + (size_t)z * 768 * 256, M, 256, bm, bn, As, Bs, acc);

    const int lane = threadIdx.x & 63, w = threadIdx.x >> 6;
    const int wr = w >> 1, wc = w & 1, l16 = lane & 15, lg = lane >> 4;
    const int row0 = bm + wr * 64, col0 = bn + wc * 64;
    const float* bias = bias768l + z * 768;
    unsigned char* base = qkvb + qoffB[z];
    float bv[4];
    #pragma unroll
    for (int fn = 0; fn < 4; ++fn) bv[fn] = bias[col0 + fn * 16 + l16];
    #pragma unroll
    for (int fm = 0; fm < 4; ++fm)
        #pragma unroll
        for (int i = 0; i < 4; ++i) {
            int gm = row0 + fm * 16 + lg * 4 + i;
            if (gm >= M) continue;
            #pragma unroll
            for (int fn = 0; fn < 4; ++fn) {
                int c = col0 + fn * 16 + l16;
                float val = acc[fm][fn][i] + bv[fn];
                unsigned char* rowp = base + (size_t)gm * 1024;
                if (c < 256) {
                    *(unsigned short*)(rowp + 2 * c) = f2bf(val);
                } else if (c < 512) {
                    int j = c - 256;
                    rowp[512 + 8 * (j >> 2) + (j & 3)] = f2fp8(val);
                } else {
                    int j = c - 512;
                    rowp[512 + 8 * (j >> 2) + 4 + (j & 3)] = f2fp8(val);
                }
            }
        }
}

// ---- a: h[t] = blend(0.5*agg[t]@a_w[l,t] + a_b[l,t], h[t])  (bf16 h in/out) ----
__global__ __launch_bounds__(256)
void a_gemm3(const unsigned short* __restrict__ aggbf, const unsigned short* __restrict__ Wtl,
             const float* __restrict__ biasl, const float* __restrict__ skipl,
             unsigned short* __restrict__ hbf)
{
    constexpr int Ms[3] = {20000, 10000, 5000};
    constexpr size_t hoff[3] = {0, 20000ull * 256, 30000ull * 256};
    const int z = blockIdx.z;
    const int M = Ms[z];
    const int bm = blockIdx.y * 128, bn = blockIdx.x * 128;
    if (bm >= M) return;
    __shared__ unsigned short As[128 * 32], Bs[128 * 32];
    v4f acc[4][4] = {};
    gemm_core_bf(aggbf + hoff[z], Wtl + (size_t)z * 65536, M, 256, bm, bn, As, Bs, acc);

    const int lane = threadIdx.x & 63, w = threadIdx.x >> 6;
    const int wr = w >> 1, wc = w & 1, l16 = lane & 15, lg = lane >> 4;
    const int row0 = bm + wr * 64, col0 = bn + wc * 64;
    const float* bias = biasl + z * 256;
    unsigned short* Cb = hbf + hoff[z];
    float sv = skipl[z];
    float alpha = 1.0f / (1.0f + expf(-sv));
    float beta = 1.0f - alpha;
    float bv[4];
    #pragma unroll
    for (int fn = 0; fn < 4; ++fn) bv[fn] = bias[col0 + fn * 16 + l16];
    #pragma unroll
    for (int fm = 0; fm < 4; ++fm)
        #pragma unroll
        for (int i = 0; i < 4; ++i) {
            int gm = row0 + fm * 16 + lg * 4 + i;
            if (gm >= M) continue;
            #pragma unroll
            for (int fn = 0; fn < 4; ++fn) {
                size_t idx = (size_t)gm * 256 + col0 + fn * 16 + l16;
                float val = acc[fm][fn][i] * 0.5f + bv[fn];
                val = alpha * val + beta * bf2f(Cb[idx]);
                Cb[idx] = f2bf(val);
            }
        }
}

// ---- final: out = fbf(bf16 feats[0]) @ head_w + cvec ----
__global__ __launch_bounds__(256)
void head_gemm(const unsigned short* __restrict__ A, const unsigned short* __restrict__ Wt,
               const float* __restrict__ bias, float* __restrict__ C)
{
    const int M = 20000, N = 512, K = 512;
    const int bm = blockIdx.y * 128, bn = blockIdx.x * 128;
    if (bm >= M) return;
    __shared__ unsigned short As[128 * 32], Bs[128 * 32];
    v4f acc[4][4] = {};
    gemm_core_bf(A, Wt, M, K, bm, bn, As, Bs, acc);

    const int lane = threadIdx.x & 63, w = threadIdx.x >> 6;
    const int wr = w >> 1, wc = w & 1, l16 = lane & 15, lg = lane >> 4;
    const int row0 = bm + wr * 64, col0 = bn + wc * 64;
    float bv[4];
    #pragma unroll
    for (int fn = 0; fn < 4; ++fn) bv[fn] = bias[col0 + fn * 16 + l16];
    #pragma unroll
    for (int fm = 0; fm < 4; ++fm)
        #pragma unroll
        for (int i = 0; i < 4; ++i) {
            int gm = row0 + fm * 16 + lg * 4 + i;
            if (gm >= M) continue;
            #pragma unroll
            for (int fn = 0; fn < 4; ++fn)
                C[(size_t)gm * N + col0 + fn * 16 + l16] = acc[fm][fn][i] + bv[fn];
        }
}

// ---------------- fused attention: 2 edges per wave (lane halves), split-softmax merge ----------------
__global__ __launch_bounds__(256)
void attn_fused_kernel(const unsigned char* __restrict__ qkvb,
                       const int* __restrict__ rp6, const int2* __restrict__ csr_es6,
                       const float* __restrict__ ewp, const float* __restrict__ ebp,
                       unsigned short* __restrict__ aggbf)
{
    constexpr int ndd[3] = {20000, 10000, 5000};
    constexpr size_t qoffB[3] = {0, 20000ull * 1024, 30000ull * 1024};
    constexpr size_t aoffE[3] = {0, 20000ull * 256, 30000ull * 256};
    constexpr int rpoff[6] = {0, 10001, 30002, 35003, 55004, 60005};
    constexpr int eAz[3] = {1, 0, 2}, eBz[3] = {3, 5, 4};    // incoming etypes per dst type
    constexpr int sAz[3] = {1, 0, 0}, sBz[3] = {2, 2, 1};    // their src node types

    const int z = blockIdx.y;
    const int d = blockIdx.x * 4 + (threadIdx.x >> 6);
    if (d >= ndd[z]) return;
    const int t = threadIdx.x & 63;
    const int half = t >> 5, h = t & 31;
    // fold 1/sqrt(32) * log2(e) into the edge-linear coefficients (exp2-domain softmax)
    const float kfold = 0.17677669529663687f * 1.4426950408889634f;
    const float ewv = ewp[0] * kfold, ebv = ebp[0] * kfold;

    // q channels 8h..8h+7 (both halves load the same row)
    uint4 qw4 = *(const uint4*)(qkvb + qoffB[z] + (size_t)d * 1024 + 16 * h);
    const float qf0 = bf2f((unsigned short)(qw4.x & 0xffff));
    const float qf1 = bf2f((unsigned short)(qw4.x >> 16));
    const float qf2 = bf2f((unsigned short)(qw4.y & 0xffff));
    const float qf3 = bf2f((unsigned short)(qw4.y >> 16));
    const float qf4 = bf2f((unsigned short)(qw4.z & 0xffff));
    const float qf5 = bf2f((unsigned short)(qw4.z >> 16));
    const float qf6 = bf2f((unsigned short)(qw4.w & 0xffff));
    const float qf7 = bf2f((unsigned short)(qw4.w >> 16));

    float r0 = 0.f, r1 = 0.f, r2 = 0.f, r3 = 0.f, r4 = 0.f, r5 = 0.f, r6 = 0.f, r7 = 0.f;

    #pragma unroll
    for (int rr = 0; rr < 2; ++rr) {
        const int ei = rr == 0 ? eAz[z] : eBz[z];
        const int stp = rr == 0 ? sAz[z] : sBz[z];
        const int2* es = csr_es6 + (size_t)ei * 100000;
        const unsigned char* kvp = qkvb + qoffB[stp] + 512 + 16 * h;
        const int beg = rp6[rpoff[ei] + d], end = rp6[rpoff[ei] + d + 1];
        const int n = end - beg;
        if (n == 0) continue;

        float m = -1e30f, s = 0.f;
        float a0 = 0.f, a1 = 0.f, a2 = 0.f, a3 = 0.f, a4 = 0.f, a5 = 0.f, a6 = 0.f, a7 = 0.f;

        // depth-2 ring on edge PAIRS; this half handles edges (jj + half)
        uint4 kv0 = {0,0,0,0}, kv1 = kv0;
        float sm0 = 0.f, sm1 = 0.f;
        {
            int i0 = half, i1 = 2 + half;
            if (i0 < n) { int2 e = es[beg + i0]; sm0 = __int_as_float(e.y); kv0 = *(const uint4*)(kvp + (size_t)e.x * 1024); }
            if (i1 < n) { int2 e = es[beg + i1]; sm1 = __int_as_float(e.y); kv1 = *(const uint4*)(kvp + (size_t)e.x * 1024); }
        }
        for (int jj = 0; jj < n; jj += 2) {
            uint4 kvc = kv0; float simc = sm0;
            kv0 = kv1; sm0 = sm1;
            int inx = jj + 4 + half;
            if (inx < n) { int2 e = es[beg + inx]; sm1 = __int_as_float(e.y); kv1 = *(const uint4*)(kvp + (size_t)e.x * 1024); }
            if (jj + half < n) {
                v2f k01 = __builtin_amdgcn_cvt_pk_f32_fp8((int)kvc.x, false);
                v2f k23 = __builtin_amdgcn_cvt_pk_f32_fp8((int)kvc.x, true);
                v2f k45 = __builtin_amdgcn_cvt_pk_f32_fp8((int)kvc.z, false);
                v2f k67 = __builtin_amdgcn_cvt_pk_f32_fp8((int)kvc.z, true);
                float dot = qf0 * k01[0] + qf1 * k01[1] + qf2 * k23[0] + qf3 * k23[1]
                          + qf4 * k45[0] + qf5 * k45[1] + qf6 * k67[0] + qf7 * k67[1];
                // head reduce: 4 lanes per head -> 2 quad-local DPP steps
                dot = dpp_xadd<0xB1>(dot);   // lane^1
                dot = dpp_xadd<0x4E>(dot);   // lane^2
                float sc = dot * fmaf(simc, ewv, ebv);
                float nm = fmaxf(m, sc);
                float rsc = exp2f(m - nm);
                float ex = exp2f(sc - nm);
                m = nm;
                s = fmaf(s, rsc, ex);
                v2f v01 = __builtin_amdgcn_cvt_pk_f32_fp8((int)kvc.y, false);
                v2f v23 = __builtin_amdgcn_cvt_pk_f32_fp8((int)kvc.y, true);
                v2f v45 = __builtin_amdgcn_cvt_pk_f32_fp8((int)kvc.w, false);
                v2f v67 = __builtin_amdgcn_cvt_pk_f32_fp8((int)kvc.w, true);
                a0 = fmaf(a0, rsc, ex * v01[0]);
                a1 = fmaf(a1, rsc, ex * v01[1]);
                a2 = fmaf(a2, rsc, ex * v23[0]);
                a3 = fmaf(a3, rsc, ex * v23[1]);
                a4 = fmaf(a4, rsc, ex * v45[0]);
                a5 = fmaf(a5, rsc, ex * v45[1]);
                a6 = fmaf(a6, rsc, ex * v67[0]);
                a7 = fmaf(a7, rsc, ex * v67[1]);
            }
        }
        // merge even/odd partial softmaxes across lane^32
        float mo = __shfl_xor(m, 32);
        float so = __shfl_xor(s, 32);
        float mm = fmaxf(m, mo);
        float rs = exp2f(m - mm), ro = exp2f(mo - mm);
        float stot = fmaf(s, rs, so * ro);     // n>0 -> stot>0
        float inv = 1.0f / stot;
        float o0 = __shfl_xor(a0, 32), o1 = __shfl_xor(a1, 32);
        float o2 = __shfl_xor(a2, 32), o3 = __shfl_xor(a3, 32);
        float o4 = __shfl_xor(a4, 32), o5 = __shfl_xor(a5, 32);
        float o6 = __shfl_xor(a6, 32), o7 = __shfl_xor(a7, 32);
        r0 += fmaf(a0, rs, o0 * ro) * inv;
        r1 += fmaf(a1, rs, o1 * ro) * inv;
        r2 += fmaf(a2, rs, o2 * ro) * inv;
        r3 += fmaf(a3, rs, o3 * ro) * inv;
        r4 += fmaf(a4, rs, o4 * ro) * inv;
        r5 += fmaf(a5, rs, o5 * ro) * inv;
        r6 += fmaf(a6, rs, o6 * ro) * inv;
        r7 += fmaf(a7, rs, o7 * ro) * inv;
    }

    if (half == 0) {
        uint4 o;
        o.x = (unsigned int)f2bf(r0) | ((unsigned int)f2bf(r1) << 16);
        o.y = (unsigned int)f2bf(r2) | ((unsigned int)f2bf(r3) << 16);
        o.z = (unsigned int)f2bf(r4) | ((unsigned int)f2bf(r5) << 16);
        o.w = (unsigned int)f2bf(r6) | ((unsigned int)f2bf(r7) << 16);
        *(uint4*)((unsigned char*)(aggbf + aoffE[z]) + (size_t)d * 512 + 16 * h) = o;
    }
}

__global__ void colsum_kernel(const unsigned short* __restrict__ hbf, float* __restrict__ out, int N)
{
    int c = threadIdx.x;
    float acc = 0.0f;
    for (int r = blockIdx.x; r < N; r += gridDim.x)
        acc += bf2f(hbf[(size_t)r * 256 + c]);
    atomicAdd(&out[c], acc);
}

__global__ __launch_bounds__(512)
void head_kernel(const float* __restrict__ colsum, float n_img,
                 const float* __restrict__ pred_w, const float* __restrict__ pred_b,
                 const float* __restrict__ head1_w, const float* __restrict__ head1_b,
                 const float* __restrict__ head_w, const float* __restrict__ head_b,
                 float* __restrict__ cvec)
{
    __shared__ float mean[256], o0[256], g[512];
    int t = threadIdx.x;
    if (t < 256) mean[t] = colsum[t] / n_img;
    __syncthreads();
    if (t < 256) {
        float acc = pred_b[t];
        for (int k = 0; k < 256; ++k) acc += mean[k] * pred_w[k * 256 + t];
        o0[t] = acc;
    }
    __syncthreads();
    {
        float acc = head1_b[t];
        for (int k = 0; k < 256; ++k) acc += o0[k] * head1_w[k * 512 + t];
        g[t] = acc;
    }
    __syncthreads();
    {
        float acc = head_b[t];
        for (int k = 0; k < 512; ++k) acc += g[k] * head_w[k * 512 + t];
        cvec[t] = acc;
    }
}

extern "C" void kernel_launch(void* const* d_in, const int* in_sizes, int n_in,
                              void* d_out, int out_size, void* d_ws, size_t ws_size,
                              hipStream_t stream)
{
    const int NI = 20000, E = 100000;

    const float* feat[3] = {(const float*)d_in[0], (const float*)d_in[1], (const float*)d_in[2]};
    const float* adapt_w = (const float*)d_in[3];
    const float* adapt_b = (const float*)d_in[4];
    const float* k_w = (const float*)d_in[5];
    const float* k_b = (const float*)d_in[6];
    const float* q_w = (const float*)d_in[7];
    const float* q_b = (const float*)d_in[8];
    const float* v_w = (const float*)d_in[9];
    const float* v_b = (const float*)d_in[10];
    const float* a_w = (const float*)d_in[11];
    const float* a_b = (const float*)d_in[12];
    const float* e_w = (const float*)d_in[13];
    const float* e_b = (const float*)d_in[14];
    const float* skip = (const float*)d_in[15];
    const float* pred_w = (const float*)d_in[16];
    const float* pred_b = (const float*)d_in[17];
    const float* head1_w = (const float*)d_in[19];
    const float* head1_b = (const float*)d_in[20];
    const float* head_w = (const float*)d_in[21];
    const float* head_b = (const float*)d_in[22];

    GraphPtrs gp;
    for (int i = 0; i < 6; ++i) {
        gp.sim[i] = (const float*)d_in[23 + i];
        gp.src[i] = (const int*)d_in[29 + 2 * i];
        gp.dst[i] = (const int*)d_in[30 + 2 * i];
    }

    float* ws = (float*)d_ws;
    size_t off = 0;
    auto alloc = [&](size_t n) { float* p = ws + off; off += (n + 3) & ~(size_t)3; return p; };
    const size_t NTOT = 35000ull * 256;
    unsigned short* hbf   = (unsigned short*)alloc(NTOT / 2);
    unsigned short* aggbf = (unsigned short*)alloc(NTOT / 2);
    unsigned char* qkvb   = (unsigned char*)alloc(35000ull * 256);   // 1024 B per node
    unsigned short* fbf   = (unsigned short*)alloc(20000ull * 512 / 2);  // bf16 feats[0]
    float* csum = alloc(256);
    float* cvec = alloc(512);
    int* deg6    = (int*)alloc(70000);
    int* cursor6 = (int*)alloc(70000);
    int* rp6     = (int*)alloc(70012);
    int2* csr_es6 = (int2*)alloc(1200000);
    unsigned short* adapt_wt = (unsigned short*)alloc(3 * 512 * 256 / 2);
    unsigned short* W3   = (unsigned short*)alloc(6ull * 768 * 256 / 2);  // [lt][768][256]
    unsigned short* a_wt = (unsigned short*)alloc(6 * 65536 / 2);
    float* bias768 = alloc(6 * 768);
    unsigned short* head_wt = (unsigned short*)alloc(512 * 512 / 2);

    // ---- CSR build: 4 dispatches for all 6 etypes ----
    hipMemsetAsync(deg6, 0, 70000 * sizeof(int), stream);
    hipLaunchKernelGGL(hist6_kernel, dim3((E + 255) / 256, 6), dim3(256), 0, stream, gp, deg6);
    hipLaunchKernelGGL(scan6_kernel, dim3(6), dim3(256), 0, stream, deg6, rp6, cursor6);
    hipLaunchKernelGGL(scatter6_kernel, dim3((E + 255) / 256, 6), dim3(256), 0, stream,
                       gp, cursor6, csr_es6);

    // ---- weights -> bf16 ----
    hipLaunchKernelGGL(wcvt_kernel, dim3(16, 8, 3), dim3(256), 0, stream, adapt_w, adapt_wt, 512, 256);
    hipLaunchKernelGGL(wcvt_qkv_kernel, dim3(8, 8, 18), dim3(256), 0, stream, q_w, k_w, v_w, W3);
    hipLaunchKernelGGL(wcvt_kernel, dim3(8, 8, 6), dim3(256), 0, stream, a_w, a_wt, 256, 256);
    hipLaunchKernelGGL(wcvt_kernel, dim3(16, 16, 1), dim3(256), 0, stream, head_w, head_wt, 512, 512);
    hipLaunchKernelGGL(bias_concat_kernel, dim3(18), dim3(256), 0, stream, q_b, k_b, v_b, bias768);

    // ---- adapt (all 3 types in one dispatch; side-writes bf16 feat0 into fbf) ----
    Ptr3f fa; fa.p[0] = feat[0]; fa.p[1] = feat[1]; fa.p[2] = feat[2];
    hipLaunchKernelGGL(adapt_gemm3, dim3(2, 157, 3), dim3(256), 0, stream, fa, adapt_wt, adapt_b, hbf, fbf);

    for (int l = 0; l < 2; ++l) {
        hipLaunchKernelGGL(qkv_gemm3, dim3(6, 157, 3), dim3(256), 0, stream,
                           hbf, W3 + (size_t)l * 3 * 768 * 256, bias768 + (size_t)l * 3 * 768, qkvb);
        hipLaunchKernelGGL(attn_fused_kernel, dim3(5000, 3), dim3(256), 0, stream,
                           qkvb, rp6, csr_es6, e_w + l, e_b + l, aggbf);
        hipLaunchKernelGGL(a_gemm3, dim3(2, 157, 3), dim3(256), 0, stream,
                           aggbf, a_wt + (size_t)l * 3 * 65536, a_b + (size_t)l * 3 * 256,
                           skip + l * 3, hbf);
    }

    hipMemsetAsync(csum, 0, 256 * sizeof(float), stream);
    hipLaunchKernelGGL(colsum_kernel, dim3(128), dim3(256), 0, stream, hbf, csum, NI);
    hipLaunchKernelGGL(head_kernel, dim3(1), dim3(512), 0, stream,
                       csum, (float)NI, pred_w, pred_b, head1_w, head1_b, head_w, head_b, cvec);

    // out = bf16(feats[0]) @ head_w + cvec
    hipLaunchKernelGGL(head_gemm, dim3(4, 157), dim3(256), 0, stream,
                       fbf, head_wt, cvec, (float*)d_out);
}